// Round 1
// 3550.602 us; speedup vs baseline: 1.1267x; 1.1267x over previous
//
#include <hip/hip_runtime.h>

namespace {

constexpr int Hn = 128, Wn = 128, HWn = 16384, HWFn = 8320;
constexpr float TWOPI = 6.2831853071795864769f;
constexpr float BN_SCALE = 0.99999500003749968f;   // 1/sqrt(1+1e-5)

typedef __attribute__((ext_vector_type(8))) short short8;
typedef __attribute__((ext_vector_type(4))) float float4v;

__device__ __forceinline__ short f2bf(float v){
  unsigned u = __float_as_uint(v);
  u += 0x7FFF + ((u >> 16) & 1);          // RNE
  return (short)(u >> 16);
}

// ---------- weight pack to MFMA A-frag order (bf16) ----------
__global__ void k_pack(const float* __restrict__ w, unsigned short* __restrict__ o, int Cin, int n){
  int i = blockIdx.x*256 + threadIdx.x;
  if (i >= n) return;
  int j = i & 7, lane = (i>>3)&63, mt = (i>>9)&3, p = i>>11;
  int blk = p/18, r = p - blk*18, tap = r>>1, ks = r&1;
  int co = mt*16 + (lane & 15);
  int ci = blk*64 + ks*32 + ((lane>>4)<<3) + j;
  o[i] = (unsigned short)f2bf(w[((size_t)co*Cin + ci)*9 + tap]);
}

// ---------- MFMA 3x3 conv: Cout=64, one output row per WG ----------
constexpr int XST = 72;
__global__ __launch_bounds__(256) void k_mconv(
    const float* __restrict__ in, const float* __restrict__ in2,
    const unsigned short* __restrict__ wpk, const float* __restrict__ bias,
    const float* __restrict__ res, float* __restrict__ out,
    int nblk, int dl, int leaky){
  __shared__ short lds[3*134*XST];
  int b = blockIdx.x >> 7, y = blockIdx.x & 127;
  int tid = threadIdx.x;
  int wv = tid >> 6, lane = tid & 63;
  int nq = lane >> 4, nr = lane & 15;
  float4v acc[4][2];
  #pragma unroll
  for (int mt=0; mt<4; mt++)
    #pragma unroll
    for (int nt=0; nt<2; nt++) acc[mt][nt] = (float4v){0.f,0.f,0.f,0.f};

  for (int blk=0; blk<nblk; blk++){
    const float* src = blk ? in2 : in;
    __syncthreads();
    for (int e = tid; e < 3*64*134; e += 256){
      int dy = e / (64*134); int r = e - dy*64*134;
      int ci = r / 134;      int x = r - ci*134;
      int yy = y + (dy-1)*dl;
      int xx = x - 3;
      float v = 0.f;
      if (yy >= 0 && yy < Hn && xx >= 0 && xx < Wn)
        v = src[(((size_t)b*64 + ci)*Hn + yy)*Wn + xx];
      lds[(dy*134 + x)*XST + ci] = f2bf(v);
    }
    __syncthreads();
    const unsigned short* wb = wpk + (size_t)blk*36864;
    for (int tap=0; tap<9; tap++){
      int dy = tap/3, dx = tap - (tap/3)*3;
      #pragma unroll
      for (int ks=0; ks<2; ks++){
        short8 a[4];
        #pragma unroll
        for (int mt=0; mt<4; mt++)
          a[mt] = *(const short8*)(wb + (((size_t)(tap*2+ks)*4+mt)<<9) + ((size_t)lane<<3));
        #pragma unroll
        for (int nt=0; nt<2; nt++){
          int x = wv*32 + nt*16 + nr + (dx-1)*dl + 3;
          short8 bf = *(const short8*)&lds[(dy*134 + x)*XST + ks*32 + nq*8];
          #pragma unroll
          for (int mt=0; mt<4; mt++)
            acc[mt][nt] = __builtin_amdgcn_mfma_f32_16x16x32_bf16(a[mt], bf, acc[mt][nt], 0, 0, 0);
        }
      }
    }
  }
  #pragma unroll
  for (int mt=0; mt<4; mt++)
  #pragma unroll
  for (int nt=0; nt<2; nt++){
    int x = wv*32 + nt*16 + nr;
    #pragma unroll
    for (int r2=0; r2<4; r2++){
      int co = mt*16 + nq*4 + r2;
      float a = acc[mt][nt][r2] + (bias ? bias[co] : 0.f);
      if (leaky) a = (a >= 0.f) ? a : 0.01f*a;
      size_t idx = (((size_t)b*64 + co)*Hn + y)*Wn + x;
      if (res) a += res[idx];
      out[idx] = a;
    }
  }
}

// ---------- depthwise 3x3, pad 1 ----------
__global__ void k_dw3x3(const float* __restrict__ in, const float* __restrict__ w,
                        const float* __restrict__ bias, float* __restrict__ out, int C){
  int bc = blockIdx.x; int y = blockIdx.y; int x = threadIdx.x;
  int c = bc % C;
  const float* ip = in + (size_t)bc*HWn;
  const float* wp = w + c*9;
  float acc = bias ? bias[c] : 0.f;
  #pragma unroll
  for (int ky=0; ky<3; ky++){
    int yy = y + ky - 1; if (yy < 0 || yy >= Hn) continue;
    #pragma unroll
    for (int kx=0; kx<3; kx++){
      int xx = x + kx - 1; if (xx < 0 || xx >= Wn) continue;
      acc = fmaf(ip[yy*Wn+xx], wp[ky*3+kx], acc);
    }
  }
  out[(size_t)bc*HWn + y*Wn + x] = acc;
}

// ---------- pointwise 1x1, register-tiled ----------
template<int CT>
__global__ void k_pwt(const float* __restrict__ in, const float* __restrict__ wg,
                      const float* __restrict__ bias, const float* __restrict__ bng,
                      const float* __restrict__ bnb, float* __restrict__ out,
                      int Cin, int Cout, int npix, int inb, int outb, int post, float slope){
  extern __shared__ float wsm[];
  int nt = (Cout + CT - 1)/CT;
  int b = blockIdx.x / nt, t = blockIdx.x - b*nt;
  int co0 = t*CT;
  for (int i = threadIdx.x; i < CT*Cin; i += 256){
    int co = i / Cin;
    wsm[i] = (co0 + co < Cout) ? wg[(size_t)(co0+co)*Cin + (i - co*Cin)] : 0.f;
  }
  __syncthreads();
  int p = blockIdx.y*256 + threadIdx.x;
  if (p >= npix) return;
  const float* ip = in + (size_t)b*inb + p;
  float acc[CT];
  #pragma unroll
  for (int j=0; j<CT; j++) acc[j] = 0.f;
  for (int ci=0; ci<Cin; ci++){
    float v = ip[(size_t)ci*npix];
    #pragma unroll
    for (int j=0; j<CT; j++) acc[j] = fmaf(v, wsm[j*Cin+ci], acc[j]);
  }
  #pragma unroll
  for (int j=0; j<CT; j++){
    int co = co0 + j;
    if (co < Cout){
      float a = acc[j] + (bias ? bias[co] : 0.f);
      if (bng) a = a*(bng[co]*BN_SCALE) + bnb[co];
      if (post == 1) a = fminf(fmaxf(a, -1.f), 1.f);
      else if (post == 2) a = a*fminf(fmaxf(a+3.f, 0.f), 6.f)*(1.f/6.f);
      else if (post == 3) a = (a >= 0.f) ? a : a*slope;
      out[(size_t)b*outb + (size_t)co*npix + p] = a;
    }
  }
}

// ---------- deformable depthwise 3x3 ----------
__global__ void k_deform(const float* __restrict__ x, const float* __restrict__ off,
                         const float* __restrict__ w, float* __restrict__ out, int C){
  int bc = blockIdx.x; int b = bc / C; int c = bc - b*C;
  int y = blockIdx.y; int x0 = threadIdx.x;
  const float* xp = x + (size_t)bc*HWn;
  const float* op = off + (size_t)b*18*HWn + y*Wn + x0;
  const float* wp = w + c*9;
  float acc = 0.f;
  #pragma unroll
  for (int k=0; k<9; k++){
    int ky = k/3 - 1, kx = k - (k/3)*3 - 1;
    float oy = op[(size_t)(2*k)*HWn];
    float ox = op[(size_t)(2*k+1)*HWn];
    float py = (float)y + (float)ky + oy;
    float px = (float)x0 + (float)kx + ox;
    float fy = floorf(py), fx = floorf(px);
    float wy = py - fy, wx = px - fx;
    int y0 = (int)fy, xx0 = (int)fx;
    float val = 0.f;
    #pragma unroll
    for (int dy=0; dy<2; dy++){
      int iy = y0 + dy; if (iy < 0 || iy >= Hn) continue;
      float wyv = dy ? wy : (1.f - wy);
      #pragma unroll
      for (int dx=0; dx<2; dx++){
        int ix = xx0 + dx; if (ix < 0 || ix >= Wn) continue;
        float wxv = dx ? wx : (1.f - wx);
        val = fmaf(xp[iy*Wn+ix], wyv*wxv, val);
      }
    }
    acc = fmaf(val, wp[k], acc);
  }
  out[(size_t)bc*HWn + y*Wn + x0] = acc;
}

// ---------- small direct conv (final 6->3) ----------
__global__ void k_conv3x3s(const float* __restrict__ in, const float* __restrict__ wgt,
                           const float* __restrict__ bias, const float* __restrict__ res,
                           float* __restrict__ out, int Cin, int Cout){
  int g = blockIdx.x;
  int b = g / Cout; int o0 = g - b*Cout;
  int y = blockIdx.y, x = threadIdx.x;
  float acc = bias ? bias[o0] : 0.f;
  for (int ci=0; ci<Cin; ci++){
    const float* iip = in + ((size_t)b*Cin + ci)*HWn;
    const float* wp = wgt + ((size_t)o0*Cin + ci)*9;
    #pragma unroll
    for (int ky=0; ky<3; ky++){
      int yy = y + ky - 1; if (yy < 0 || yy >= Hn) continue;
      #pragma unroll
      for (int kx=0; kx<3; kx++){
        int xx = x + kx - 1; if (xx < 0 || xx >= Wn) continue;
        acc = fmaf(iip[yy*Wn+xx], wp[ky*3+kx], acc);
      }
    }
  }
  size_t idx = ((size_t)b*Cout + o0)*HWn + y*Wn + x;
  if (res) acc += res[idx];
  out[idx] = acc;
}

// ---------- fused cross-attention: one WG per (b,h) ----------
__global__ __launch_bounds__(256) void k_attn(
    const float* __restrict__ q, const float* __restrict__ k,
    const float* __restrict__ v, float* __restrict__ o){
  __shared__ float qs[64][129];
  __shared__ float ks[64][129];
  __shared__ float vs[64][129];
  __shared__ float ps[64][66];
  int bh = blockIdx.x; int b = bh >> 7, h = bh & 127;
  size_t base = ((size_t)b*64*128 + h)*128;
  int tid = threadIdx.x;
  for (int e = tid; e < 8192; e += 256){
    int c = e >> 7, w = e & 127;
    size_t g = base + (size_t)c*HWn + w;
    qs[c][w] = q[g]; ks[c][w] = k[g]; vs[c][w] = v[g];
  }
  __syncthreads();
  {
    int c0 = (tid >> 4) << 2, d0 = (tid & 15) << 2;
    float acc[4][4];
    #pragma unroll
    for (int a=0; a<4; a++)
      #pragma unroll
      for (int bb=0; bb<4; bb++) acc[a][bb] = 0.f;
    for (int i=0; i<128; i++){
      float qv[4], kv[4];
      #pragma unroll
      for (int a=0; a<4; a++){ qv[a] = qs[c0+a][i]; kv[a] = ks[d0+a][i]; }
      #pragma unroll
      for (int a=0; a<4; a++)
        #pragma unroll
        for (int bb=0; bb<4; bb++) acc[a][bb] = fmaf(qv[a], kv[bb], acc[a][bb]);
    }
    #pragma unroll
    for (int a=0; a<4; a++)
      #pragma unroll
      for (int bb=0; bb<4; bb++)
        ps[c0+a][d0+bb] = acc[a][bb] * 0.35355339059327373f;
  }
  __syncthreads();
  {
    int wv = tid >> 6, lane = tid & 63;
    for (int it=0; it<16; it++){
      int row = wv*16 + it;
      float vv = ps[row][lane];
      float m = vv;
      #pragma unroll
      for (int off=32; off; off>>=1) m = fmaxf(m, __shfl_xor(m, off));
      float e = expf(vv - m);
      float s = e;
      #pragma unroll
      for (int off=32; off; off>>=1) s += __shfl_xor(s, off);
      ps[row][lane] = e / s;
    }
  }
  __syncthreads();
  {
    int c0 = (tid >> 4) << 2, w0 = (tid & 15) << 3;
    float acc[4][8];
    #pragma unroll
    for (int a=0; a<4; a++)
      #pragma unroll
      for (int j=0; j<8; j++) acc[a][j] = 0.f;
    for (int d=0; d<64; d++){
      float pv[4], vv[8];
      #pragma unroll
      for (int a=0; a<4; a++) pv[a] = ps[c0+a][d];
      #pragma unroll
      for (int j=0; j<8; j++) vv[j] = vs[d][w0+j];
      #pragma unroll
      for (int a=0; a<4; a++)
        #pragma unroll
        for (int j=0; j<8; j++) acc[a][j] = fmaf(pv[a], vv[j], acc[a][j]);
    }
    #pragma unroll
    for (int a=0; a<4; a++)
      #pragma unroll
      for (int j=0; j<8; j++)
        o[base + (size_t)(c0+a)*HWn + w0 + j] = acc[a][j];
  }
}

// ============ radix-2 FFT machinery (128-point, in LDS) ============
// DIF stages (natural in, bit-reversed out) + bit-reversal pass.
// Twiddle table tw[j] = (cos th, -sin th) forward / (cos th, +sin th) inverse,
// th = 2*pi*j/128.  Direction is baked into the table.

// 64 independent 128-pt complex FFTs over rows: zb[f*128 + i], f=0..63
__device__ __forceinline__ void fft128_rows(float2* zb, const float2* tw, int tid){
  for (int s = 6; s >= 0; --s){
    int h = 1 << s;
    for (int b = tid; b < 4096; b += 256){
      int f = b >> 6, j = b & 63;
      int jh = j & (h - 1);
      int i0 = (f << 7) + ((j >> s) << (s + 1)) + jh;
      int i1 = i0 + h;
      float2 u = zb[i0], v = zb[i1];
      float2 w = tw[jh << (6 - s)];
      float dx = u.x - v.x, dy = u.y - v.y;
      zb[i0] = make_float2(u.x + v.x, u.y + v.y);
      zb[i1] = make_float2(dx*w.x - dy*w.y, dx*w.y + dy*w.x);
    }
    __syncthreads();
  }
  for (int i = tid; i < 8192; i += 256){
    int f = i & ~127, m = i & 127;
    int r = (int)(__brev((unsigned)m) >> 25);
    if (m < r){
      float2 a = zb[f + m], c = zb[f + r];
      zb[f + m] = c; zb[f + r] = a;
    }
  }
  __syncthreads();
}

// 65 independent 128-pt complex FFTs down columns: sp[r*66 + col], col=0..64
__device__ __forceinline__ void fft128_cols(float2* sp, const float2* tw, int tid){
  for (int s = 6; s >= 0; --s){
    int h = 1 << s;
    int hs = h * 66;
    for (int b = tid; b < 4160; b += 256){
      int j = b / 65, col = b - j*65;
      int jh = j & (h - 1);
      int i0 = (((j >> s) << (s + 1)) + jh) * 66 + col;
      int i1 = i0 + hs;
      float2 u = sp[i0], v = sp[i1];
      float2 w = tw[jh << (6 - s)];
      float dx = u.x - v.x, dy = u.y - v.y;
      sp[i0] = make_float2(u.x + v.x, u.y + v.y);
      sp[i1] = make_float2(dx*w.x - dy*w.y, dx*w.y + dy*w.x);
    }
    __syncthreads();
  }
  for (int i = tid; i < 8320; i += 256){
    int m = i / 65, col = i - m*65;
    int r = (int)(__brev((unsigned)m) >> 25);
    if (m < r){
      int a0 = m*66 + col, a1 = r*66 + col;
      float2 a = sp[a0], c = sp[a1];
      sp[a0] = c; sp[a1] = a;
    }
  }
  __syncthreads();
}

// ---------- fused rfft2 + mag/pha: one WG per image plane ----------
// x: [B*64][128][128]; mag/pha: [B][128ch][8320], write ch 0..63
__global__ __launch_bounds__(256) void k_fft2(
    const float* __restrict__ x, float* __restrict__ mag, float* __restrict__ pha){
  __shared__ float2 zb[8192];     // 64 packed complex rows x 128    (64 KiB)
  __shared__ float2 sp[8448];     // 128 x 66 (65 used) row spectra  (66 KiB)
  __shared__ float2 tw[64];
  int img = blockIdx.x;
  int tid = threadIdx.x;
  if (tid < 64){
    float th = TWOPI * (float)tid * (1.f/128.f);
    float s, c; sincosf(th, &s, &c);
    tw[tid] = make_float2(c, -s);          // forward: e^{-i th}
  }
  // pack: z_f = x[2f] + i*x[2f+1]
  const float* xp = x + (size_t)img*HWn;
  for (int i = tid; i < 8192; i += 256){
    int f = i >> 7, n = i & 127;
    zb[i] = make_float2(xp[(2*f)*Wn + n], xp[(2*f+1)*Wn + n]);
  }
  __syncthreads();
  fft128_rows(zb, tw, tid);
  // Hermitian unpack: A[k] row 2f, B[k] row 2f+1, k = 0..64
  for (int i = tid; i < 4160; i += 256){
    int f = i / 65, k = i - f*65;
    float2 Zk = zb[(f << 7) + k];
    float2 Zn = zb[(f << 7) + ((128 - k) & 127)];
    sp[(2*f)*66 + k]   = make_float2(0.5f*(Zk.x + Zn.x), 0.5f*(Zk.y - Zn.y));
    sp[(2*f+1)*66 + k] = make_float2(0.5f*(Zk.y + Zn.y), 0.5f*(Zn.x - Zk.x));
  }
  __syncthreads();
  fft128_cols(sp, tw, tid);
  // mag / pha out
  int b = img >> 6, ch = img & 63;
  float* mp = mag + ((size_t)b*128 + ch)*HWFn;
  float* pp = pha + ((size_t)b*128 + ch)*HWFn;
  for (int i = tid; i < 8320; i += 256){
    int kk = i / 65, w = i - kk*65;
    float2 v = sp[kk*66 + w];
    mp[i] = sqrtf(v.x*v.x + v.y*v.y);
    pp[i] = atan2f(v.y, v.x);
  }
}

// ---------- fused irfft2 + residual add: one WG per image plane (256 imgs) ----------
// mo/po: [256 img][8320] (= out1/out2 head); hsrc/outp: [256 img][16384]
__global__ __launch_bounds__(256) void k_ifft2(
    const float* __restrict__ mo, const float* __restrict__ po,
    const float* __restrict__ hsrc, float* __restrict__ outp){
  __shared__ float2 sp[8448];     // 128 x 66 spectrum
  __shared__ float2 zb[8192];     // 64 packed complex rows
  __shared__ float2 tw[64];
  int img = blockIdx.x;
  int tid = threadIdx.x;
  if (tid < 64){
    float th = TWOPI * (float)tid * (1.f/128.f);
    float s, c; sincosf(th, &s, &c);
    tw[tid] = make_float2(c, s);           // inverse: e^{+i th}
  }
  const float* mp = mo + (size_t)img*HWFn;
  const float* pp = po + (size_t)img*HWFn;
  for (int i = tid; i < 8320; i += 256){
    int kk = i / 65, w = i - kk*65;
    float m = mp[i], p = pp[i];
    float s, c; sincosf(p, &s, &c);
    sp[kk*66 + w] = make_float2(m*c, m*s);
  }
  __syncthreads();
  fft128_cols(sp, tw, tid);                // unnormalized inverse along k
  // build packed rows Z = A + iB with Hermitian extension over t
  // (Im at t=0 and t=64 dropped -- matches numpy c2r semantics)
  for (int i = tid; i < 8192; i += 256){
    int f = i >> 7, k = i & 127;
    float2 A, B;
    if (k <= 64){
      A = sp[(2*f)*66 + k]; B = sp[(2*f+1)*66 + k];
      if (k == 0 || k == 64){ A.y = 0.f; B.y = 0.f; }
    } else {
      int kk = 128 - k;
      A = sp[(2*f)*66 + kk];   A.y = -A.y;
      B = sp[(2*f+1)*66 + kk]; B.y = -B.y;
    }
    zb[i] = make_float2(A.x - B.y, A.y + B.x);
  }
  __syncthreads();
  fft128_rows(zb, tw, tid);                // unnormalized inverse along t
  const float scale = 1.f/16384.f;
  for (int i = tid; i < 8192; i += 256){
    int f = i >> 7, n = i & 127;
    float2 z = zb[i];
    size_t g0 = (size_t)img*HWn + (size_t)(2*f)*Wn + n;
    outp[g0]       = z.x*scale + hsrc[g0];
    outp[g0 + Wn]  = z.y*scale + hsrc[g0 + Wn];
  }
}

} // namespace

extern "C" void kernel_launch(void* const* d_in, const int* in_sizes, int n_in,
                              void* d_out, int out_size, void* d_ws, size_t ws_size,
                              hipStream_t stream){
  const float *xf   =(const float*)d_in[0],  *chodw=(const float*)d_in[1],
              *chopw=(const float*)d_in[2],  *chdcn=(const float*)d_in[3],
              *chpw =(const float*)d_in[4],  *ctodw=(const float*)d_in[5],
              *ctopw=(const float*)d_in[6],  *ctdcn=(const float*)d_in[7],
              *ctpw =(const float*)d_in[8],  *dbw  =(const float*)d_in[9],
              *dbb  =(const float*)d_in[10], *cadw =(const float*)d_in[11],
              *cadb =(const float*)d_in[12], *capw =(const float*)d_in[13],
              *capb =(const float*)d_in[14], *hhw  =(const float*)d_in[15],
              *hhb  =(const float*)d_in[16], *fd1w =(const float*)d_in[17],
              *fd2w =(const float*)d_in[18], *fd1g =(const float*)d_in[19],
              *fd1bt=(const float*)d_in[20], *fd2g =(const float*)d_in[21],
              *fd2bt=(const float*)d_in[22], *fcw  =(const float*)d_in[23],
              *cw   =(const float*)d_in[24], *cb   =(const float*)d_in[25];

  constexpr size_t M = 1048576;            // one batch x 64ch x HW (floats)
  float* ws = (float*)d_ws;
  float* h     = ws;                       // 12*M
  float* fftHL = ws + 12*M;                // 4*M
  float* cat6  = ws + 16*M;                // 1,179,648
  unsigned short* wpkDB = (unsigned short*)(cat6 + 1179648);
  unsigned short* wpkHH = wpkDB + 552960;
  float* P = cat6 + 1179648 + 313344;      // pool

  const int NB = (ws_size >= 266018816ull) ? 4 : 1;
  const size_t S = (size_t)NB*M;
  float* kb  = P;        float* vb  = P + S;   float* qb  = P + 2*S;
  float* qs  = P + 3*S;  float* aA  = P + 4*S; float* aB  = P + 5*S;
  float* aC  = P + 6*S;  float* hh1 = P + 7*S; float* sA  = P + 8*S;
  float* sB  = P + 9*S;  float* dbuf= P + 10*S;
  float* X   = P + 11*S;
  // phase-1 aliases
  float* dwb3 = P; float* offb12 = P + 589824; float* yb3 = P + 4128768;

  float* out = (float*)d_out;
  float* out0 = out;
  float* out1 = out + 589824;
  float* out2 = out + 589824 + 6389760;

  auto PW = [&](const float* in, const float* wg, const float* bi, const float* g, const float* bt,
                float* o, int B, int Ci, int Co, int npix, int inb, int outb, int post, float slope){
    int py = (npix + 255)/256;
    if (Co > 32){
      k_pwt<32><<<dim3(B*2, py), 256, 32*Ci*4, stream>>>(in, wg, bi, g, bt, o, Ci, Co, npix, inb, outb, post, slope);
    } else if (Co > 18){
      k_pwt<32><<<dim3(B, py), 256, 32*Ci*4, stream>>>(in, wg, bi, g, bt, o, Ci, Co, npix, inb, outb, post, slope);
    } else if (Co > 3){
      k_pwt<18><<<dim3(B, py), 256, 18*Ci*4, stream>>>(in, wg, bi, g, bt, o, Ci, Co, npix, inb, outb, post, slope);
    } else {
      k_pwt<3><<<dim3(B, py), 256, 3*Ci*4, stream>>>(in, wg, bi, g, bt, o, Ci, Co, npix, inb, outb, post, slope);
    }
  };
  auto MCONV = [&](const float* in, const float* in2, const unsigned short* wp, const float* bi,
                   const float* res, float* o, int B, int nblk, int dl, int lk){
    k_mconv<<<B*128, 256, 0, stream>>>(in, in2, wp, bi, res, o, nblk, dl, lk);
  };
  auto DILm = [&](const float* in, int set, const float* bset, int B){
    const unsigned short* w5 = wpkDB + (size_t)set*5*36864;
    MCONV(in, nullptr, w5,          bset,      nullptr, sA,   B, 1, 1, 1);
    MCONV(sA, nullptr, w5+36864,    bset+64,   nullptr, sB,   B, 1, 2, 1);
    MCONV(sB, nullptr, w5+2*36864,  bset+128,  nullptr, sA,   B, 1, 3, 1);
    MCONV(sA, nullptr, w5+3*36864,  bset+192,  nullptr, sB,   B, 1, 2, 1);
    MCONV(sB, nullptr, w5+4*36864,  bset+256,  in,      dbuf, B, 1, 1, 0);
  };
  auto DCONVm = [&](const float* in, int idx, float* o, int B){
    k_dw3x3<<<dim3(B*64, Hn), 128, 0, stream>>>(in, cadw + idx*576, cadb + idx*64, qs, 64);
    PW(qs, capw + (size_t)idx*4096, capb + idx*64, nullptr, nullptr, o, B, 64, 64, HWn, 64*HWn, 64*HWn, 0, 0.f);
  };
  auto ATTNm = [&](const float* qsrc, int qidx, float* o, int B){
    DCONVm(qsrc, qidx, qb, B);
    k_attn<<<B*128, 256, 0, stream>>>(qb, kb, vb, o);
  };
  auto PEMBEDm = [&](const float* in, float* outSlice, int B){
    k_dw3x3<<<dim3(B*64, Hn), 128, 0, stream>>>(in, ctodw, nullptr, qs, 64);
    PW(qs, ctopw, nullptr, nullptr, nullptr, X, B, 64, 18, HWn, 64*HWn, 18*HWn, 1, 0.f);
    k_deform<<<dim3(B*64, Hn), 128, 0, stream>>>(in, X, ctdcn, qs, 64);
    PW(qs, ctpw, nullptr, nullptr, nullptr, outSlice, B, 64, 3, HWn, 64*HWn, 6*HWn, 2, 0.f);
  };

  // ===== Pack conv weights =====
  for (int c=0; c<15; c++)
    k_pack<<<144, 256, 0, stream>>>(dbw + (size_t)c*36864, wpkDB + (size_t)c*36864, 64, 36864);
  k_pack<<<288, 256, 0, stream>>>(hhw, wpkHH, 128, 73728);

  // ===== Phase 1: patch_embed(ch) -> h =====
  k_dw3x3<<<dim3(36, Hn), 128, 0, stream>>>(xf, chodw, nullptr, dwb3, 3);
  PW(dwb3, chopw, nullptr, nullptr, nullptr, offb12, 12, 3, 18, HWn, 3*HWn, 18*HWn, 1, 0.f);
  k_deform<<<dim3(36, Hn), 128, 0, stream>>>(xf, offb12, chdcn, yb3, 3);
  PW(yb3, chpw, nullptr, nullptr, nullptr, h, 12, 3, 64, HWn, 3*HWn, 64*HWn, 2, 0.f);

  // ===== Phase 2: fft_block (fused LDS-resident 2-D FFT) =====
  if (NB == 4){
    float* mB = P;                 // [12][128][8320]
    float* pB = P + 12779520;
    k_fft2<<<768, 256, 0, stream>>>(h, mB, pB);
    PW(mB, fd1w, nullptr, fd1g, fd1bt, mB + 64*HWFn, 12, 64, 32, HWFn, 128*HWFn, 128*HWFn, 3, 0.1f);
    PW(mB, fd2w, nullptr, fd2g, fd2bt, mB + 96*HWFn, 12, 96, 32, HWFn, 128*HWFn, 128*HWFn, 3, 0.1f);
    PW(mB, fcw,  nullptr, nullptr, nullptr, out1,    12, 128, 64, HWFn, 128*HWFn, 64*HWFn, 0, 0.f);
    PW(pB, fd1w+2048, nullptr, fd1g+32, fd1bt+32, pB + 64*HWFn, 12, 64, 32, HWFn, 128*HWFn, 128*HWFn, 3, 0.1f);
    PW(pB, fd2w+3072, nullptr, fd2g+32, fd2bt+32, pB + 96*HWFn, 12, 96, 32, HWFn, 128*HWFn, 128*HWFn, 3, 0.1f);
    PW(pB, fcw+8192,  nullptr, nullptr, nullptr,  out2, 12, 128, 64, HWFn, 128*HWFn, 64*HWFn, 0, 0.f);
    k_ifft2<<<256, 256, 0, stream>>>(out1, out2, h, fftHL);
  } else {
    // 3 chunks of 4 batches
    float* mB = P;                 // [4][128][8320]
    float* pB = P + 4259840;
    for (int c=0; c<3; c++){
      const float* hsrc = h + (size_t)c*4*M;
      float* o1 = out1 + (size_t)c*2129920;
      float* o2 = out2 + (size_t)c*2129920;
      k_fft2<<<256, 256, 0, stream>>>(hsrc, mB, pB);
      PW(mB, fd1w, nullptr, fd1g, fd1bt, mB + 64*HWFn, 4, 64, 32, HWFn, 128*HWFn, 128*HWFn, 3, 0.1f);
      PW(mB, fd2w, nullptr, fd2g, fd2bt, mB + 96*HWFn, 4, 96, 32, HWFn, 128*HWFn, 128*HWFn, 3, 0.1f);
      PW(mB, fcw,  nullptr, nullptr, nullptr, o1,      4, 128, 64, HWFn, 128*HWFn, 64*HWFn, 0, 0.f);
      PW(pB, fd1w+2048, nullptr, fd1g+32, fd1bt+32, pB + 64*HWFn, 4, 64, 32, HWFn, 128*HWFn, 128*HWFn, 3, 0.1f);
      PW(pB, fd2w+3072, nullptr, fd2g+32, fd2bt+32, pB + 96*HWFn, 4, 96, 32, HWFn, 128*HWFn, 128*HWFn, 3, 0.1f);
      PW(pB, fcw+8192,  nullptr, nullptr, nullptr,  o2, 4, 128, 64, HWFn, 128*HWFn, 64*HWFn, 0, 0.f);
      if (c == 0)
        k_ifft2<<<256, 256, 0, stream>>>(out1, out2, h, fftHL);
    }
  }

  // ===== Phases 3-5 in groups of NB batches =====
  for (int g0=0; g0<4; g0+=NB){
    const float* hHL = h + (size_t)g0*M;
    const float* hLH = h + (size_t)(4+g0)*M;
    const float* hHH = h + (size_t)(8+g0)*M;
    const float* fHL = fftHL + (size_t)g0*M;
    DCONVm(hHH, 1, kb, NB);
    DCONVm(hHH, 2, vb, NB);
    ATTNm(hLH, 0, aA, NB);                       // x_HH_LH (== f_HH_LH)
    DCONVm(hHH, 4, kb, NB);
    DCONVm(hHH, 5, vb, NB);
    ATTNm(hHL, 3, aB, NB);                       // x_HH_HL
    ATTNm(fHL, 3, aC, NB);                       // f_HH_HL
    // x_HH2 path
    MCONV(aA, aB, wpkHH, hhb, nullptr, hh1, NB, 2, 1, 0);
    DILm(hh1, 2, dbb + 2*320, NB);
    PEMBEDm(dbuf, cat6 + (size_t)((8+g0)*6)*HWn, NB);
    // f_HH2 path
    MCONV(aA, aC, wpkHH, hhb, nullptr, hh1, NB, 2, 1, 0);
    DILm(hh1, 2, dbb + 2*320, NB);
    PEMBEDm(dbuf, cat6 + (size_t)((8+g0)*6+3)*HWn, NB);
    // x_HL2 / x_LH2
    DILm(hHL, 1, dbb + 320, NB);
    PEMBEDm(dbuf, cat6 + (size_t)(g0*6)*HWn, NB);
    DILm(hLH, 0, dbb, NB);
    PEMBEDm(dbuf, cat6 + (size_t)((4+g0)*6)*HWn, NB);
    // fft_HL / fft_LH passthroughs
    PEMBEDm(fHL, cat6 + (size_t)(g0*6+3)*HWn, NB);
    PEMBEDm(hLH, cat6 + (size_t)((4+g0)*6+3)*HWn, NB);
  }

  // ===== Final conv + residual -> out0 =====
  k_conv3x3s<<<dim3(36, Hn), 128, 0, stream>>>(cat6, cw, cb, xf, out0, 6, 3);
}

// Round 2
// 3465.580 us; speedup vs baseline: 1.1543x; 1.0245x over previous
//
#include <hip/hip_runtime.h>

namespace {

constexpr int Hn = 128, Wn = 128, HWn = 16384, HWFn = 8320;
constexpr float TWOPI = 6.2831853071795864769f;
constexpr float BN_SCALE = 0.99999500003749968f;   // 1/sqrt(1+1e-5)

typedef __attribute__((ext_vector_type(8))) short short8;
typedef __attribute__((ext_vector_type(4))) float float4v;

__device__ __forceinline__ short f2bf(float v){
  unsigned u = __float_as_uint(v);
  u += 0x7FFF + ((u >> 16) & 1);          // RNE
  return (short)(u >> 16);
}

// ---------- weight pack to MFMA A-frag order (bf16) ----------
__global__ void k_pack(const float* __restrict__ w, unsigned short* __restrict__ o,
                       int Cin, int csz, int n){
  int idx = blockIdx.x*256 + threadIdx.x;
  if (idx >= n) return;
  int ck = idx / csz;
  int i  = idx - ck*csz;
  const float* wp = w + (size_t)ck*csz;
  int j = i & 7, lane = (i>>3)&63, mt = (i>>9)&3, p = i>>11;
  int blk = p/18, r = p - blk*18, tap = r>>1, ks = r&1;
  int co = mt*16 + (lane & 15);
  int ci = blk*64 + ks*32 + ((lane>>4)<<3) + j;
  o[idx] = (unsigned short)f2bf(wp[((size_t)co*Cin + ci)*9 + tap]);
}

// ---------- MFMA 3x3 conv: Cout=64, one output row per WG ----------
constexpr int XST = 72;
__global__ __launch_bounds__(256) void k_mconv(
    const float* __restrict__ in, const float* __restrict__ in2,
    const unsigned short* __restrict__ wpk, const float* __restrict__ bias,
    const float* __restrict__ res, float* __restrict__ out,
    int nblk, int dl, int leaky){
  __shared__ short lds[3*134*XST];
  int b = blockIdx.x >> 7, y = blockIdx.x & 127;
  int tid = threadIdx.x;
  int wv = tid >> 6, lane = tid & 63;
  int nq = lane >> 4, nr = lane & 15;
  float4v acc[4][2];
  #pragma unroll
  for (int mt=0; mt<4; mt++)
    #pragma unroll
    for (int nt=0; nt<2; nt++) acc[mt][nt] = (float4v){0.f,0.f,0.f,0.f};

  for (int blk=0; blk<nblk; blk++){
    const float* src = blk ? in2 : in;
    __syncthreads();
    for (int e = tid; e < 3*64*134; e += 256){
      int dy = e / (64*134); int r = e - dy*64*134;
      int ci = r / 134;      int x = r - ci*134;
      int yy = y + (dy-1)*dl;
      int xx = x - 3;
      float v = 0.f;
      if (yy >= 0 && yy < Hn && xx >= 0 && xx < Wn)
        v = src[(((size_t)b*64 + ci)*Hn + yy)*Wn + xx];
      lds[(dy*134 + x)*XST + ci] = f2bf(v);
    }
    __syncthreads();
    const unsigned short* wb = wpk + (size_t)blk*36864;
    for (int tap=0; tap<9; tap++){
      int dy = tap/3, dx = tap - (tap/3)*3;
      #pragma unroll
      for (int ks=0; ks<2; ks++){
        short8 a[4];
        #pragma unroll
        for (int mt=0; mt<4; mt++)
          a[mt] = *(const short8*)(wb + (((size_t)(tap*2+ks)*4+mt)<<9) + ((size_t)lane<<3));
        #pragma unroll
        for (int nt=0; nt<2; nt++){
          int x = wv*32 + nt*16 + nr + (dx-1)*dl + 3;
          short8 bf = *(const short8*)&lds[(dy*134 + x)*XST + ks*32 + nq*8];
          #pragma unroll
          for (int mt=0; mt<4; mt++)
            acc[mt][nt] = __builtin_amdgcn_mfma_f32_16x16x32_bf16(a[mt], bf, acc[mt][nt], 0, 0, 0);
        }
      }
    }
  }
  #pragma unroll
  for (int mt=0; mt<4; mt++)
  #pragma unroll
  for (int nt=0; nt<2; nt++){
    int x = wv*32 + nt*16 + nr;
    #pragma unroll
    for (int r2=0; r2<4; r2++){
      int co = mt*16 + nq*4 + r2;
      float a = acc[mt][nt][r2] + (bias ? bias[co] : 0.f);
      if (leaky) a = (a >= 0.f) ? a : 0.01f*a;
      size_t idx = (((size_t)b*64 + co)*Hn + y)*Wn + x;
      if (res) a += res[idx];
      out[idx] = a;
    }
  }
}

// ---------- depthwise 3x3, pad 1 ----------
__global__ void k_dw3x3(const float* __restrict__ in, const float* __restrict__ w,
                        const float* __restrict__ bias, float* __restrict__ out, int C){
  int bc = blockIdx.x; int y = blockIdx.y; int x = threadIdx.x;
  int c = bc % C;
  const float* ip = in + (size_t)bc*HWn;
  const float* wp = w + c*9;
  float acc = bias ? bias[c] : 0.f;
  #pragma unroll
  for (int ky=0; ky<3; ky++){
    int yy = y + ky - 1; if (yy < 0 || yy >= Hn) continue;
    #pragma unroll
    for (int kx=0; kx<3; kx++){
      int xx = x + kx - 1; if (xx < 0 || xx >= Wn) continue;
      acc = fmaf(ip[yy*Wn+xx], wp[ky*3+kx], acc);
    }
  }
  out[(size_t)bc*HWn + y*Wn + x] = acc;
}

// ---------- pointwise 1x1, register-tiled ----------
template<int CT>
__global__ void k_pwt(const float* __restrict__ in, const float* __restrict__ wg,
                      const float* __restrict__ bias, const float* __restrict__ bng,
                      const float* __restrict__ bnb, float* __restrict__ out,
                      int Cin, int Cout, int npix, int inb, int outb, int post, float slope){
  extern __shared__ float wsm[];
  int nt = (Cout + CT - 1)/CT;
  int b = blockIdx.x / nt, t = blockIdx.x - b*nt;
  int co0 = t*CT;
  for (int i = threadIdx.x; i < CT*Cin; i += 256){
    int co = i / Cin;
    wsm[i] = (co0 + co < Cout) ? wg[(size_t)(co0+co)*Cin + (i - co*Cin)] : 0.f;
  }
  __syncthreads();
  int p = blockIdx.y*256 + threadIdx.x;
  if (p >= npix) return;
  const float* ip = in + (size_t)b*inb + p;
  float acc[CT];
  #pragma unroll
  for (int j=0; j<CT; j++) acc[j] = 0.f;
  for (int ci=0; ci<Cin; ci++){
    float v = ip[(size_t)ci*npix];
    #pragma unroll
    for (int j=0; j<CT; j++) acc[j] = fmaf(v, wsm[j*Cin+ci], acc[j]);
  }
  #pragma unroll
  for (int j=0; j<CT; j++){
    int co = co0 + j;
    if (co < Cout){
      float a = acc[j] + (bias ? bias[co] : 0.f);
      if (bng) a = a*(bng[co]*BN_SCALE) + bnb[co];
      if (post == 1) a = fminf(fmaxf(a, -1.f), 1.f);
      else if (post == 2) a = a*fminf(fmaxf(a+3.f, 0.f), 6.f)*(1.f/6.f);
      else if (post == 3) a = (a >= 0.f) ? a : a*slope;
      out[(size_t)b*outb + (size_t)co*npix + p] = a;
    }
  }
}

// ---------- deformable depthwise 3x3 ----------
__global__ void k_deform(const float* __restrict__ x, const float* __restrict__ off,
                         const float* __restrict__ w, float* __restrict__ out, int C){
  int bc = blockIdx.x; int b = bc / C; int c = bc - b*C;
  int y = blockIdx.y; int x0 = threadIdx.x;
  const float* xp = x + (size_t)bc*HWn;
  const float* op = off + (size_t)b*18*HWn + y*Wn + x0;
  const float* wp = w + c*9;
  float acc = 0.f;
  #pragma unroll
  for (int k=0; k<9; k++){
    int ky = k/3 - 1, kx = k - (k/3)*3 - 1;
    float oy = op[(size_t)(2*k)*HWn];
    float ox = op[(size_t)(2*k+1)*HWn];
    float py = (float)y + (float)ky + oy;
    float px = (float)x0 + (float)kx + ox;
    float fy = floorf(py), fx = floorf(px);
    float wy = py - fy, wx = px - fx;
    int y0 = (int)fy, xx0 = (int)fx;
    float val = 0.f;
    #pragma unroll
    for (int dy=0; dy<2; dy++){
      int iy = y0 + dy; if (iy < 0 || iy >= Hn) continue;
      float wyv = dy ? wy : (1.f - wy);
      #pragma unroll
      for (int dx=0; dx<2; dx++){
        int ix = xx0 + dx; if (ix < 0 || ix >= Wn) continue;
        float wxv = dx ? wx : (1.f - wx);
        val = fmaf(xp[iy*Wn+ix], wyv*wxv, val);
      }
    }
    acc = fmaf(val, wp[k], acc);
  }
  out[(size_t)bc*HWn + y*Wn + x0] = acc;
}

// ---------- small direct conv (final 6->3) ----------
__global__ void k_conv3x3s(const float* __restrict__ in, const float* __restrict__ wgt,
                           const float* __restrict__ bias, const float* __restrict__ res,
                           float* __restrict__ out, int Cin, int Cout){
  int g = blockIdx.x;
  int b = g / Cout; int o0 = g - b*Cout;
  int y = blockIdx.y, x = threadIdx.x;
  float acc = bias ? bias[o0] : 0.f;
  for (int ci=0; ci<Cin; ci++){
    const float* iip = in + ((size_t)b*Cin + ci)*HWn;
    const float* wp = wgt + ((size_t)o0*Cin + ci)*9;
    #pragma unroll
    for (int ky=0; ky<3; ky++){
      int yy = y + ky - 1; if (yy < 0 || yy >= Hn) continue;
      #pragma unroll
      for (int kx=0; kx<3; kx++){
        int xx = x + kx - 1; if (xx < 0 || xx >= Wn) continue;
        acc = fmaf(iip[yy*Wn+xx], wp[ky*3+kx], acc);
      }
    }
  }
  size_t idx = ((size_t)b*Cout + o0)*HWn + y*Wn + x;
  if (res) acc += res[idx];
  out[idx] = acc;
}

// ---------- fused cross-attention: one WG per (b,h) ----------
__global__ __launch_bounds__(256) void k_attn(
    const float* __restrict__ q, const float* __restrict__ k,
    const float* __restrict__ v, float* __restrict__ o){
  __shared__ float qs[64][129];
  __shared__ float ks[64][129];
  __shared__ float vs[64][129];
  __shared__ float ps[64][66];
  int bh = blockIdx.x; int b = bh >> 7, h = bh & 127;
  size_t base = ((size_t)b*64*128 + h)*128;
  int tid = threadIdx.x;
  for (int e = tid; e < 8192; e += 256){
    int c = e >> 7, w = e & 127;
    size_t g = base + (size_t)c*HWn + w;
    qs[c][w] = q[g]; ks[c][w] = k[g]; vs[c][w] = v[g];
  }
  __syncthreads();
  {
    int c0 = (tid >> 4) << 2, d0 = (tid & 15) << 2;
    float acc[4][4];
    #pragma unroll
    for (int a=0; a<4; a++)
      #pragma unroll
      for (int bb=0; bb<4; bb++) acc[a][bb] = 0.f;
    for (int i=0; i<128; i++){
      float qv[4], kv[4];
      #pragma unroll
      for (int a=0; a<4; a++){ qv[a] = qs[c0+a][i]; kv[a] = ks[d0+a][i]; }
      #pragma unroll
      for (int a=0; a<4; a++)
        #pragma unroll
        for (int bb=0; bb<4; bb++) acc[a][bb] = fmaf(qv[a], kv[bb], acc[a][bb]);
    }
    #pragma unroll
    for (int a=0; a<4; a++)
      #pragma unroll
      for (int bb=0; bb<4; bb++)
        ps[c0+a][d0+bb] = acc[a][bb] * 0.35355339059327373f;
  }
  __syncthreads();
  {
    int wv = tid >> 6, lane = tid & 63;
    for (int it=0; it<16; it++){
      int row = wv*16 + it;
      float vv = ps[row][lane];
      float m = vv;
      #pragma unroll
      for (int off=32; off; off>>=1) m = fmaxf(m, __shfl_xor(m, off));
      float e = expf(vv - m);
      float s = e;
      #pragma unroll
      for (int off=32; off; off>>=1) s += __shfl_xor(s, off);
      ps[row][lane] = e / s;
    }
  }
  __syncthreads();
  {
    int c0 = (tid >> 4) << 2, w0 = (tid & 15) << 3;
    float acc[4][8];
    #pragma unroll
    for (int a=0; a<4; a++)
      #pragma unroll
      for (int j=0; j<8; j++) acc[a][j] = 0.f;
    for (int d=0; d<64; d++){
      float pv[4], vv[8];
      #pragma unroll
      for (int a=0; a<4; a++) pv[a] = ps[c0+a][d];
      #pragma unroll
      for (int j=0; j<8; j++) vv[j] = vs[d][w0+j];
      #pragma unroll
      for (int a=0; a<4; a++)
        #pragma unroll
        for (int j=0; j<8; j++) acc[a][j] = fmaf(pv[a], vv[j], acc[a][j]);
    }
    #pragma unroll
    for (int a=0; a<4; a++)
      #pragma unroll
      for (int j=0; j<8; j++)
        o[base + (size_t)(c0+a)*HWn + w0 + j] = acc[a][j];
  }
}

// ============ wave-level 128-pt FFT (no barriers, register-resident) ============
// Lane l holds points i=l (z0) and i=64+l (z1). DIF radix-2, output bit-reversed,
// then wreorder() undoes bit-reversal via lane permutation.
// twl[s] = e^{sgn*2*pi*i*((l&(2^s-1))<<(6-s))/128}, sgn=-1 fwd / +1 inv.

__device__ __forceinline__ float2 cmul(float2 a, float2 b){
  return make_float2(a.x*b.x - a.y*b.y, a.x*b.y + a.y*b.x);
}

__device__ __forceinline__ void wfft(float2& z0, float2& z1, const float2* twl, int l){
  // s=6: pair (l, 64+l) in-register
  {
    float dx = z0.x - z1.x, dy = z0.y - z1.y;
    z0.x += z1.x; z0.y += z1.y;
    z1 = cmul(make_float2(dx, dy), twl[6]);
  }
  #pragma unroll
  for (int s = 5; s >= 0; --s){
    int h = 1 << s;
    bool up = (l & h) != 0;
    float2 w = twl[s];
    {
      float ox = __shfl_xor(z0.x, h), oy = __shfl_xor(z0.y, h);
      float sx = up ? ox - z0.x : z0.x + ox;
      float sy = up ? oy - z0.y : z0.y + oy;
      float2 t = cmul(make_float2(sx, sy), w);
      z0.x = up ? t.x : sx;  z0.y = up ? t.y : sy;
    }
    {
      float ox = __shfl_xor(z1.x, h), oy = __shfl_xor(z1.y, h);
      float sx = up ? ox - z1.x : z1.x + ox;
      float sy = up ? oy - z1.y : z1.y + oy;
      float2 t = cmul(make_float2(sx, sy), w);
      z1.x = up ? t.x : sx;  z1.y = up ? t.y : sy;
    }
  }
}

// bit-reversed regs -> natural order: n0 = X[l], n1 = X[64+l]
__device__ __forceinline__ void wreorder(float2 z0, float2 z1, float2& n0, float2& n1, int l){
  int a = (int)(__brev((unsigned)(l >> 1)) >> 26);   // brev6(l>>1), even
  float p0x = __shfl(z0.x, a),   p0y = __shfl(z0.y, a);
  float p1x = __shfl(z1.x, a),   p1y = __shfl(z1.y, a);
  float q0x = __shfl(z0.x, a+1), q0y = __shfl(z0.y, a+1);
  float q1x = __shfl(z1.x, a+1), q1y = __shfl(z1.y, a+1);
  bool odd = (l & 1) != 0;
  n0 = odd ? make_float2(p1x, p1y) : make_float2(p0x, p0y);
  n1 = odd ? make_float2(q1x, q1y) : make_float2(q0x, q0y);
}

// ---------- fused rfft2 + mag/pha: one WG per image plane ----------
// x: [B*64][128][128]; mag/pha: [B][128ch][8320], write ch 0..63
__global__ __launch_bounds__(256) void k_fft2(
    const float* __restrict__ x, float* __restrict__ mag, float* __restrict__ pha){
  __shared__ float2 sp[8320];          // [row 0..127][col 0..64], stride 65 (66.5 KiB)
  int img = blockIdx.x;
  int tid = threadIdx.x;
  int wv = tid >> 6, l = tid & 63;
  float2 twl[7];
  #pragma unroll
  for (int s = 0; s < 7; ++s){
    int jh = (l & ((1 << s) - 1)) << (6 - s);
    float sv, cv; sincosf(-TWOPI * (float)jh * (1.f/128.f), &sv, &cv);
    twl[s] = make_float2(cv, sv);
  }
  // row FFTs: pack rows (2f, 2f+1) as complex, wave-local FFT, Hermitian unpack
  const float* xp = x + (size_t)img*HWn;
  for (int f = wv; f < 64; f += 4){
    const float* r0 = xp + (2*f)*Wn;
    const float* r1 = xp + (2*f+1)*Wn;
    float2 z0 = make_float2(r0[l],      r1[l]);
    float2 z1 = make_float2(r0[64 + l], r1[64 + l]);
    wfft(z0, z1, twl, l);
    float2 n0, n1; wreorder(z0, z1, n0, n1, l);
    // Zn = Z[(128-l)&127]
    float zhx = __shfl(n1.x, (64 - l) & 63);
    float zhy = __shfl(n1.y, (64 - l) & 63);
    float2 Zn = (l == 0) ? n0 : make_float2(zhx, zhy);
    float2 A  = make_float2(0.5f*(n0.x + Zn.x), 0.5f*(n0.y - Zn.y));
    float2 Bv = make_float2(0.5f*(n0.y + Zn.y), 0.5f*(Zn.x - n0.x));
    sp[(2*f)*65 + l]   = A;
    sp[(2*f+1)*65 + l] = Bv;
    if (l == 0){
      sp[(2*f)*65 + 64]   = make_float2(n1.x, 0.f);
      sp[(2*f+1)*65 + 64] = make_float2(n1.y, 0.f);
    }
  }
  __syncthreads();
  // column FFTs (wave-local, in place) + mag/pha
  for (int c = wv; c < 65; c += 4){
    float2 z0 = sp[l*65 + c];
    float2 z1 = sp[(64 + l)*65 + c];
    wfft(z0, z1, twl, l);
    float2 n0, n1; wreorder(z0, z1, n0, n1, l);
    sp[l*65 + c]        = make_float2(sqrtf(n0.x*n0.x + n0.y*n0.y), atan2f(n0.y, n0.x));
    sp[(64 + l)*65 + c] = make_float2(sqrtf(n1.x*n1.x + n1.y*n1.y), atan2f(n1.y, n1.x));
  }
  __syncthreads();
  // coalesced copy-out: sp[i] is exactly [kk][w] at i = kk*65+w
  int b = img >> 6, ch = img & 63;
  float* mp = mag + ((size_t)b*128 + ch)*HWFn;
  float* pp = pha + ((size_t)b*128 + ch)*HWFn;
  for (int i = tid; i < 8320; i += 256){
    float2 v = sp[i];
    mp[i] = v.x; pp[i] = v.y;
  }
}

// ---------- fused irfft2 + residual add: one WG per image plane (256 imgs) ----------
// mo/po: [256 img][8320] (= out1/out2 head); hsrc/outp: [256 img][16384]
__global__ __launch_bounds__(256) void k_ifft2(
    const float* __restrict__ mo, const float* __restrict__ po,
    const float* __restrict__ hsrc, float* __restrict__ outp){
  __shared__ float2 sp[8320];          // [kk][w], stride 65
  int img = blockIdx.x;
  int tid = threadIdx.x;
  int wv = tid >> 6, l = tid & 63;
  float2 twl[7];
  #pragma unroll
  for (int s = 0; s < 7; ++s){
    int jh = (l & ((1 << s) - 1)) << (6 - s);
    float sv, cv; sincosf(TWOPI * (float)jh * (1.f/128.f), &sv, &cv);   // inverse
    twl[s] = make_float2(cv, sv);
  }
  const float* mp = mo + (size_t)img*HWFn;
  const float* pp = po + (size_t)img*HWFn;
  for (int i = tid; i < 8320; i += 256){
    float m = mp[i], p = pp[i];
    float sv, cv; sincosf(p, &sv, &cv);
    sp[i] = make_float2(m*cv, m*sv);
  }
  __syncthreads();
  // column inverse (wave-local, in place): g[hh][w]
  for (int c = wv; c < 65; c += 4){
    float2 z0 = sp[l*65 + c];
    float2 z1 = sp[(64 + l)*65 + c];
    wfft(z0, z1, twl, l);
    float2 n0, n1; wreorder(z0, z1, n0, n1, l);
    sp[l*65 + c]        = n0;
    sp[(64 + l)*65 + c] = n1;
  }
  __syncthreads();
  // row inverse c2r (packed pairs) + residual add
  const float scl = 1.f/16384.f;
  for (int f = wv; f < 64; f += 4){
    float2 A  = sp[(2*f)*65 + l];
    float2 Bv = sp[(2*f+1)*65 + l];
    if (l == 0){ A.y = 0.f; Bv.y = 0.f; }            // c2r drops Im at k=0
    float2 z0 = make_float2(A.x - Bv.y, A.y + Bv.x); // Z[l] = A + iB
    int lm = 64 - l;                                  // l=0 -> k=64 slot
    float2 Am = sp[(2*f)*65 + lm];
    float2 Bm = sp[(2*f+1)*65 + lm];
    float2 z1 = (l == 0) ? make_float2(Am.x, Bm.x)                    // Z[64], Im dropped
                         : make_float2(Am.x + Bm.y, Bm.x - Am.y);     // conj-extension
    wfft(z0, z1, twl, l);
    float2 n0, n1; wreorder(z0, z1, n0, n1, l);
    size_t g0 = (size_t)img*HWn + (size_t)(2*f)*Wn + l;
    size_t g1 = g0 + Wn;
    outp[g0]      = n0.x*scl + hsrc[g0];
    outp[g0 + 64] = n1.x*scl + hsrc[g0 + 64];
    outp[g1]      = n0.y*scl + hsrc[g1];
    outp[g1 + 64] = n1.y*scl + hsrc[g1 + 64];
  }
}

} // namespace

extern "C" void kernel_launch(void* const* d_in, const int* in_sizes, int n_in,
                              void* d_out, int out_size, void* d_ws, size_t ws_size,
                              hipStream_t stream){
  const float *xf   =(const float*)d_in[0],  *chodw=(const float*)d_in[1],
              *chopw=(const float*)d_in[2],  *chdcn=(const float*)d_in[3],
              *chpw =(const float*)d_in[4],  *ctodw=(const float*)d_in[5],
              *ctopw=(const float*)d_in[6],  *ctdcn=(const float*)d_in[7],
              *ctpw =(const float*)d_in[8],  *dbw  =(const float*)d_in[9],
              *dbb  =(const float*)d_in[10], *cadw =(const float*)d_in[11],
              *cadb =(const float*)d_in[12], *capw =(const float*)d_in[13],
              *capb =(const float*)d_in[14], *hhw  =(const float*)d_in[15],
              *hhb  =(const float*)d_in[16], *fd1w =(const float*)d_in[17],
              *fd2w =(const float*)d_in[18], *fd1g =(const float*)d_in[19],
              *fd1bt=(const float*)d_in[20], *fd2g =(const float*)d_in[21],
              *fd2bt=(const float*)d_in[22], *fcw  =(const float*)d_in[23],
              *cw   =(const float*)d_in[24], *cb   =(const float*)d_in[25];

  constexpr size_t M = 1048576;            // one batch x 64ch x HW (floats)
  float* ws = (float*)d_ws;
  float* h     = ws;                       // 12*M
  float* fftHL = ws + 12*M;                // 4*M
  float* cat6  = ws + 16*M;                // 1,179,648
  unsigned short* wpkDB = (unsigned short*)(cat6 + 1179648);
  unsigned short* wpkHH = wpkDB + 552960;
  float* P = cat6 + 1179648 + 313344;      // pool

  const int NB = (ws_size >= 266018816ull) ? 4 : 1;
  const size_t S = (size_t)NB*M;
  float* kb  = P;        float* vb  = P + S;   float* qb  = P + 2*S;
  float* qs  = P + 3*S;  float* aA  = P + 4*S; float* aB  = P + 5*S;
  float* aC  = P + 6*S;  float* hh1 = P + 7*S; float* sA  = P + 8*S;
  float* sB  = P + 9*S;  float* dbuf= P + 10*S;
  float* X   = P + 11*S;
  // phase-1 aliases
  float* dwb3 = P; float* offb12 = P + 589824; float* yb3 = P + 4128768;

  float* out = (float*)d_out;
  float* out0 = out;
  float* out1 = out + 589824;
  float* out2 = out + 589824 + 6389760;

  auto PW = [&](const float* in, const float* wg, const float* bi, const float* g, const float* bt,
                float* o, int B, int Ci, int Co, int npix, int inb, int outb, int post, float slope){
    int py = (npix + 255)/256;
    if (Co > 32){
      k_pwt<32><<<dim3(B*2, py), 256, 32*Ci*4, stream>>>(in, wg, bi, g, bt, o, Ci, Co, npix, inb, outb, post, slope);
    } else if (Co > 18){
      k_pwt<32><<<dim3(B, py), 256, 32*Ci*4, stream>>>(in, wg, bi, g, bt, o, Ci, Co, npix, inb, outb, post, slope);
    } else if (Co > 3){
      k_pwt<18><<<dim3(B, py), 256, 18*Ci*4, stream>>>(in, wg, bi, g, bt, o, Ci, Co, npix, inb, outb, post, slope);
    } else {
      k_pwt<3><<<dim3(B, py), 256, 3*Ci*4, stream>>>(in, wg, bi, g, bt, o, Ci, Co, npix, inb, outb, post, slope);
    }
  };
  auto MCONV = [&](const float* in, const float* in2, const unsigned short* wp, const float* bi,
                   const float* res, float* o, int B, int nblk, int dl, int lk){
    k_mconv<<<B*128, 256, 0, stream>>>(in, in2, wp, bi, res, o, nblk, dl, lk);
  };
  auto DILm = [&](const float* in, int set, const float* bset, int B){
    const unsigned short* w5 = wpkDB + (size_t)set*5*36864;
    MCONV(in, nullptr, w5,          bset,      nullptr, sA,   B, 1, 1, 1);
    MCONV(sA, nullptr, w5+36864,    bset+64,   nullptr, sB,   B, 1, 2, 1);
    MCONV(sB, nullptr, w5+2*36864,  bset+128,  nullptr, sA,   B, 1, 3, 1);
    MCONV(sA, nullptr, w5+3*36864,  bset+192,  nullptr, sB,   B, 1, 2, 1);
    MCONV(sB, nullptr, w5+4*36864,  bset+256,  in,      dbuf, B, 1, 1, 0);
  };
  auto DCONVm = [&](const float* in, int idx, float* o, int B){
    k_dw3x3<<<dim3(B*64, Hn), 128, 0, stream>>>(in, cadw + idx*576, cadb + idx*64, qs, 64);
    PW(qs, capw + (size_t)idx*4096, capb + idx*64, nullptr, nullptr, o, B, 64, 64, HWn, 64*HWn, 64*HWn, 0, 0.f);
  };
  auto ATTNm = [&](const float* qsrc, int qidx, float* o, int B){
    DCONVm(qsrc, qidx, qb, B);
    k_attn<<<B*128, 256, 0, stream>>>(qb, kb, vb, o);
  };
  auto PEMBEDm = [&](const float* in, float* outSlice, int B){
    k_dw3x3<<<dim3(B*64, Hn), 128, 0, stream>>>(in, ctodw, nullptr, qs, 64);
    PW(qs, ctopw, nullptr, nullptr, nullptr, X, B, 64, 18, HWn, 64*HWn, 18*HWn, 1, 0.f);
    k_deform<<<dim3(B*64, Hn), 128, 0, stream>>>(in, X, ctdcn, qs, 64);
    PW(qs, ctpw, nullptr, nullptr, nullptr, outSlice, B, 64, 3, HWn, 64*HWn, 6*HWn, 2, 0.f);
  };

  // ===== Pack conv weights (2 launches) =====
  k_pack<<<(552960 + 255)/256, 256, 0, stream>>>(dbw, wpkDB, 64, 36864, 552960);
  k_pack<<<288, 256, 0, stream>>>(hhw, wpkHH, 128, 73728, 73728);

  // ===== Phase 1: patch_embed(ch) -> h =====
  k_dw3x3<<<dim3(36, Hn), 128, 0, stream>>>(xf, chodw, nullptr, dwb3, 3);
  PW(dwb3, chopw, nullptr, nullptr, nullptr, offb12, 12, 3, 18, HWn, 3*HWn, 18*HWn, 1, 0.f);
  k_deform<<<dim3(36, Hn), 128, 0, stream>>>(xf, offb12, chdcn, yb3, 3);
  PW(yb3, chpw, nullptr, nullptr, nullptr, h, 12, 3, 64, HWn, 3*HWn, 64*HWn, 2, 0.f);

  // ===== Phase 2: fft_block (wave-register 2-D FFT) =====
  if (NB == 4){
    float* mB = P;                 // [12][128][8320]
    float* pB = P + 12779520;
    k_fft2<<<768, 256, 0, stream>>>(h, mB, pB);
    PW(mB, fd1w, nullptr, fd1g, fd1bt, mB + 64*HWFn, 12, 64, 32, HWFn, 128*HWFn, 128*HWFn, 3, 0.1f);
    PW(mB, fd2w, nullptr, fd2g, fd2bt, mB + 96*HWFn, 12, 96, 32, HWFn, 128*HWFn, 128*HWFn, 3, 0.1f);
    PW(mB, fcw,  nullptr, nullptr, nullptr, out1,    12, 128, 64, HWFn, 128*HWFn, 64*HWFn, 0, 0.f);
    PW(pB, fd1w+2048, nullptr, fd1g+32, fd1bt+32, pB + 64*HWFn, 12, 64, 32, HWFn, 128*HWFn, 128*HWFn, 3, 0.1f);
    PW(pB, fd2w+3072, nullptr, fd2g+32, fd2bt+32, pB + 96*HWFn, 12, 96, 32, HWFn, 128*HWFn, 128*HWFn, 3, 0.1f);
    PW(pB, fcw+8192,  nullptr, nullptr, nullptr,  out2, 12, 128, 64, HWFn, 128*HWFn, 64*HWFn, 0, 0.f);
    k_ifft2<<<256, 256, 0, stream>>>(out1, out2, h, fftHL);
  } else {
    // 3 chunks of 4 batches
    float* mB = P;                 // [4][128][8320]
    float* pB = P + 4259840;
    for (int c=0; c<3; c++){
      const float* hsrc = h + (size_t)c*4*M;
      float* o1 = out1 + (size_t)c*2129920;
      float* o2 = out2 + (size_t)c*2129920;
      k_fft2<<<256, 256, 0, stream>>>(hsrc, mB, pB);
      PW(mB, fd1w, nullptr, fd1g, fd1bt, mB + 64*HWFn, 4, 64, 32, HWFn, 128*HWFn, 128*HWFn, 3, 0.1f);
      PW(mB, fd2w, nullptr, fd2g, fd2bt, mB + 96*HWFn, 4, 96, 32, HWFn, 128*HWFn, 128*HWFn, 3, 0.1f);
      PW(mB, fcw,  nullptr, nullptr, nullptr, o1,      4, 128, 64, HWFn, 128*HWFn, 64*HWFn, 0, 0.f);
      PW(pB, fd1w+2048, nullptr, fd1g+32, fd1bt+32, pB + 64*HWFn, 4, 64, 32, HWFn, 128*HWFn, 128*HWFn, 3, 0.1f);
      PW(pB, fd2w+3072, nullptr, fd2g+32, fd2bt+32, pB + 96*HWFn, 4, 96, 32, HWFn, 128*HWFn, 128*HWFn, 3, 0.1f);
      PW(pB, fcw+8192,  nullptr, nullptr, nullptr,  o2, 4, 128, 64, HWFn, 128*HWFn, 64*HWFn, 0, 0.f);
      if (c == 0)
        k_ifft2<<<256, 256, 0, stream>>>(out1, out2, h, fftHL);
    }
  }

  // ===== Phases 3-5 in groups of NB batches =====
  for (int g0=0; g0<4; g0+=NB){
    const float* hHL = h + (size_t)g0*M;
    const float* hLH = h + (size_t)(4+g0)*M;
    const float* hHH = h + (size_t)(8+g0)*M;
    const float* fHL = fftHL + (size_t)g0*M;
    DCONVm(hHH, 1, kb, NB);
    DCONVm(hHH, 2, vb, NB);
    ATTNm(hLH, 0, aA, NB);                       // x_HH_LH (== f_HH_LH)
    DCONVm(hHH, 4, kb, NB);
    DCONVm(hHH, 5, vb, NB);
    ATTNm(hHL, 3, aB, NB);                       // x_HH_HL
    ATTNm(fHL, 3, aC, NB);                       // f_HH_HL
    // x_HH2 path
    MCONV(aA, aB, wpkHH, hhb, nullptr, hh1, NB, 2, 1, 0);
    DILm(hh1, 2, dbb + 2*320, NB);
    PEMBEDm(dbuf, cat6 + (size_t)((8+g0)*6)*HWn, NB);
    // f_HH2 path
    MCONV(aA, aC, wpkHH, hhb, nullptr, hh1, NB, 2, 1, 0);
    DILm(hh1, 2, dbb + 2*320, NB);
    PEMBEDm(dbuf, cat6 + (size_t)((8+g0)*6+3)*HWn, NB);
    // x_HL2 / x_LH2
    DILm(hHL, 1, dbb + 320, NB);
    PEMBEDm(dbuf, cat6 + (size_t)(g0*6)*HWn, NB);
    DILm(hLH, 0, dbb, NB);
    PEMBEDm(dbuf, cat6 + (size_t)((4+g0)*6)*HWn, NB);
    // fft_HL / fft_LH passthroughs
    PEMBEDm(fHL, cat6 + (size_t)(g0*6+3)*HWn, NB);
    PEMBEDm(hLH, cat6 + (size_t)((4+g0)*6+3)*HWn, NB);
  }

  // ===== Final conv + residual -> out0 =====
  k_conv3x3s<<<dim3(36, Hn), 128, 0, stream>>>(cat6, cw, cb, xf, out0, 6, 3);
}

// Round 3
// 3445.758 us; speedup vs baseline: 1.1609x; 1.0058x over previous
//
#include <hip/hip_runtime.h>

namespace {

constexpr int Hn = 128, Wn = 128, HWn = 16384, HWFn = 8320;
constexpr float TWOPI = 6.2831853071795864769f;
constexpr float BN_SCALE = 0.99999500003749968f;   // 1/sqrt(1+1e-5)

typedef __attribute__((ext_vector_type(8))) short short8;
typedef __attribute__((ext_vector_type(4))) float float4v;

__device__ __forceinline__ short f2bf(float v){
  unsigned u = __float_as_uint(v);
  u += 0x7FFF + ((u >> 16) & 1);          // RNE
  return (short)(u >> 16);
}

// ---------- weight pack to MFMA A-frag order (bf16), 3x3 convs ----------
__global__ void k_pack(const float* __restrict__ w, unsigned short* __restrict__ o,
                       int Cin, int csz, int n){
  int idx = blockIdx.x*256 + threadIdx.x;
  if (idx >= n) return;
  int ck = idx / csz;
  int i  = idx - ck*csz;
  const float* wp = w + (size_t)ck*csz;
  int j = i & 7, lane = (i>>3)&63, mt = (i>>9)&3, p = i>>11;
  int blk = p/18, r = p - blk*18, tap = r>>1, ks = r&1;
  int co = mt*16 + (lane & 15);
  int ci = blk*64 + ks*32 + ((lane>>4)<<3) + j;
  o[idx] = (unsigned short)f2bf(wp[((size_t)co*Cin + ci)*9 + tap]);
}

// ---------- weight pack for 1x1 (Cin=64): blocks ordered ks*MT+mt ----------
__global__ void k_packpw(const float* __restrict__ w, unsigned short* __restrict__ o,
                         int Cout, int MT, int n){
  int i = blockIdx.x*256 + threadIdx.x;
  if (i >= n) return;
  int per = MT << 10;                 // 2*MT*512
  int set = i / per;
  int r = i - set*per;
  int j = r & 7, lane = (r>>3)&63, blk = r>>9;
  int ks = blk / MT, mt = blk - ks*MT;
  int co = mt*16 + (lane & 15);
  int ci = ks*32 + ((lane>>4)<<3) + j;
  float v = (co < Cout) ? w[(size_t)set*Cout*64 + co*64 + ci] : 0.f;
  o[i] = (unsigned short)f2bf(v);
}

// ---------- MFMA 3x3 conv: Cout=64, one output row per WG ----------
constexpr int XST = 72;
__global__ __launch_bounds__(256) void k_mconv(
    const float* __restrict__ in, const float* __restrict__ in2,
    const unsigned short* __restrict__ wpk, const float* __restrict__ bias,
    const float* __restrict__ res, float* __restrict__ out,
    int nblk, int dl, int leaky){
  __shared__ short lds[3*134*XST];
  int b = blockIdx.x >> 7, y = blockIdx.x & 127;
  int tid = threadIdx.x;
  int wv = tid >> 6, lane = tid & 63;
  int nq = lane >> 4, nr = lane & 15;
  float4v acc[4][2];
  #pragma unroll
  for (int mt=0; mt<4; mt++)
    #pragma unroll
    for (int nt=0; nt<2; nt++) acc[mt][nt] = (float4v){0.f,0.f,0.f,0.f};

  for (int blk=0; blk<nblk; blk++){
    const float* src = blk ? in2 : in;
    __syncthreads();
    for (int e = tid; e < 3*64*134; e += 256){
      int dy = e / (64*134); int r = e - dy*64*134;
      int ci = r / 134;      int x = r - ci*134;
      int yy = y + (dy-1)*dl;
      int xx = x - 3;
      float v = 0.f;
      if (yy >= 0 && yy < Hn && xx >= 0 && xx < Wn)
        v = src[(((size_t)b*64 + ci)*Hn + yy)*Wn + xx];
      lds[(dy*134 + x)*XST + ci] = f2bf(v);
    }
    __syncthreads();
    const unsigned short* wb = wpk + (size_t)blk*36864;
    for (int tap=0; tap<9; tap++){
      int dy = tap/3, dx = tap - (tap/3)*3;
      #pragma unroll
      for (int ks=0; ks<2; ks++){
        short8 a[4];
        #pragma unroll
        for (int mt=0; mt<4; mt++)
          a[mt] = *(const short8*)(wb + (((size_t)(tap*2+ks)*4+mt)<<9) + ((size_t)lane<<3));
        #pragma unroll
        for (int nt=0; nt<2; nt++){
          int x = wv*32 + nt*16 + nr + (dx-1)*dl + 3;
          short8 bf = *(const short8*)&lds[(dy*134 + x)*XST + ks*32 + nq*8];
          #pragma unroll
          for (int mt=0; mt<4; mt++)
            acc[mt][nt] = __builtin_amdgcn_mfma_f32_16x16x32_bf16(a[mt], bf, acc[mt][nt], 0, 0, 0);
        }
      }
    }
  }
  #pragma unroll
  for (int mt=0; mt<4; mt++)
  #pragma unroll
  for (int nt=0; nt<2; nt++){
    int x = wv*32 + nt*16 + nr;
    #pragma unroll
    for (int r2=0; r2<4; r2++){
      int co = mt*16 + nq*4 + r2;
      float a = acc[mt][nt][r2] + (bias ? bias[co] : 0.f);
      if (leaky) a = (a >= 0.f) ? a : 0.01f*a;
      size_t idx = (((size_t)b*64 + co)*Hn + y)*Wn + x;
      if (res) a += res[idx];
      out[idx] = a;
    }
  }
}

// ---------- fused depthwise 3x3 + pointwise 1x1 (Cin=64) via MFMA ----------
template<int MT>
__global__ __launch_bounds__(256) void k_dwpw(
    const float* __restrict__ in, const float* __restrict__ dww, const float* __restrict__ dwb,
    const unsigned short* __restrict__ pwpk, const float* __restrict__ pwb,
    float* __restrict__ out, int Cout, size_t outb, int post){
  __shared__ short tb[128*72];       // dw output [x][ci] bf16
  __shared__ float wsm[640];         // dw weights 64*9 + bias 64
  int b = blockIdx.x >> 7, y = blockIdx.x & 127;
  int tid = threadIdx.x;
  for (int i = tid; i < 640; i += 256)
    wsm[i] = (i < 576) ? dww[i] : (dwb ? dwb[i-576] : 0.f);
  __syncthreads();
  for (int e = tid; e < 8192; e += 256){
    int ci = e >> 7, x = e & 127;
    const float* ip = in + ((size_t)b*64 + ci)*HWn;
    const float* wp = wsm + ci*9;
    float acc = wsm[576+ci];
    #pragma unroll
    for (int ky=0; ky<3; ky++){
      int yy = y + ky - 1; if (yy < 0 || yy >= Hn) continue;
      const float* rp = ip + yy*Wn;
      #pragma unroll
      for (int kx=0; kx<3; kx++){
        int xx = x + kx - 1; if (xx < 0 || xx >= Wn) continue;
        acc = fmaf(rp[xx], wp[ky*3+kx], acc);
      }
    }
    tb[x*72 + ci] = f2bf(acc);
  }
  __syncthreads();
  int wv = tid>>6, lane = tid&63, nq = lane>>4, nr = lane&15;
  float4v acc[MT][2];
  #pragma unroll
  for (int mt=0; mt<MT; mt++)
    #pragma unroll
    for (int nt=0; nt<2; nt++) acc[mt][nt] = (float4v){0.f,0.f,0.f,0.f};
  #pragma unroll
  for (int ks=0; ks<2; ks++){
    short8 a[MT];
    #pragma unroll
    for (int mt=0; mt<MT; mt++)
      a[mt] = *(const short8*)(pwpk + ((ks*MT+mt)<<9) + (lane<<3));
    #pragma unroll
    for (int nt=0; nt<2; nt++){
      int x = wv*32 + nt*16 + nr;
      short8 bf = *(const short8*)&tb[x*72 + ks*32 + nq*8];
      #pragma unroll
      for (int mt=0; mt<MT; mt++)
        acc[mt][nt] = __builtin_amdgcn_mfma_f32_16x16x32_bf16(a[mt], bf, acc[mt][nt], 0, 0, 0);
    }
  }
  #pragma unroll
  for (int mt=0; mt<MT; mt++)
  #pragma unroll
  for (int nt=0; nt<2; nt++){
    int x = wv*32 + nt*16 + nr;
    #pragma unroll
    for (int r2=0; r2<4; r2++){
      int co = mt*16 + nq*4 + r2;
      if (co < Cout){
        float a = acc[mt][nt][r2] + (pwb ? pwb[co] : 0.f);
        if (post == 1) a = fminf(fmaxf(a, -1.f), 1.f);
        else if (post == 2) a = a*fminf(fmaxf(a+3.f, 0.f), 6.f)*(1.f/6.f);
        out[(size_t)b*outb + (size_t)co*HWn + y*Wn + x] = a;
      }
    }
  }
}

// ---------- fused deformable dw 3x3 + pointwise 1x1 (64 -> Cout<=16) ----------
__global__ __launch_bounds__(256) void k_defpw(
    const float* __restrict__ xg, const float* __restrict__ off, const float* __restrict__ dcnw,
    const unsigned short* __restrict__ pwpk, float* __restrict__ out,
    int Cout, size_t outb, int post){
  __shared__ short tb[128*72];
  __shared__ float wsm[576];
  int b = blockIdx.x >> 7, y = blockIdx.x & 127;
  int tid = threadIdx.x;
  int px = tid & 127;
  for (int i = tid; i < 576; i += 256) wsm[i] = dcnw[i];
  // per-thread tap precompute (validity folded into weights, indices clamped)
  const float* op = off + (size_t)b*18*HWn + y*Wn + px;
  int r0[9], r1[9], c0[9], c1[9];
  float w00[9], w01[9], w10[9], w11[9];
  #pragma unroll
  for (int k=0; k<9; k++){
    int ky = k/3 - 1, kx = k - (k/3)*3 - 1;
    float oy = op[(size_t)(2*k)*HWn];
    float ox = op[(size_t)(2*k+1)*HWn];
    float py = (float)(y + ky) + oy;
    float pxx = (float)(px + kx) + ox;
    float fy = floorf(py), fx = floorf(pxx);
    float wy = py - fy, wx = pxx - fx;
    int y0 = (int)fy, x0 = (int)fx;
    float vy0 = (y0 >= 0 && y0 < Hn) ? 1.f : 0.f;
    float vy1 = (y0+1 >= 0 && y0+1 < Hn) ? 1.f : 0.f;
    float vx0 = (x0 >= 0 && x0 < Wn) ? 1.f : 0.f;
    float vx1 = (x0+1 >= 0 && x0+1 < Wn) ? 1.f : 0.f;
    w00[k] = (1.f-wy)*(1.f-wx)*vy0*vx0;
    w01[k] = (1.f-wy)*wx*vy0*vx1;
    w10[k] = wy*(1.f-wx)*vy1*vx0;
    w11[k] = wy*wx*vy1*vx1;
    r0[k] = min(max(y0, 0), Hn-1)*Wn;
    r1[k] = min(max(y0+1, 0), Hn-1)*Wn;
    c0[k] = min(max(x0, 0), Wn-1);
    c1[k] = min(max(x0+1, 0), Wn-1);
  }
  __syncthreads();
  for (int ci = tid >> 7; ci < 64; ci += 2){
    const float* xp = xg + ((size_t)b*64 + ci)*HWn;
    float acc = 0.f;
    #pragma unroll
    for (int k=0; k<9; k++){
      float v = w00[k]*xp[r0[k]+c0[k]] + w01[k]*xp[r0[k]+c1[k]]
              + w10[k]*xp[r1[k]+c0[k]] + w11[k]*xp[r1[k]+c1[k]];
      acc = fmaf(v, wsm[ci*9 + k], acc);
    }
    tb[px*72 + ci] = f2bf(acc);
  }
  __syncthreads();
  int wv = tid>>6, lane = tid&63, nq = lane>>4, nr = lane&15;
  float4v acc[2];
  acc[0] = (float4v){0.f,0.f,0.f,0.f};
  acc[1] = (float4v){0.f,0.f,0.f,0.f};
  #pragma unroll
  for (int ks=0; ks<2; ks++){
    short8 a = *(const short8*)(pwpk + (ks<<9) + (lane<<3));
    #pragma unroll
    for (int nt=0; nt<2; nt++){
      int x = wv*32 + nt*16 + nr;
      short8 bf = *(const short8*)&tb[x*72 + ks*32 + nq*8];
      acc[nt] = __builtin_amdgcn_mfma_f32_16x16x32_bf16(a, bf, acc[nt], 0, 0, 0);
    }
  }
  #pragma unroll
  for (int nt=0; nt<2; nt++){
    int x = wv*32 + nt*16 + nr;
    #pragma unroll
    for (int r2=0; r2<4; r2++){
      int co = nq*4 + r2;
      if (co < Cout){
        float a = acc[nt][r2];
        if (post == 2) a = a*fminf(fmaxf(a+3.f, 0.f), 6.f)*(1.f/6.f);
        out[(size_t)b*outb + (size_t)co*HWn + y*Wn + x] = a;
      }
    }
  }
}

// ---------- depthwise 3x3, pad 1 (phase-1, 3ch) ----------
__global__ void k_dw3x3(const float* __restrict__ in, const float* __restrict__ w,
                        const float* __restrict__ bias, float* __restrict__ out, int C){
  int bc = blockIdx.x; int y = blockIdx.y; int x = threadIdx.x;
  int c = bc % C;
  const float* ip = in + (size_t)bc*HWn;
  const float* wp = w + c*9;
  float acc = bias ? bias[c] : 0.f;
  #pragma unroll
  for (int ky=0; ky<3; ky++){
    int yy = y + ky - 1; if (yy < 0 || yy >= Hn) continue;
    #pragma unroll
    for (int kx=0; kx<3; kx++){
      int xx = x + kx - 1; if (xx < 0 || xx >= Wn) continue;
      acc = fmaf(ip[yy*Wn+xx], wp[ky*3+kx], acc);
    }
  }
  out[(size_t)bc*HWn + y*Wn + x] = acc;
}

// ---------- pointwise 1x1, register-tiled ----------
template<int CT>
__global__ void k_pwt(const float* __restrict__ in, const float* __restrict__ wg,
                      const float* __restrict__ bias, const float* __restrict__ bng,
                      const float* __restrict__ bnb, float* __restrict__ out,
                      int Cin, int Cout, int npix, int inb, int outb, int post, float slope){
  extern __shared__ float wsm[];
  int nt = (Cout + CT - 1)/CT;
  int b = blockIdx.x / nt, t = blockIdx.x - b*nt;
  int co0 = t*CT;
  for (int i = threadIdx.x; i < CT*Cin; i += 256){
    int co = i / Cin;
    wsm[i] = (co0 + co < Cout) ? wg[(size_t)(co0+co)*Cin + (i - co*Cin)] : 0.f;
  }
  __syncthreads();
  int p = blockIdx.y*256 + threadIdx.x;
  if (p >= npix) return;
  const float* ip = in + (size_t)b*inb + p;
  float acc[CT];
  #pragma unroll
  for (int j=0; j<CT; j++) acc[j] = 0.f;
  for (int ci=0; ci<Cin; ci++){
    float v = ip[(size_t)ci*npix];
    #pragma unroll
    for (int j=0; j<CT; j++) acc[j] = fmaf(v, wsm[j*Cin+ci], acc[j]);
  }
  #pragma unroll
  for (int j=0; j<CT; j++){
    int co = co0 + j;
    if (co < Cout){
      float a = acc[j] + (bias ? bias[co] : 0.f);
      if (bng) a = a*(bng[co]*BN_SCALE) + bnb[co];
      if (post == 1) a = fminf(fmaxf(a, -1.f), 1.f);
      else if (post == 2) a = a*fminf(fmaxf(a+3.f, 0.f), 6.f)*(1.f/6.f);
      else if (post == 3) a = (a >= 0.f) ? a : a*slope;
      out[(size_t)b*outb + (size_t)co*npix + p] = a;
    }
  }
}

// ---------- deformable depthwise 3x3 (phase-1, 3ch) ----------
__global__ void k_deform(const float* __restrict__ x, const float* __restrict__ off,
                         const float* __restrict__ w, float* __restrict__ out, int C){
  int bc = blockIdx.x; int b = bc / C; int c = bc - b*C;
  int y = blockIdx.y; int x0 = threadIdx.x;
  const float* xp = x + (size_t)bc*HWn;
  const float* op = off + (size_t)b*18*HWn + y*Wn + x0;
  const float* wp = w + c*9;
  float acc = 0.f;
  #pragma unroll
  for (int k=0; k<9; k++){
    int ky = k/3 - 1, kx = k - (k/3)*3 - 1;
    float oy = op[(size_t)(2*k)*HWn];
    float ox = op[(size_t)(2*k+1)*HWn];
    float py = (float)y + (float)ky + oy;
    float px = (float)x0 + (float)kx + ox;
    float fy = floorf(py), fx = floorf(px);
    float wy = py - fy, wx = px - fx;
    int y0 = (int)fy, xx0 = (int)fx;
    float val = 0.f;
    #pragma unroll
    for (int dy=0; dy<2; dy++){
      int iy = y0 + dy; if (iy < 0 || iy >= Hn) continue;
      float wyv = dy ? wy : (1.f - wy);
      #pragma unroll
      for (int dx=0; dx<2; dx++){
        int ix = xx0 + dx; if (ix < 0 || ix >= Wn) continue;
        float wxv = dx ? wx : (1.f - wx);
        val = fmaf(xp[iy*Wn+ix], wyv*wxv, val);
      }
    }
    acc = fmaf(val, wp[k], acc);
  }
  out[(size_t)bc*HWn + y*Wn + x0] = acc;
}

// ---------- small direct conv (final 6->3) ----------
__global__ void k_conv3x3s(const float* __restrict__ in, const float* __restrict__ wgt,
                           const float* __restrict__ bias, const float* __restrict__ res,
                           float* __restrict__ out, int Cin, int Cout){
  int g = blockIdx.x;
  int b = g / Cout; int o0 = g - b*Cout;
  int y = blockIdx.y, x = threadIdx.x;
  float acc = bias ? bias[o0] : 0.f;
  for (int ci=0; ci<Cin; ci++){
    const float* iip = in + ((size_t)b*Cin + ci)*HWn;
    const float* wp = wgt + ((size_t)o0*Cin + ci)*9;
    #pragma unroll
    for (int ky=0; ky<3; ky++){
      int yy = y + ky - 1; if (yy < 0 || yy >= Hn) continue;
      #pragma unroll
      for (int kx=0; kx<3; kx++){
        int xx = x + kx - 1; if (xx < 0 || xx >= Wn) continue;
        acc = fmaf(iip[yy*Wn+xx], wp[ky*3+kx], acc);
      }
    }
  }
  size_t idx = ((size_t)b*Cout + o0)*HWn + y*Wn + x;
  if (res) acc += res[idx];
  out[idx] = acc;
}

// ---------- fused cross-attention: one WG per (b,h) ----------
__global__ __launch_bounds__(256) void k_attn(
    const float* __restrict__ q, const float* __restrict__ k,
    const float* __restrict__ v, float* __restrict__ o){
  __shared__ float qs[64][129];
  __shared__ float ks[64][129];
  __shared__ float vs[64][129];
  __shared__ float ps[64][66];
  int bh = blockIdx.x; int b = bh >> 7, h = bh & 127;
  size_t base = ((size_t)b*64*128 + h)*128;
  int tid = threadIdx.x;
  for (int e = tid; e < 8192; e += 256){
    int c = e >> 7, w = e & 127;
    size_t g = base + (size_t)c*HWn + w;
    qs[c][w] = q[g]; ks[c][w] = k[g]; vs[c][w] = v[g];
  }
  __syncthreads();
  {
    int c0 = (tid >> 4) << 2, d0 = (tid & 15) << 2;
    float acc[4][4];
    #pragma unroll
    for (int a=0; a<4; a++)
      #pragma unroll
      for (int bb=0; bb<4; bb++) acc[a][bb] = 0.f;
    for (int i=0; i<128; i++){
      float qv[4], kv[4];
      #pragma unroll
      for (int a=0; a<4; a++){ qv[a] = qs[c0+a][i]; kv[a] = ks[d0+a][i]; }
      #pragma unroll
      for (int a=0; a<4; a++)
        #pragma unroll
        for (int bb=0; bb<4; bb++) acc[a][bb] = fmaf(qv[a], kv[bb], acc[a][bb]);
    }
    #pragma unroll
    for (int a=0; a<4; a++)
      #pragma unroll
      for (int bb=0; bb<4; bb++)
        ps[c0+a][d0+bb] = acc[a][bb] * 0.35355339059327373f;
  }
  __syncthreads();
  {
    int wv = tid >> 6, lane = tid & 63;
    for (int it=0; it<16; it++){
      int row = wv*16 + it;
      float vv = ps[row][lane];
      float m = vv;
      #pragma unroll
      for (int off=32; off; off>>=1) m = fmaxf(m, __shfl_xor(m, off));
      float e = expf(vv - m);
      float s = e;
      #pragma unroll
      for (int off=32; off; off>>=1) s += __shfl_xor(s, off);
      ps[row][lane] = e / s;
    }
  }
  __syncthreads();
  {
    int c0 = (tid >> 4) << 2, w0 = (tid & 15) << 3;
    float acc[4][8];
    #pragma unroll
    for (int a=0; a<4; a++)
      #pragma unroll
      for (int j=0; j<8; j++) acc[a][j] = 0.f;
    for (int d=0; d<64; d++){
      float pv[4], vv[8];
      #pragma unroll
      for (int a=0; a<4; a++) pv[a] = ps[c0+a][d];
      #pragma unroll
      for (int j=0; j<8; j++) vv[j] = vs[d][w0+j];
      #pragma unroll
      for (int a=0; a<4; a++)
        #pragma unroll
        for (int j=0; j<8; j++) acc[a][j] = fmaf(pv[a], vv[j], acc[a][j]);
    }
    #pragma unroll
    for (int a=0; a<4; a++)
      #pragma unroll
      for (int j=0; j<8; j++)
        o[base + (size_t)(c0+a)*HWn + w0 + j] = acc[a][j];
  }
}

// ============ wave-level 128-pt FFT (no barriers, register-resident) ============
__device__ __forceinline__ float2 cmul(float2 a, float2 b){
  return make_float2(a.x*b.x - a.y*b.y, a.x*b.y + a.y*b.x);
}

__device__ __forceinline__ void wfft(float2& z0, float2& z1, const float2* twl, int l){
  {
    float dx = z0.x - z1.x, dy = z0.y - z1.y;
    z0.x += z1.x; z0.y += z1.y;
    z1 = cmul(make_float2(dx, dy), twl[6]);
  }
  #pragma unroll
  for (int s = 5; s >= 0; --s){
    int h = 1 << s;
    bool up = (l & h) != 0;
    float2 w = twl[s];
    {
      float ox = __shfl_xor(z0.x, h), oy = __shfl_xor(z0.y, h);
      float sx = up ? ox - z0.x : z0.x + ox;
      float sy = up ? oy - z0.y : z0.y + oy;
      float2 t = cmul(make_float2(sx, sy), w);
      z0.x = up ? t.x : sx;  z0.y = up ? t.y : sy;
    }
    {
      float ox = __shfl_xor(z1.x, h), oy = __shfl_xor(z1.y, h);
      float sx = up ? ox - z1.x : z1.x + ox;
      float sy = up ? oy - z1.y : z1.y + oy;
      float2 t = cmul(make_float2(sx, sy), w);
      z1.x = up ? t.x : sx;  z1.y = up ? t.y : sy;
    }
  }
}

__device__ __forceinline__ void wreorder(float2 z0, float2 z1, float2& n0, float2& n1, int l){
  int a = (int)(__brev((unsigned)(l >> 1)) >> 26);
  float p0x = __shfl(z0.x, a),   p0y = __shfl(z0.y, a);
  float p1x = __shfl(z1.x, a),   p1y = __shfl(z1.y, a);
  float q0x = __shfl(z0.x, a+1), q0y = __shfl(z0.y, a+1);
  float q1x = __shfl(z1.x, a+1), q1y = __shfl(z1.y, a+1);
  bool odd = (l & 1) != 0;
  n0 = odd ? make_float2(p1x, p1y) : make_float2(p0x, p0y);
  n1 = odd ? make_float2(q1x, q1y) : make_float2(q0x, q0y);
}

// ---------- fused rfft2 + mag/pha ----------
__global__ __launch_bounds__(256) void k_fft2(
    const float* __restrict__ x, float* __restrict__ mag, float* __restrict__ pha){
  __shared__ float2 sp[8320];
  int img = blockIdx.x;
  int tid = threadIdx.x;
  int wv = tid >> 6, l = tid & 63;
  float2 twl[7];
  #pragma unroll
  for (int s = 0; s < 7; ++s){
    int jh = (l & ((1 << s) - 1)) << (6 - s);
    float sv, cv; sincosf(-TWOPI * (float)jh * (1.f/128.f), &sv, &cv);
    twl[s] = make_float2(cv, sv);
  }
  const float* xp = x + (size_t)img*HWn;
  for (int f = wv; f < 64; f += 4){
    const float* r0 = xp + (2*f)*Wn;
    const float* r1 = xp + (2*f+1)*Wn;
    float2 z0 = make_float2(r0[l],      r1[l]);
    float2 z1 = make_float2(r0[64 + l], r1[64 + l]);
    wfft(z0, z1, twl, l);
    float2 n0, n1; wreorder(z0, z1, n0, n1, l);
    float zhx = __shfl(n1.x, (64 - l) & 63);
    float zhy = __shfl(n1.y, (64 - l) & 63);
    float2 Zn = (l == 0) ? n0 : make_float2(zhx, zhy);
    float2 A  = make_float2(0.5f*(n0.x + Zn.x), 0.5f*(n0.y - Zn.y));
    float2 Bv = make_float2(0.5f*(n0.y + Zn.y), 0.5f*(Zn.x - n0.x));
    sp[(2*f)*65 + l]   = A;
    sp[(2*f+1)*65 + l] = Bv;
    if (l == 0){
      sp[(2*f)*65 + 64]   = make_float2(n1.x, 0.f);
      sp[(2*f+1)*65 + 64] = make_float2(n1.y, 0.f);
    }
  }
  __syncthreads();
  for (int c = wv; c < 65; c += 4){
    float2 z0 = sp[l*65 + c];
    float2 z1 = sp[(64 + l)*65 + c];
    wfft(z0, z1, twl, l);
    float2 n0, n1; wreorder(z0, z1, n0, n1, l);
    sp[l*65 + c]        = make_float2(sqrtf(n0.x*n0.x + n0.y*n0.y), atan2f(n0.y, n0.x));
    sp[(64 + l)*65 + c] = make_float2(sqrtf(n1.x*n1.x + n1.y*n1.y), atan2f(n1.y, n1.x));
  }
  __syncthreads();
  int b = img >> 6, ch = img & 63;
  float* mp = mag + ((size_t)b*128 + ch)*HWFn;
  float* pp = pha + ((size_t)b*128 + ch)*HWFn;
  for (int i = tid; i < 8320; i += 256){
    float2 v = sp[i];
    mp[i] = v.x; pp[i] = v.y;
  }
}

// ---------- fused irfft2 + residual add ----------
__global__ __launch_bounds__(256) void k_ifft2(
    const float* __restrict__ mo, const float* __restrict__ po,
    const float* __restrict__ hsrc, float* __restrict__ outp){
  __shared__ float2 sp[8320];
  int img = blockIdx.x;
  int tid = threadIdx.x;
  int wv = tid >> 6, l = tid & 63;
  float2 twl[7];
  #pragma unroll
  for (int s = 0; s < 7; ++s){
    int jh = (l & ((1 << s) - 1)) << (6 - s);
    float sv, cv; sincosf(TWOPI * (float)jh * (1.f/128.f), &sv, &cv);
    twl[s] = make_float2(cv, sv);
  }
  const float* mp = mo + (size_t)img*HWFn;
  const float* pp = po + (size_t)img*HWFn;
  for (int i = tid; i < 8320; i += 256){
    float m = mp[i], p = pp[i];
    float sv, cv; sincosf(p, &sv, &cv);
    sp[i] = make_float2(m*cv, m*sv);
  }
  __syncthreads();
  for (int c = wv; c < 65; c += 4){
    float2 z0 = sp[l*65 + c];
    float2 z1 = sp[(64 + l)*65 + c];
    wfft(z0, z1, twl, l);
    float2 n0, n1; wreorder(z0, z1, n0, n1, l);
    sp[l*65 + c]        = n0;
    sp[(64 + l)*65 + c] = n1;
  }
  __syncthreads();
  const float scl = 1.f/16384.f;
  for (int f = wv; f < 64; f += 4){
    float2 A  = sp[(2*f)*65 + l];
    float2 Bv = sp[(2*f+1)*65 + l];
    if (l == 0){ A.y = 0.f; Bv.y = 0.f; }
    float2 z0 = make_float2(A.x - Bv.y, A.y + Bv.x);
    int lm = 64 - l;
    float2 Am = sp[(2*f)*65 + lm];
    float2 Bm = sp[(2*f+1)*65 + lm];
    float2 z1 = (l == 0) ? make_float2(Am.x, Bm.x)
                         : make_float2(Am.x + Bm.y, Bm.x - Am.y);
    wfft(z0, z1, twl, l);
    float2 n0, n1; wreorder(z0, z1, n0, n1, l);
    size_t g0 = (size_t)img*HWn + (size_t)(2*f)*Wn + l;
    size_t g1 = g0 + Wn;
    outp[g0]      = n0.x*scl + hsrc[g0];
    outp[g0 + 64] = n1.x*scl + hsrc[g0 + 64];
    outp[g1]      = n0.y*scl + hsrc[g1];
    outp[g1 + 64] = n1.y*scl + hsrc[g1 + 64];
  }
}

} // namespace

extern "C" void kernel_launch(void* const* d_in, const int* in_sizes, int n_in,
                              void* d_out, int out_size, void* d_ws, size_t ws_size,
                              hipStream_t stream){
  const float *xf   =(const float*)d_in[0],  *chodw=(const float*)d_in[1],
              *chopw=(const float*)d_in[2],  *chdcn=(const float*)d_in[3],
              *chpw =(const float*)d_in[4],  *ctodw=(const float*)d_in[5],
              *ctopw=(const float*)d_in[6],  *ctdcn=(const float*)d_in[7],
              *ctpw =(const float*)d_in[8],  *dbw  =(const float*)d_in[9],
              *dbb  =(const float*)d_in[10], *cadw =(const float*)d_in[11],
              *cadb =(const float*)d_in[12], *capw =(const float*)d_in[13],
              *capb =(const float*)d_in[14], *hhw  =(const float*)d_in[15],
              *hhb  =(const float*)d_in[16], *fd1w =(const float*)d_in[17],
              *fd2w =(const float*)d_in[18], *fd1g =(const float*)d_in[19],
              *fd1bt=(const float*)d_in[20], *fd2g =(const float*)d_in[21],
              *fd2bt=(const float*)d_in[22], *fcw  =(const float*)d_in[23],
              *cw   =(const float*)d_in[24], *cb   =(const float*)d_in[25];

  constexpr size_t M = 1048576;            // one batch x 64ch x HW (floats)
  float* ws = (float*)d_ws;
  float* h     = ws;                       // 12*M
  float* fftHL = ws + 12*M;                // 4*M
  float* cat6  = ws + 16*M;                // 1,179,648
  unsigned short* wpkDB = (unsigned short*)(cat6 + 1179648);
  unsigned short* wpkHH = wpkDB + 552960;
  float* P = cat6 + 1179648 + 313344;      // pool

  const int NB = (ws_size >= 266018816ull) ? 4 : 1;
  const size_t S = (size_t)NB*M;
  float* kb  = P;        float* vb  = P + S;   float* qb  = P + 2*S;
  float* qsl = P + 3*S;  // former qs slot: now holds packed pw weights (after phase 2)
  float* aA  = P + 4*S;  float* aB  = P + 5*S;
  float* aC  = P + 6*S;  float* hh1 = P + 7*S; float* sA  = P + 8*S;
  float* sB  = P + 9*S;  float* dbuf= P + 10*S;
  float* X   = P + 11*S;
  unsigned short* pwpkCA = (unsigned short*)qsl;      // 6*4096
  unsigned short* pwpkTO = pwpkCA + 24576;            // 2048
  unsigned short* pwpkTP = pwpkTO + 2048;             // 1024
  // phase-1 aliases
  float* dwb3 = P; float* offb12 = P + 589824; float* yb3 = P + 4128768;

  float* out = (float*)d_out;
  float* out0 = out;
  float* out1 = out + 589824;
  float* out2 = out + 589824 + 6389760;

  auto PW = [&](const float* in, const float* wg, const float* bi, const float* g, const float* bt,
                float* o, int B, int Ci, int Co, int npix, int inb, int outb, int post, float slope){
    int py = (npix + 255)/256;
    if (Co >= 64 && Ci >= 96){
      k_pwt<64><<<dim3(B, py), 256, 64*Ci*4, stream>>>(in, wg, bi, g, bt, o, Ci, Co, npix, inb, outb, post, slope);
    } else if (Co > 32){
      k_pwt<32><<<dim3(B*2, py), 256, 32*Ci*4, stream>>>(in, wg, bi, g, bt, o, Ci, Co, npix, inb, outb, post, slope);
    } else if (Co > 18){
      k_pwt<32><<<dim3(B, py), 256, 32*Ci*4, stream>>>(in, wg, bi, g, bt, o, Ci, Co, npix, inb, outb, post, slope);
    } else if (Co > 3){
      k_pwt<18><<<dim3(B, py), 256, 18*Ci*4, stream>>>(in, wg, bi, g, bt, o, Ci, Co, npix, inb, outb, post, slope);
    } else {
      k_pwt<3><<<dim3(B, py), 256, 3*Ci*4, stream>>>(in, wg, bi, g, bt, o, Ci, Co, npix, inb, outb, post, slope);
    }
  };
  auto MCONV = [&](const float* in, const float* in2, const unsigned short* wp, const float* bi,
                   const float* res, float* o, int B, int nblk, int dl, int lk){
    k_mconv<<<B*128, 256, 0, stream>>>(in, in2, wp, bi, res, o, nblk, dl, lk);
  };
  auto DILm = [&](const float* in, int set, const float* bset, int B){
    const unsigned short* w5 = wpkDB + (size_t)set*5*36864;
    MCONV(in, nullptr, w5,          bset,      nullptr, sA,   B, 1, 1, 1);
    MCONV(sA, nullptr, w5+36864,    bset+64,   nullptr, sB,   B, 1, 2, 1);
    MCONV(sB, nullptr, w5+2*36864,  bset+128,  nullptr, sA,   B, 1, 3, 1);
    MCONV(sA, nullptr, w5+3*36864,  bset+192,  nullptr, sB,   B, 1, 2, 1);
    MCONV(sB, nullptr, w5+4*36864,  bset+256,  in,      dbuf, B, 1, 1, 0);
  };
  auto DCONVm = [&](const float* in, int idx, float* o, int B){
    k_dwpw<4><<<B*128, 256, 0, stream>>>(in, cadw + idx*576, cadb + idx*64,
        pwpkCA + (size_t)idx*4096, capb + idx*64, o, 64, (size_t)64*HWn, 0);
  };
  auto ATTNm = [&](const float* qsrc, int qidx, float* o, int B){
    DCONVm(qsrc, qidx, qb, B);
    k_attn<<<B*128, 256, 0, stream>>>(qb, kb, vb, o);
  };
  auto PEMBEDm = [&](const float* in, float* outSlice, int B){
    k_dwpw<2><<<B*128, 256, 0, stream>>>(in, ctodw, nullptr, pwpkTO, nullptr,
        X, 18, (size_t)18*HWn, 1);
    k_defpw<<<B*128, 256, 0, stream>>>(in, X, ctdcn, pwpkTP, outSlice, 3, (size_t)6*HWn, 2);
  };

  // ===== Pack 3x3 conv weights =====
  k_pack<<<(552960 + 255)/256, 256, 0, stream>>>(dbw, wpkDB, 64, 36864, 552960);
  k_pack<<<288, 256, 0, stream>>>(hhw, wpkHH, 128, 73728, 73728);

  // ===== Phase 1: patch_embed(ch) -> h (3-channel, unfused path) =====
  k_dw3x3<<<dim3(36, Hn), 128, 0, stream>>>(xf, chodw, nullptr, dwb3, 3);
  PW(dwb3, chopw, nullptr, nullptr, nullptr, offb12, 12, 3, 18, HWn, 3*HWn, 18*HWn, 1, 0.f);
  k_deform<<<dim3(36, Hn), 128, 0, stream>>>(xf, offb12, chdcn, yb3, 3);
  PW(yb3, chpw, nullptr, nullptr, nullptr, h, 12, 3, 64, HWn, 3*HWn, 64*HWn, 2, 0.f);

  // ===== Phase 2: fft_block (wave-register 2-D FFT) =====
  if (NB == 4){
    float* mB = P;                 // [12][128][8320]
    float* pB = P + 12779520;
    k_fft2<<<768, 256, 0, stream>>>(h, mB, pB);
    PW(mB, fd1w, nullptr, fd1g, fd1bt, mB + 64*HWFn, 12, 64, 32, HWFn, 128*HWFn, 128*HWFn, 3, 0.1f);
    PW(mB, fd2w, nullptr, fd2g, fd2bt, mB + 96*HWFn, 12, 96, 32, HWFn, 128*HWFn, 128*HWFn, 3, 0.1f);
    PW(mB, fcw,  nullptr, nullptr, nullptr, out1,    12, 128, 64, HWFn, 128*HWFn, 64*HWFn, 0, 0.f);
    PW(pB, fd1w+2048, nullptr, fd1g+32, fd1bt+32, pB + 64*HWFn, 12, 64, 32, HWFn, 128*HWFn, 128*HWFn, 3, 0.1f);
    PW(pB, fd2w+3072, nullptr, fd2g+32, fd2bt+32, pB + 96*HWFn, 12, 96, 32, HWFn, 128*HWFn, 128*HWFn, 3, 0.1f);
    PW(pB, fcw+8192,  nullptr, nullptr, nullptr,  out2, 12, 128, 64, HWFn, 128*HWFn, 64*HWFn, 0, 0.f);
    k_ifft2<<<256, 256, 0, stream>>>(out1, out2, h, fftHL);
  } else {
    float* mB = P;                 // [4][128][8320]
    float* pB = P + 4259840;
    for (int c=0; c<3; c++){
      const float* hsrc = h + (size_t)c*4*M;
      float* o1 = out1 + (size_t)c*2129920;
      float* o2 = out2 + (size_t)c*2129920;
      k_fft2<<<256, 256, 0, stream>>>(hsrc, mB, pB);
      PW(mB, fd1w, nullptr, fd1g, fd1bt, mB + 64*HWFn, 4, 64, 32, HWFn, 128*HWFn, 128*HWFn, 3, 0.1f);
      PW(mB, fd2w, nullptr, fd2g, fd2bt, mB + 96*HWFn, 4, 96, 32, HWFn, 128*HWFn, 128*HWFn, 3, 0.1f);
      PW(mB, fcw,  nullptr, nullptr, nullptr, o1,      4, 128, 64, HWFn, 128*HWFn, 64*HWFn, 0, 0.f);
      PW(pB, fd1w+2048, nullptr, fd1g+32, fd1bt+32, pB + 64*HWFn, 4, 64, 32, HWFn, 128*HWFn, 128*HWFn, 3, 0.1f);
      PW(pB, fd2w+3072, nullptr, fd2g+32, fd2bt+32, pB + 96*HWFn, 4, 96, 32, HWFn, 128*HWFn, 128*HWFn, 3, 0.1f);
      PW(pB, fcw+8192,  nullptr, nullptr, nullptr,  o2, 4, 128, 64, HWFn, 128*HWFn, 64*HWFn, 0, 0.f);
      if (c == 0)
        k_ifft2<<<256, 256, 0, stream>>>(out1, out2, h, fftHL);
    }
  }

  // ===== Pack 1x1 pw weights (into former qs slot; free after phase 2) =====
  k_packpw<<<96, 256, 0, stream>>>(capw,  pwpkCA, 64, 4, 24576);
  k_packpw<<<8,  256, 0, stream>>>(ctopw, pwpkTO, 18, 2, 2048);
  k_packpw<<<4,  256, 0, stream>>>(ctpw,  pwpkTP, 3,  1, 1024);

  // ===== Phases 3-5 in groups of NB batches =====
  for (int g0=0; g0<4; g0+=NB){
    const float* hHL = h + (size_t)g0*M;
    const float* hLH = h + (size_t)(4+g0)*M;
    const float* hHH = h + (size_t)(8+g0)*M;
    const float* fHL = fftHL + (size_t)g0*M;
    DCONVm(hHH, 1, kb, NB);
    DCONVm(hHH, 2, vb, NB);
    ATTNm(hLH, 0, aA, NB);                       // x_HH_LH (== f_HH_LH)
    DCONVm(hHH, 4, kb, NB);
    DCONVm(hHH, 5, vb, NB);
    ATTNm(hHL, 3, aB, NB);                       // x_HH_HL
    ATTNm(fHL, 3, aC, NB);                       // f_HH_HL
    // x_HH2 path
    MCONV(aA, aB, wpkHH, hhb, nullptr, hh1, NB, 2, 1, 0);
    DILm(hh1, 2, dbb + 2*320, NB);
    PEMBEDm(dbuf, cat6 + (size_t)((8+g0)*6)*HWn, NB);
    // f_HH2 path
    MCONV(aA, aC, wpkHH, hhb, nullptr, hh1, NB, 2, 1, 0);
    DILm(hh1, 2, dbb + 2*320, NB);
    PEMBEDm(dbuf, cat6 + (size_t)((8+g0)*6+3)*HWn, NB);
    // x_HL2 / x_LH2
    DILm(hHL, 1, dbb + 320, NB);
    PEMBEDm(dbuf, cat6 + (size_t)(g0*6)*HWn, NB);
    DILm(hLH, 0, dbb, NB);
    PEMBEDm(dbuf, cat6 + (size_t)((4+g0)*6)*HWn, NB);
    // fft_HL / fft_LH passthroughs
    PEMBEDm(fHL, cat6 + (size_t)(g0*6+3)*HWn, NB);
    PEMBEDm(hLH, cat6 + (size_t)((4+g0)*6+3)*HWn, NB);
  }

  // ===== Final conv + residual -> out0 =====
  k_conv3x3s<<<dim3(36, Hn), 128, 0, stream>>>(cat6, cw, cb, xf, out0, 6, 3);
}

// Round 4
// 2151.242 us; speedup vs baseline: 1.8595x; 1.6018x over previous
//
#include <hip/hip_runtime.h>

namespace {

constexpr int Hn = 128, Wn = 128, HWn = 16384, HWFn = 8320;
constexpr float TWOPI = 6.2831853071795864769f;
constexpr float BN_SCALE = 0.99999500003749968f;   // 1/sqrt(1+1e-5)

typedef __attribute__((ext_vector_type(8))) short short8;
typedef __attribute__((ext_vector_type(4))) float float4v;

__device__ __forceinline__ short f2bf(float v){
  unsigned u = __float_as_uint(v);
  u += 0x7FFF + ((u >> 16) & 1);          // RNE
  return (short)(u >> 16);
}

// ---------- weight pack to MFMA A-frag order (bf16), 3x3 convs ----------
__global__ void k_pack(const float* __restrict__ w, unsigned short* __restrict__ o,
                       int Cin, int csz, int n){
  int idx = blockIdx.x*256 + threadIdx.x;
  if (idx >= n) return;
  int ck = idx / csz;
  int i  = idx - ck*csz;
  const float* wp = w + (size_t)ck*csz;
  int j = i & 7, lane = (i>>3)&63, mt = (i>>9)&3, p = i>>11;
  int blk = p/18, r = p - blk*18, tap = r>>1, ks = r&1;
  int co = mt*16 + (lane & 15);
  int ci = blk*64 + ks*32 + ((lane>>4)<<3) + j;
  o[idx] = (unsigned short)f2bf(wp[((size_t)co*Cin + ci)*9 + tap]);
}

// ---------- weight pack for 1x1 (Cin=64): blocks ordered ks*MT+mt ----------
__global__ void k_packpw(const float* __restrict__ w, unsigned short* __restrict__ o,
                         int Cout, int MT, int n){
  int i = blockIdx.x*256 + threadIdx.x;
  if (i >= n) return;
  int per = MT << 10;                 // 2*MT*512
  int set = i / per;
  int r = i - set*per;
  int j = r & 7, lane = (r>>3)&63, blk = r>>9;
  int ks = blk / MT, mt = blk - ks*MT;
  int co = mt*16 + (lane & 15);
  int ci = ks*32 + ((lane>>4)<<3) + j;
  float v = (co < Cout) ? w[(size_t)set*Cout*64 + co*64 + ci] : 0.f;
  o[i] = (unsigned short)f2bf(v);
}

// ---------- weight transform for fused fd1/fd2/fconv chain ----------
// o layout per branch (13312 floats): fd1T[64ci][32co] (BN-scale folded),
// fd2T[96ci][32co] (folded), fcT[128ci][64co]
__global__ void k_wfdc(const float* __restrict__ fd1w, const float* __restrict__ fd2w,
                       const float* __restrict__ fcw,  const float* __restrict__ fd1g,
                       const float* __restrict__ fd2g, float* __restrict__ o){
  int i = blockIdx.x*256 + threadIdx.x;   // 2*13312
  if (i >= 26624) return;
  int br = i / 13312, r = i - br*13312;
  float v;
  if (r < 2048){
    int ci = r >> 5, j = r & 31;
    v = fd1w[br*2048 + j*64 + ci] * (fd1g[br*32 + j]*BN_SCALE);
  } else if (r < 5120){
    int rr = r - 2048; int ci = rr >> 5, j = rr & 31;
    v = fd2w[br*3072 + j*96 + ci] * (fd2g[br*32 + j]*BN_SCALE);
  } else {
    int rr = r - 5120; int ci = rr >> 6, j = rr & 63;
    v = fcw[br*8192 + j*128 + ci];
  }
  o[i] = v;
}

// ---------- fused fd1+fd2+fconv over FFT-domain pixels (f32 exact) ----------
// in: [B][64][HWFn] (mag or pha); outp: [B][64][HWFn]
__global__ __launch_bounds__(256) void k_fdc(
    const float* __restrict__ in, const float* __restrict__ wT,
    const float* __restrict__ bt1, const float* __restrict__ bt2,
    float* __restrict__ outp){
  __shared__ float tls[32*256];
  __shared__ float uls[32*256];
  int b = blockIdx.x, tile = blockIdx.y;
  int tid = threadIdx.x;
  int p = tile*256 + tid;
  bool act = p < HWFn;
  if (!act) p = HWFn - 1;
  const float* ip = in + (size_t)b*64*HWFn + p;
  // pass 1: t = leaky(bn(fd1 . m))
  float t[32];
  #pragma unroll
  for (int j=0;j<32;j++) t[j] = bt1[j];
  for (int ci=0; ci<64; ci++){
    float v = ip[(size_t)ci*HWFn];
    const float* w = wT + ci*32;
    #pragma unroll
    for (int j=0;j<32;j++) t[j] = fmaf(v, w[j], t[j]);
  }
  #pragma unroll
  for (int j=0;j<32;j++){
    float a = t[j]; tls[j*256+tid] = (a>=0.f)? a : 0.1f*a;
  }
  // pass 2: u = leaky(bn(fd2 . [m; t]))
  float u[32];
  #pragma unroll
  for (int j=0;j<32;j++) u[j] = bt2[j];
  for (int ci=0; ci<64; ci++){
    float v = ip[(size_t)ci*HWFn];
    const float* w = wT + 2048 + ci*32;
    #pragma unroll
    for (int j=0;j<32;j++) u[j] = fmaf(v, w[j], u[j]);
  }
  for (int ci=0; ci<32; ci++){
    float v = tls[ci*256+tid];
    const float* w = wT + 2048 + (64+ci)*32;
    #pragma unroll
    for (int j=0;j<32;j++) u[j] = fmaf(v, w[j], u[j]);
  }
  #pragma unroll
  for (int j=0;j<32;j++){
    float a = u[j]; uls[j*256+tid] = (a>=0.f)? a : 0.1f*a;
  }
  // pass 3: out = fconv . [m; t; u]
  float acc[64];
  #pragma unroll
  for (int j=0;j<64;j++) acc[j] = 0.f;
  for (int ci=0; ci<64; ci++){
    float v = ip[(size_t)ci*HWFn];
    const float* w = wT + 5120 + ci*64;
    #pragma unroll
    for (int j=0;j<64;j++) acc[j] = fmaf(v, w[j], acc[j]);
  }
  for (int ci=0; ci<32; ci++){
    float v = tls[ci*256+tid];
    const float* w = wT + 5120 + (64+ci)*64;
    #pragma unroll
    for (int j=0;j<64;j++) acc[j] = fmaf(v, w[j], acc[j]);
  }
  for (int ci=0; ci<32; ci++){
    float v = uls[ci*256+tid];
    const float* w = wT + 5120 + (96+ci)*64;
    #pragma unroll
    for (int j=0;j<64;j++) acc[j] = fmaf(v, w[j], acc[j]);
  }
  if (act){
    float* op = outp + (size_t)b*64*HWFn + p;
    #pragma unroll
    for (int j=0;j<64;j++) op[(size_t)j*HWFn] = acc[j];
  }
}

// ---------- MFMA 3x3 conv: Cout=64, one output row per WG ----------
constexpr int XST = 72;
__global__ __launch_bounds__(256) void k_mconv(
    const float* __restrict__ in, const float* __restrict__ in2,
    const unsigned short* __restrict__ wpk, const float* __restrict__ bias,
    const float* __restrict__ res, float* __restrict__ out,
    int nblk, int dl, int leaky){
  __shared__ short lds[3*134*XST];
  int b = blockIdx.x >> 7, y = blockIdx.x & 127;
  int tid = threadIdx.x;
  int wv = tid >> 6, lane = tid & 63;
  int nq = lane >> 4, nr = lane & 15;
  float4v acc[4][2];
  #pragma unroll
  for (int mt=0; mt<4; mt++)
    #pragma unroll
    for (int nt=0; nt<2; nt++) acc[mt][nt] = (float4v){0.f,0.f,0.f,0.f};

  for (int blk=0; blk<nblk; blk++){
    const float* src = blk ? in2 : in;
    __syncthreads();
    // interior: vectorized float4 along x
    for (int e = tid; e < 3*64*32; e += 256){
      int dy = e >> 11;
      int r  = e & 2047;
      int ci = r >> 5;
      int xx = (r & 31) << 2;              // 0..124
      int yy = y + (dy-1)*dl;
      float4 v = make_float4(0.f,0.f,0.f,0.f);
      if (yy >= 0 && yy < Hn)
        v = *(const float4*)&src[(((size_t)b*64 + ci)*Hn + yy)*Wn + xx];
      short* d = &lds[(dy*134 + xx + 3)*XST + ci];
      d[0]     = f2bf(v.x);
      d[XST]   = f2bf(v.y);
      d[2*XST] = f2bf(v.z);
      d[3*XST] = f2bf(v.w);
    }
    // edges zero: x in {0,1,2,131,132,133}
    for (int e = tid; e < 3*64*6; e += 256){
      int dy = e / 384; int r = e - dy*384;
      int ci = r / 6;   int k = r - ci*6;
      int x = (k < 3) ? k : 128 + k;
      lds[(dy*134 + x)*XST + ci] = 0;
    }
    __syncthreads();
    const unsigned short* wb = wpk + (size_t)blk*36864;
    for (int tap=0; tap<9; tap++){
      int dy = tap/3, dx = tap - (tap/3)*3;
      #pragma unroll
      for (int ks=0; ks<2; ks++){
        short8 a[4];
        #pragma unroll
        for (int mt=0; mt<4; mt++)
          a[mt] = *(const short8*)(wb + (((size_t)(tap*2+ks)*4+mt)<<9) + ((size_t)lane<<3));
        #pragma unroll
        for (int nt=0; nt<2; nt++){
          int x = wv*32 + nt*16 + nr + (dx-1)*dl + 3;
          short8 bf = *(const short8*)&lds[(dy*134 + x)*XST + ks*32 + nq*8];
          #pragma unroll
          for (int mt=0; mt<4; mt++)
            acc[mt][nt] = __builtin_amdgcn_mfma_f32_16x16x32_bf16(a[mt], bf, acc[mt][nt], 0, 0, 0);
        }
      }
    }
  }
  #pragma unroll
  for (int mt=0; mt<4; mt++)
  #pragma unroll
  for (int nt=0; nt<2; nt++){
    int x = wv*32 + nt*16 + nr;
    #pragma unroll
    for (int r2=0; r2<4; r2++){
      int co = mt*16 + nq*4 + r2;
      float a = acc[mt][nt][r2] + (bias ? bias[co] : 0.f);
      if (leaky) a = (a >= 0.f) ? a : 0.01f*a;
      size_t idx = (((size_t)b*64 + co)*Hn + y)*Wn + x;
      if (res) a += res[idx];
      out[idx] = a;
    }
  }
}

// ---------- fused depthwise 3x3 + pointwise 1x1 (Cin=64) via MFMA ----------
template<int MT>
__global__ __launch_bounds__(256) void k_dwpw(
    const float* __restrict__ in, const float* __restrict__ dww, const float* __restrict__ dwb,
    const unsigned short* __restrict__ pwpk, const float* __restrict__ pwb,
    float* __restrict__ out, int Cout, size_t outb, int post){
  __shared__ short tb[128*72];       // dw output [x][ci] bf16
  __shared__ float wsm[640];         // dw weights 64*9 + bias 64
  int b = blockIdx.x >> 7, y = blockIdx.x & 127;
  int tid = threadIdx.x;
  for (int i = tid; i < 640; i += 256)
    wsm[i] = (i < 576) ? dww[i] : (dwb ? dwb[i-576] : 0.f);
  __syncthreads();
  // dw 3x3, vectorized 4x along x
  for (int e = tid; e < 2048; e += 256){
    int ci = e >> 5;
    int xx = (e & 31) << 2;            // 0..124
    const float* ip = in + ((size_t)b*64 + ci)*HWn;
    const float* wp = wsm + ci*9;
    float4 a0 = make_float4(0.f,0.f,0.f,0.f), a1 = a0, a2 = a0;
    float L0=0.f,L1=0.f,L2=0.f,R0=0.f,R1=0.f,R2=0.f;
    if (y > 0){
      const float* r = ip + (y-1)*Wn;
      a0 = *(const float4*)(r + xx);
      if (xx) L0 = r[xx-1];
      if (xx < 124) R0 = r[xx+4];
    }
    {
      const float* r = ip + y*Wn;
      a1 = *(const float4*)(r + xx);
      if (xx) L1 = r[xx-1];
      if (xx < 124) R1 = r[xx+4];
    }
    if (y < Hn-1){
      const float* r = ip + (y+1)*Wn;
      a2 = *(const float4*)(r + xx);
      if (xx) L2 = r[xx-1];
      if (xx < 124) R2 = r[xx+4];
    }
    float bb = wsm[576+ci];
    float o0=bb,o1=bb,o2=bb,o3=bb;
    float w0=wp[0],w1=wp[1],w2=wp[2];
    o0 = fmaf(w0,L0,  fmaf(w1,a0.x, fmaf(w2,a0.y, o0)));
    o1 = fmaf(w0,a0.x,fmaf(w1,a0.y, fmaf(w2,a0.z, o1)));
    o2 = fmaf(w0,a0.y,fmaf(w1,a0.z, fmaf(w2,a0.w, o2)));
    o3 = fmaf(w0,a0.z,fmaf(w1,a0.w, fmaf(w2,R0,   o3)));
    w0=wp[3];w1=wp[4];w2=wp[5];
    o0 = fmaf(w0,L1,  fmaf(w1,a1.x, fmaf(w2,a1.y, o0)));
    o1 = fmaf(w0,a1.x,fmaf(w1,a1.y, fmaf(w2,a1.z, o1)));
    o2 = fmaf(w0,a1.y,fmaf(w1,a1.z, fmaf(w2,a1.w, o2)));
    o3 = fmaf(w0,a1.z,fmaf(w1,a1.w, fmaf(w2,R1,   o3)));
    w0=wp[6];w1=wp[7];w2=wp[8];
    o0 = fmaf(w0,L2,  fmaf(w1,a2.x, fmaf(w2,a2.y, o0)));
    o1 = fmaf(w0,a2.x,fmaf(w1,a2.y, fmaf(w2,a2.z, o1)));
    o2 = fmaf(w0,a2.y,fmaf(w1,a2.z, fmaf(w2,a2.w, o2)));
    o3 = fmaf(w0,a2.z,fmaf(w1,a2.w, fmaf(w2,R2,   o3)));
    short* d = &tb[xx*72 + ci];
    d[0]   = f2bf(o0);
    d[72]  = f2bf(o1);
    d[144] = f2bf(o2);
    d[216] = f2bf(o3);
  }
  __syncthreads();
  int wv = tid>>6, lane = tid&63, nq = lane>>4, nr = lane&15;
  float4v acc[MT][2];
  #pragma unroll
  for (int mt=0; mt<MT; mt++)
    #pragma unroll
    for (int nt=0; nt<2; nt++) acc[mt][nt] = (float4v){0.f,0.f,0.f,0.f};
  #pragma unroll
  for (int ks=0; ks<2; ks++){
    short8 a[MT];
    #pragma unroll
    for (int mt=0; mt<MT; mt++)
      a[mt] = *(const short8*)(pwpk + ((ks*MT+mt)<<9) + (lane<<3));
    #pragma unroll
    for (int nt=0; nt<2; nt++){
      int x = wv*32 + nt*16 + nr;
      short8 bf = *(const short8*)&tb[x*72 + ks*32 + nq*8];
      #pragma unroll
      for (int mt=0; mt<MT; mt++)
        acc[mt][nt] = __builtin_amdgcn_mfma_f32_16x16x32_bf16(a[mt], bf, acc[mt][nt], 0, 0, 0);
    }
  }
  #pragma unroll
  for (int mt=0; mt<MT; mt++)
  #pragma unroll
  for (int nt=0; nt<2; nt++){
    int x = wv*32 + nt*16 + nr;
    #pragma unroll
    for (int r2=0; r2<4; r2++){
      int co = mt*16 + nq*4 + r2;
      if (co < Cout){
        float a = acc[mt][nt][r2] + (pwb ? pwb[co] : 0.f);
        if (post == 1) a = fminf(fmaxf(a, -1.f), 1.f);
        else if (post == 2) a = a*fminf(fmaxf(a+3.f, 0.f), 6.f)*(1.f/6.f);
        out[(size_t)b*outb + (size_t)co*HWn + y*Wn + x] = a;
      }
    }
  }
}

// ---------- fused deformable dw 3x3 + pointwise 1x1 (64 -> Cout<=16) ----------
__global__ __launch_bounds__(256) void k_defpw(
    const float* __restrict__ xg, const float* __restrict__ off, const float* __restrict__ dcnw,
    const unsigned short* __restrict__ pwpk, float* __restrict__ out,
    int Cout, size_t outb, int post){
  __shared__ short tb[128*72];
  __shared__ float wsm[576];
  int b = blockIdx.x >> 7, y = blockIdx.x & 127;
  int tid = threadIdx.x;
  int px = tid & 127;
  for (int i = tid; i < 576; i += 256) wsm[i] = dcnw[i];
  const float* op = off + (size_t)b*18*HWn + y*Wn + px;
  int r0[9], r1[9], c0[9], c1[9];
  float w00[9], w01[9], w10[9], w11[9];
  #pragma unroll
  for (int k=0; k<9; k++){
    int ky = k/3 - 1, kx = k - (k/3)*3 - 1;
    float oy = op[(size_t)(2*k)*HWn];
    float ox = op[(size_t)(2*k+1)*HWn];
    float py = (float)(y + ky) + oy;
    float pxx = (float)(px + kx) + ox;
    float fy = floorf(py), fx = floorf(pxx);
    float wy = py - fy, wx = pxx - fx;
    int y0 = (int)fy, x0 = (int)fx;
    float vy0 = (y0 >= 0 && y0 < Hn) ? 1.f : 0.f;
    float vy1 = (y0+1 >= 0 && y0+1 < Hn) ? 1.f : 0.f;
    float vx0 = (x0 >= 0 && x0 < Wn) ? 1.f : 0.f;
    float vx1 = (x0+1 >= 0 && x0+1 < Wn) ? 1.f : 0.f;
    w00[k] = (1.f-wy)*(1.f-wx)*vy0*vx0;
    w01[k] = (1.f-wy)*wx*vy0*vx1;
    w10[k] = wy*(1.f-wx)*vy1*vx0;
    w11[k] = wy*wx*vy1*vx1;
    r0[k] = min(max(y0, 0), Hn-1)*Wn;
    r1[k] = min(max(y0+1, 0), Hn-1)*Wn;
    c0[k] = min(max(x0, 0), Wn-1);
    c1[k] = min(max(x0+1, 0), Wn-1);
  }
  __syncthreads();
  for (int ci = tid >> 7; ci < 64; ci += 2){
    const float* xp = xg + ((size_t)b*64 + ci)*HWn;
    float acc = 0.f;
    #pragma unroll
    for (int k=0; k<9; k++){
      float v = w00[k]*xp[r0[k]+c0[k]] + w01[k]*xp[r0[k]+c1[k]]
              + w10[k]*xp[r1[k]+c0[k]] + w11[k]*xp[r1[k]+c1[k]];
      acc = fmaf(v, wsm[ci*9 + k], acc);
    }
    tb[px*72 + ci] = f2bf(acc);
  }
  __syncthreads();
  int wv = tid>>6, lane = tid&63, nq = lane>>4, nr = lane&15;
  float4v acc[2];
  acc[0] = (float4v){0.f,0.f,0.f,0.f};
  acc[1] = (float4v){0.f,0.f,0.f,0.f};
  #pragma unroll
  for (int ks=0; ks<2; ks++){
    short8 a = *(const short8*)(pwpk + (ks<<9) + (lane<<3));
    #pragma unroll
    for (int nt=0; nt<2; nt++){
      int x = wv*32 + nt*16 + nr;
      short8 bf = *(const short8*)&tb[x*72 + ks*32 + nq*8];
      acc[nt] = __builtin_amdgcn_mfma_f32_16x16x32_bf16(a, bf, acc[nt], 0, 0, 0);
    }
  }
  #pragma unroll
  for (int nt=0; nt<2; nt++){
    int x = wv*32 + nt*16 + nr;
    #pragma unroll
    for (int r2=0; r2<4; r2++){
      int co = nq*4 + r2;
      if (co < Cout){
        float a = acc[nt][r2];
        if (post == 2) a = a*fminf(fmaxf(a+3.f, 0.f), 6.f)*(1.f/6.f);
        out[(size_t)b*outb + (size_t)co*HWn + y*Wn + x] = a;
      }
    }
  }
}

// ---------- depthwise 3x3, pad 1 (phase-1, 3ch) ----------
__global__ void k_dw3x3(const float* __restrict__ in, const float* __restrict__ w,
                        const float* __restrict__ bias, float* __restrict__ out, int C){
  int bc = blockIdx.x; int y = blockIdx.y; int x = threadIdx.x;
  int c = bc % C;
  const float* ip = in + (size_t)bc*HWn;
  const float* wp = w + c*9;
  float acc = bias ? bias[c] : 0.f;
  #pragma unroll
  for (int ky=0; ky<3; ky++){
    int yy = y + ky - 1; if (yy < 0 || yy >= Hn) continue;
    #pragma unroll
    for (int kx=0; kx<3; kx++){
      int xx = x + kx - 1; if (xx < 0 || xx >= Wn) continue;
      acc = fmaf(ip[yy*Wn+xx], wp[ky*3+kx], acc);
    }
  }
  out[(size_t)bc*HWn + y*Wn + x] = acc;
}

// ---------- pointwise 1x1, register-tiled (phase-1 only) ----------
template<int CT>
__global__ void k_pwt(const float* __restrict__ in, const float* __restrict__ wg,
                      const float* __restrict__ bias, const float* __restrict__ bng,
                      const float* __restrict__ bnb, float* __restrict__ out,
                      int Cin, int Cout, int npix, int inb, int outb, int post, float slope){
  extern __shared__ float wsm[];
  int nt = (Cout + CT - 1)/CT;
  int b = blockIdx.x / nt, t = blockIdx.x - b*nt;
  int co0 = t*CT;
  for (int i = threadIdx.x; i < CT*Cin; i += 256){
    int co = i / Cin;
    wsm[i] = (co0 + co < Cout) ? wg[(size_t)(co0+co)*Cin + (i - co*Cin)] : 0.f;
  }
  __syncthreads();
  int p = blockIdx.y*256 + threadIdx.x;
  if (p >= npix) return;
  const float* ip = in + (size_t)b*inb + p;
  float acc[CT];
  #pragma unroll
  for (int j=0; j<CT; j++) acc[j] = 0.f;
  for (int ci=0; ci<Cin; ci++){
    float v = ip[(size_t)ci*npix];
    #pragma unroll
    for (int j=0; j<CT; j++) acc[j] = fmaf(v, wsm[j*Cin+ci], acc[j]);
  }
  #pragma unroll
  for (int j=0; j<CT; j++){
    int co = co0 + j;
    if (co < Cout){
      float a = acc[j] + (bias ? bias[co] : 0.f);
      if (bng) a = a*(bng[co]*BN_SCALE) + bnb[co];
      if (post == 1) a = fminf(fmaxf(a, -1.f), 1.f);
      else if (post == 2) a = a*fminf(fmaxf(a+3.f, 0.f), 6.f)*(1.f/6.f);
      else if (post == 3) a = (a >= 0.f) ? a : a*slope;
      out[(size_t)b*outb + (size_t)co*npix + p] = a;
    }
  }
}

// ---------- deformable depthwise 3x3 (phase-1, 3ch) ----------
__global__ void k_deform(const float* __restrict__ x, const float* __restrict__ off,
                         const float* __restrict__ w, float* __restrict__ out, int C){
  int bc = blockIdx.x; int b = bc / C; int c = bc - b*C;
  int y = blockIdx.y; int x0 = threadIdx.x;
  const float* xp = x + (size_t)bc*HWn;
  const float* op = off + (size_t)b*18*HWn + y*Wn + x0;
  const float* wp = w + c*9;
  float acc = 0.f;
  #pragma unroll
  for (int k=0; k<9; k++){
    int ky = k/3 - 1, kx = k - (k/3)*3 - 1;
    float oy = op[(size_t)(2*k)*HWn];
    float ox = op[(size_t)(2*k+1)*HWn];
    float py = (float)y + (float)ky + oy;
    float px = (float)x0 + (float)kx + ox;
    float fy = floorf(py), fx = floorf(px);
    float wy = py - fy, wx = px - fx;
    int y0 = (int)fy, xx0 = (int)fx;
    float val = 0.f;
    #pragma unroll
    for (int dy=0; dy<2; dy++){
      int iy = y0 + dy; if (iy < 0 || iy >= Hn) continue;
      float wyv = dy ? wy : (1.f - wy);
      #pragma unroll
      for (int dx=0; dx<2; dx++){
        int ix = xx0 + dx; if (ix < 0 || ix >= Wn) continue;
        float wxv = dx ? wx : (1.f - wx);
        val = fmaf(xp[iy*Wn+ix], wyv*wxv, val);
      }
    }
    acc = fmaf(val, wp[k], acc);
  }
  out[(size_t)bc*HWn + y*Wn + x0] = acc;
}

// ---------- small direct conv (final 6->3) ----------
__global__ void k_conv3x3s(const float* __restrict__ in, const float* __restrict__ wgt,
                           const float* __restrict__ bias, const float* __restrict__ res,
                           float* __restrict__ out, int Cin, int Cout){
  int g = blockIdx.x;
  int b = g / Cout; int o0 = g - b*Cout;
  int y = blockIdx.y, x = threadIdx.x;
  float acc = bias ? bias[o0] : 0.f;
  for (int ci=0; ci<Cin; ci++){
    const float* iip = in + ((size_t)b*Cin + ci)*HWn;
    const float* wp = wgt + ((size_t)o0*Cin + ci)*9;
    #pragma unroll
    for (int ky=0; ky<3; ky++){
      int yy = y + ky - 1; if (yy < 0 || yy >= Hn) continue;
      #pragma unroll
      for (int kx=0; kx<3; kx++){
        int xx = x + kx - 1; if (xx < 0 || xx >= Wn) continue;
        acc = fmaf(iip[yy*Wn+xx], wp[ky*3+kx], acc);
      }
    }
  }
  size_t idx = ((size_t)b*Cout + o0)*HWn + y*Wn + x;
  if (res) acc += res[idx];
  out[idx] = acc;
}

// ---------- fused cross-attention: one WG per (b,h) ----------
__global__ __launch_bounds__(256) void k_attn(
    const float* __restrict__ q, const float* __restrict__ k,
    const float* __restrict__ v, float* __restrict__ o){
  __shared__ float qs[64][129];
  __shared__ float ks[64][129];
  __shared__ float vs[64][129];
  __shared__ float ps[64][66];
  int bh = blockIdx.x; int b = bh >> 7, h = bh & 127;
  size_t base = ((size_t)b*64*128 + h)*128;
  int tid = threadIdx.x;
  for (int e = tid; e < 8192; e += 256){
    int c = e >> 7, w = e & 127;
    size_t g = base + (size_t)c*HWn + w;
    qs[c][w] = q[g]; ks[c][w] = k[g]; vs[c][w] = v[g];
  }
  __syncthreads();
  {
    int c0 = (tid >> 4) << 2, d0 = (tid & 15) << 2;
    float acc[4][4];
    #pragma unroll
    for (int a=0; a<4; a++)
      #pragma unroll
      for (int bb=0; bb<4; bb++) acc[a][bb] = 0.f;
    for (int i=0; i<128; i++){
      float qv[4], kv[4];
      #pragma unroll
      for (int a=0; a<4; a++){ qv[a] = qs[c0+a][i]; kv[a] = ks[d0+a][i]; }
      #pragma unroll
      for (int a=0; a<4; a++)
        #pragma unroll
        for (int bb=0; bb<4; bb++) acc[a][bb] = fmaf(qv[a], kv[bb], acc[a][bb]);
    }
    #pragma unroll
    for (int a=0; a<4; a++)
      #pragma unroll
      for (int bb=0; bb<4; bb++)
        ps[c0+a][d0+bb] = acc[a][bb] * 0.35355339059327373f;
  }
  __syncthreads();
  {
    int wv = tid >> 6, lane = tid & 63;
    for (int it=0; it<16; it++){
      int row = wv*16 + it;
      float vv = ps[row][lane];
      float m = vv;
      #pragma unroll
      for (int off=32; off; off>>=1) m = fmaxf(m, __shfl_xor(m, off));
      float e = expf(vv - m);
      float s = e;
      #pragma unroll
      for (int off=32; off; off>>=1) s += __shfl_xor(s, off);
      ps[row][lane] = e / s;
    }
  }
  __syncthreads();
  {
    int c0 = (tid >> 4) << 2, w0 = (tid & 15) << 3;
    float acc[4][8];
    #pragma unroll
    for (int a=0; a<4; a++)
      #pragma unroll
      for (int j=0; j<8; j++) acc[a][j] = 0.f;
    for (int d=0; d<64; d++){
      float pv[4], vv[8];
      #pragma unroll
      for (int a=0; a<4; a++) pv[a] = ps[c0+a][d];
      #pragma unroll
      for (int j=0; j<8; j++) vv[j] = vs[d][w0+j];
      #pragma unroll
      for (int a=0; a<4; a++)
        #pragma unroll
        for (int j=0; j<8; j++) acc[a][j] = fmaf(pv[a], vv[j], acc[a][j]);
    }
    #pragma unroll
    for (int a=0; a<4; a++)
      #pragma unroll
      for (int j=0; j<8; j++)
        o[base + (size_t)(c0+a)*HWn + w0 + j] = acc[a][j];
  }
}

// ============ wave-level 128-pt FFT (no barriers, register-resident) ============
__device__ __forceinline__ float2 cmul(float2 a, float2 b){
  return make_float2(a.x*b.x - a.y*b.y, a.x*b.y + a.y*b.x);
}

__device__ __forceinline__ void wfft(float2& z0, float2& z1, const float2* twl, int l){
  {
    float dx = z0.x - z1.x, dy = z0.y - z1.y;
    z0.x += z1.x; z0.y += z1.y;
    z1 = cmul(make_float2(dx, dy), twl[6]);
  }
  #pragma unroll
  for (int s = 5; s >= 0; --s){
    int h = 1 << s;
    bool up = (l & h) != 0;
    float2 w = twl[s];
    {
      float ox = __shfl_xor(z0.x, h), oy = __shfl_xor(z0.y, h);
      float sx = up ? ox - z0.x : z0.x + ox;
      float sy = up ? oy - z0.y : z0.y + oy;
      float2 t = cmul(make_float2(sx, sy), w);
      z0.x = up ? t.x : sx;  z0.y = up ? t.y : sy;
    }
    {
      float ox = __shfl_xor(z1.x, h), oy = __shfl_xor(z1.y, h);
      float sx = up ? ox - z1.x : z1.x + ox;
      float sy = up ? oy - z1.y : z1.y + oy;
      float2 t = cmul(make_float2(sx, sy), w);
      z1.x = up ? t.x : sx;  z1.y = up ? t.y : sy;
    }
  }
}

__device__ __forceinline__ void wreorder(float2 z0, float2 z1, float2& n0, float2& n1, int l){
  int a = (int)(__brev((unsigned)(l >> 1)) >> 26);
  float p0x = __shfl(z0.x, a),   p0y = __shfl(z0.y, a);
  float p1x = __shfl(z1.x, a),   p1y = __shfl(z1.y, a);
  float q0x = __shfl(z0.x, a+1), q0y = __shfl(z0.y, a+1);
  float q1x = __shfl(z1.x, a+1), q1y = __shfl(z1.y, a+1);
  bool odd = (l & 1) != 0;
  n0 = odd ? make_float2(p1x, p1y) : make_float2(p0x, p0y);
  n1 = odd ? make_float2(q1x, q1y) : make_float2(q0x, q0y);
}

// ---------- fused rfft2 + mag/pha: mag/pha are [B*64][HWFn] ----------
__global__ __launch_bounds__(256) void k_fft2(
    const float* __restrict__ x, float* __restrict__ mag, float* __restrict__ pha){
  __shared__ float2 sp[8320];
  int img = blockIdx.x;
  int tid = threadIdx.x;
  int wv = tid >> 6, l = tid & 63;
  float2 twl[7];
  #pragma unroll
  for (int s = 0; s < 7; ++s){
    int jh = (l & ((1 << s) - 1)) << (6 - s);
    float sv, cv; sincosf(-TWOPI * (float)jh * (1.f/128.f), &sv, &cv);
    twl[s] = make_float2(cv, sv);
  }
  const float* xp = x + (size_t)img*HWn;
  for (int f = wv; f < 64; f += 4){
    const float* r0 = xp + (2*f)*Wn;
    const float* r1 = xp + (2*f+1)*Wn;
    float2 z0 = make_float2(r0[l],      r1[l]);
    float2 z1 = make_float2(r0[64 + l], r1[64 + l]);
    wfft(z0, z1, twl, l);
    float2 n0, n1; wreorder(z0, z1, n0, n1, l);
    float zhx = __shfl(n1.x, (64 - l) & 63);
    float zhy = __shfl(n1.y, (64 - l) & 63);
    float2 Zn = (l == 0) ? n0 : make_float2(zhx, zhy);
    float2 A  = make_float2(0.5f*(n0.x + Zn.x), 0.5f*(n0.y - Zn.y));
    float2 Bv = make_float2(0.5f*(n0.y + Zn.y), 0.5f*(Zn.x - n0.x));
    sp[(2*f)*65 + l]   = A;
    sp[(2*f+1)*65 + l] = Bv;
    if (l == 0){
      sp[(2*f)*65 + 64]   = make_float2(n1.x, 0.f);
      sp[(2*f+1)*65 + 64] = make_float2(n1.y, 0.f);
    }
  }
  __syncthreads();
  for (int c = wv; c < 65; c += 4){
    float2 z0 = sp[l*65 + c];
    float2 z1 = sp[(64 + l)*65 + c];
    wfft(z0, z1, twl, l);
    float2 n0, n1; wreorder(z0, z1, n0, n1, l);
    sp[l*65 + c]        = make_float2(sqrtf(n0.x*n0.x + n0.y*n0.y), atan2f(n0.y, n0.x));
    sp[(64 + l)*65 + c] = make_float2(sqrtf(n1.x*n1.x + n1.y*n1.y), atan2f(n1.y, n1.x));
  }
  __syncthreads();
  float* mp = mag + (size_t)img*HWFn;
  float* pp = pha + (size_t)img*HWFn;
  for (int i = tid; i < 8320; i += 256){
    float2 v = sp[i];
    mp[i] = v.x; pp[i] = v.y;
  }
}

// ---------- fused irfft2 + residual add ----------
__global__ __launch_bounds__(256) void k_ifft2(
    const float* __restrict__ mo, const float* __restrict__ po,
    const float* __restrict__ hsrc, float* __restrict__ outp){
  __shared__ float2 sp[8320];
  int img = blockIdx.x;
  int tid = threadIdx.x;
  int wv = tid >> 6, l = tid & 63;
  float2 twl[7];
  #pragma unroll
  for (int s = 0; s < 7; ++s){
    int jh = (l & ((1 << s) - 1)) << (6 - s);
    float sv, cv; sincosf(TWOPI * (float)jh * (1.f/128.f), &sv, &cv);
    twl[s] = make_float2(cv, sv);
  }
  const float* mp = mo + (size_t)img*HWFn;
  const float* pp = po + (size_t)img*HWFn;
  for (int i = tid; i < 8320; i += 256){
    float m = mp[i], p = pp[i];
    float sv, cv; sincosf(p, &sv, &cv);
    sp[i] = make_float2(m*cv, m*sv);
  }
  __syncthreads();
  for (int c = wv; c < 65; c += 4){
    float2 z0 = sp[l*65 + c];
    float2 z1 = sp[(64 + l)*65 + c];
    wfft(z0, z1, twl, l);
    float2 n0, n1; wreorder(z0, z1, n0, n1, l);
    sp[l*65 + c]        = n0;
    sp[(64 + l)*65 + c] = n1;
  }
  __syncthreads();
  const float scl = 1.f/16384.f;
  for (int f = wv; f < 64; f += 4){
    float2 A  = sp[(2*f)*65 + l];
    float2 Bv = sp[(2*f+1)*65 + l];
    if (l == 0){ A.y = 0.f; Bv.y = 0.f; }
    float2 z0 = make_float2(A.x - Bv.y, A.y + Bv.x);
    int lm = 64 - l;
    float2 Am = sp[(2*f)*65 + lm];
    float2 Bm = sp[(2*f+1)*65 + lm];
    float2 z1 = (l == 0) ? make_float2(Am.x, Bm.x)
                         : make_float2(Am.x + Bm.y, Bm.x - Am.y);
    wfft(z0, z1, twl, l);
    float2 n0, n1; wreorder(z0, z1, n0, n1, l);
    size_t g0 = (size_t)img*HWn + (size_t)(2*f)*Wn + l;
    size_t g1 = g0 + Wn;
    outp[g0]      = n0.x*scl + hsrc[g0];
    outp[g0 + 64] = n1.x*scl + hsrc[g0 + 64];
    outp[g1]      = n0.y*scl + hsrc[g1];
    outp[g1 + 64] = n1.y*scl + hsrc[g1 + 64];
  }
}

} // namespace

extern "C" void kernel_launch(void* const* d_in, const int* in_sizes, int n_in,
                              void* d_out, int out_size, void* d_ws, size_t ws_size,
                              hipStream_t stream){
  const float *xf   =(const float*)d_in[0],  *chodw=(const float*)d_in[1],
              *chopw=(const float*)d_in[2],  *chdcn=(const float*)d_in[3],
              *chpw =(const float*)d_in[4],  *ctodw=(const float*)d_in[5],
              *ctopw=(const float*)d_in[6],  *ctdcn=(const float*)d_in[7],
              *ctpw =(const float*)d_in[8],  *dbw  =(const float*)d_in[9],
              *dbb  =(const float*)d_in[10], *cadw =(const float*)d_in[11],
              *cadb =(const float*)d_in[12], *capw =(const float*)d_in[13],
              *capb =(const float*)d_in[14], *hhw  =(const float*)d_in[15],
              *hhb  =(const float*)d_in[16], *fd1w =(const float*)d_in[17],
              *fd2w =(const float*)d_in[18], *fd1g =(const float*)d_in[19],
              *fd1bt=(const float*)d_in[20], *fd2g =(const float*)d_in[21],
              *fd2bt=(const float*)d_in[22], *fcw  =(const float*)d_in[23],
              *cw   =(const float*)d_in[24], *cb   =(const float*)d_in[25];

  constexpr size_t M = 1048576;            // one batch x 64ch x HW (floats)
  float* ws = (float*)d_ws;
  float* h     = ws;                       // 12*M
  float* fftHL = ws + 12*M;                // 4*M
  float* cat6  = ws + 16*M;                // 1,179,648
  unsigned short* wpkDB = (unsigned short*)(cat6 + 1179648);
  unsigned short* wpkHH = wpkDB + 552960;
  float* wfdc = (float*)(wpkHH + 73728);   // 26624 floats (2 branches x 13312)
  float* P = cat6 + 1179648 + 313344 + 26624;   // pool

  const int NB = (ws_size >= 266018816ull) ? 4 : 1;
  const size_t S = (size_t)NB*M;
  float* kb  = P;        float* vb  = P + S;   float* qb  = P + 2*S;
  float* qsl = P + 3*S;  // packed pw weights live here (written after phase 2)
  float* aA  = P + 4*S;  float* aB  = P + 5*S;
  float* aC  = P + 6*S;  float* hh1 = P + 7*S; float* sA  = P + 8*S;
  float* sB  = P + 9*S;  float* dbuf= P + 10*S;
  float* X   = P + 11*S;
  unsigned short* pwpkCA = (unsigned short*)qsl;      // 6*4096
  unsigned short* pwpkTO = pwpkCA + 24576;            // 2048
  unsigned short* pwpkTP = pwpkTO + 2048;             // 1024
  // phase-1 aliases
  float* dwb3 = P; float* offb12 = P + 589824; float* yb3 = P + 4128768;

  float* out = (float*)d_out;
  float* out0 = out;
  float* out1 = out + 589824;
  float* out2 = out + 589824 + 6389760;

  auto PW = [&](const float* in, const float* wg, const float* bi, const float* g, const float* bt,
                float* o, int B, int Ci, int Co, int npix, int inb, int outb, int post, float slope){
    int py = (npix + 255)/256;
    if (Co > 32){
      k_pwt<32><<<dim3(B*2, py), 256, 32*Ci*4, stream>>>(in, wg, bi, g, bt, o, Ci, Co, npix, inb, outb, post, slope);
    } else if (Co > 18){
      k_pwt<32><<<dim3(B, py), 256, 32*Ci*4, stream>>>(in, wg, bi, g, bt, o, Ci, Co, npix, inb, outb, post, slope);
    } else if (Co > 3){
      k_pwt<18><<<dim3(B, py), 256, 18*Ci*4, stream>>>(in, wg, bi, g, bt, o, Ci, Co, npix, inb, outb, post, slope);
    } else {
      k_pwt<3><<<dim3(B, py), 256, 3*Ci*4, stream>>>(in, wg, bi, g, bt, o, Ci, Co, npix, inb, outb, post, slope);
    }
  };
  auto MCONV = [&](const float* in, const float* in2, const unsigned short* wp, const float* bi,
                   const float* res, float* o, int B, int nblk, int dl, int lk){
    k_mconv<<<B*128, 256, 0, stream>>>(in, in2, wp, bi, res, o, nblk, dl, lk);
  };
  auto DILm = [&](const float* in, int set, const float* bset, int B){
    const unsigned short* w5 = wpkDB + (size_t)set*5*36864;
    MCONV(in, nullptr, w5,          bset,      nullptr, sA,   B, 1, 1, 1);
    MCONV(sA, nullptr, w5+36864,    bset+64,   nullptr, sB,   B, 1, 2, 1);
    MCONV(sB, nullptr, w5+2*36864,  bset+128,  nullptr, sA,   B, 1, 3, 1);
    MCONV(sA, nullptr, w5+3*36864,  bset+192,  nullptr, sB,   B, 1, 2, 1);
    MCONV(sB, nullptr, w5+4*36864,  bset+256,  in,      dbuf, B, 1, 1, 0);
  };
  auto DCONVm = [&](const float* in, int idx, float* o, int B){
    k_dwpw<4><<<B*128, 256, 0, stream>>>(in, cadw + idx*576, cadb + idx*64,
        pwpkCA + (size_t)idx*4096, capb + idx*64, o, 64, (size_t)64*HWn, 0);
  };
  auto ATTNm = [&](const float* qsrc, int qidx, float* o, int B){
    DCONVm(qsrc, qidx, qb, B);
    k_attn<<<B*128, 256, 0, stream>>>(qb, kb, vb, o);
  };
  auto PEMBEDm = [&](const float* in, float* outSlice, int B){
    k_dwpw<2><<<B*128, 256, 0, stream>>>(in, ctodw, nullptr, pwpkTO, nullptr,
        X, 18, (size_t)18*HWn, 1);
    k_defpw<<<B*128, 256, 0, stream>>>(in, X, ctdcn, pwpkTP, outSlice, 3, (size_t)6*HWn, 2);
  };

  // ===== Pack 3x3 conv weights + fdc weight transform =====
  k_pack<<<(552960 + 255)/256, 256, 0, stream>>>(dbw, wpkDB, 64, 36864, 552960);
  k_pack<<<288, 256, 0, stream>>>(hhw, wpkHH, 128, 73728, 73728);
  k_wfdc<<<104, 256, 0, stream>>>(fd1w, fd2w, fcw, fd1g, fd2g, wfdc);

  // ===== Phase 1: patch_embed(ch) -> h (3-channel, unfused path) =====
  k_dw3x3<<<dim3(36, Hn), 128, 0, stream>>>(xf, chodw, nullptr, dwb3, 3);
  PW(dwb3, chopw, nullptr, nullptr, nullptr, offb12, 12, 3, 18, HWn, 3*HWn, 18*HWn, 1, 0.f);
  k_deform<<<dim3(36, Hn), 128, 0, stream>>>(xf, offb12, chdcn, yb3, 3);
  PW(yb3, chpw, nullptr, nullptr, nullptr, h, 12, 3, 64, HWn, 3*HWn, 64*HWn, 2, 0.f);

  // ===== Phase 2: fft_block (wave-register 2-D FFT + fused branch chain) =====
  if (NB == 4){
    float* mB = P;                 // [12][64][8320]
    float* pB = P + 6389760;
    k_fft2<<<768, 256, 0, stream>>>(h, mB, pB);
    k_fdc<<<dim3(12, 33), 256, 0, stream>>>(mB, wfdc,         fd1bt,      fd2bt,      out1);
    k_fdc<<<dim3(12, 33), 256, 0, stream>>>(pB, wfdc + 13312, fd1bt + 32, fd2bt + 32, out2);
    k_ifft2<<<256, 256, 0, stream>>>(out1, out2, h, fftHL);
  } else {
    // 3 chunks of 4 batches
    float* mB = P;                 // [4][64][8320]
    float* pB = P + 2129920;
    for (int c=0; c<3; c++){
      const float* hsrc = h + (size_t)c*4*M;
      float* o1 = out1 + (size_t)c*2129920;
      float* o2 = out2 + (size_t)c*2129920;
      k_fft2<<<256, 256, 0, stream>>>(hsrc, mB, pB);
      k_fdc<<<dim3(4, 33), 256, 0, stream>>>(mB, wfdc,         fd1bt,      fd2bt,      o1);
      k_fdc<<<dim3(4, 33), 256, 0, stream>>>(pB, wfdc + 13312, fd1bt + 32, fd2bt + 32, o2);
      if (c == 0)
        k_ifft2<<<256, 256, 0, stream>>>(out1, out2, h, fftHL);
    }
  }

  // ===== Pack 1x1 pw weights (into pool slot; free after phase 2) =====
  k_packpw<<<96, 256, 0, stream>>>(capw,  pwpkCA, 64, 4, 24576);
  k_packpw<<<8,  256, 0, stream>>>(ctopw, pwpkTO, 18, 2, 2048);
  k_packpw<<<4,  256, 0, stream>>>(ctpw,  pwpkTP, 3,  1, 1024);

  // ===== Phases 3-5 in groups of NB batches =====
  for (int g0=0; g0<4; g0+=NB){
    const float* hHL = h + (size_t)g0*M;
    const float* hLH = h + (size_t)(4+g0)*M;
    const float* hHH = h + (size_t)(8+g0)*M;
    const float* fHL = fftHL + (size_t)g0*M;
    DCONVm(hHH, 1, kb, NB);
    DCONVm(hHH, 2, vb, NB);
    ATTNm(hLH, 0, aA, NB);                       // x_HH_LH (== f_HH_LH)
    DCONVm(hHH, 4, kb, NB);
    DCONVm(hHH, 5, vb, NB);
    ATTNm(hHL, 3, aB, NB);                       // x_HH_HL
    ATTNm(fHL, 3, aC, NB);                       // f_HH_HL
    // x_HH2 path
    MCONV(aA, aB, wpkHH, hhb, nullptr, hh1, NB, 2, 1, 0);
    DILm(hh1, 2, dbb + 2*320, NB);
    PEMBEDm(dbuf, cat6 + (size_t)((8+g0)*6)*HWn, NB);
    // f_HH2 path
    MCONV(aA, aC, wpkHH, hhb, nullptr, hh1, NB, 2, 1, 0);
    DILm(hh1, 2, dbb + 2*320, NB);
    PEMBEDm(dbuf, cat6 + (size_t)((8+g0)*6+3)*HWn, NB);
    // x_HL2 / x_LH2
    DILm(hHL, 1, dbb + 320, NB);
    PEMBEDm(dbuf, cat6 + (size_t)(g0*6)*HWn, NB);
    DILm(hLH, 0, dbb, NB);
    PEMBEDm(dbuf, cat6 + (size_t)((4+g0)*6)*HWn, NB);
    // fft_HL / fft_LH passthroughs
    PEMBEDm(fHL, cat6 + (size_t)(g0*6+3)*HWn, NB);
    PEMBEDm(hLH, cat6 + (size_t)((4+g0)*6+3)*HWn, NB);
  }

  // ===== Final conv + residual -> out0 =====
  k_conv3x3s<<<dim3(36, Hn), 128, 0, stream>>>(cat6, cw, cb, xf, out0, 6, 3);
}

// Round 5
// 1732.565 us; speedup vs baseline: 2.3089x; 1.2417x over previous
//
#include <hip/hip_runtime.h>

namespace {

constexpr int Hn = 128, Wn = 128, HWn = 16384, HWFn = 8320;
constexpr float TWOPI = 6.2831853071795864769f;
constexpr float BN_SCALE = 0.99999500003749968f;   // 1/sqrt(1+1e-5)

typedef __attribute__((ext_vector_type(8))) short short8;
typedef __attribute__((ext_vector_type(4))) float float4v;

__device__ __forceinline__ short f2bf(float v){
  unsigned u = __float_as_uint(v);
  u += 0x7FFF + ((u >> 16) & 1);          // RNE
  return (short)(u >> 16);
}
__device__ __forceinline__ float bf2f(unsigned short u){
  return __uint_as_float(((unsigned)u) << 16);
}

// ---------- weight pack to MFMA A-frag order (bf16), 3x3 convs ----------
__global__ void k_pack(const float* __restrict__ w, unsigned short* __restrict__ o,
                       int Cin, int csz, int n){
  int idx = blockIdx.x*256 + threadIdx.x;
  if (idx >= n) return;
  int ck = idx / csz;
  int i  = idx - ck*csz;
  const float* wp = w + (size_t)ck*csz;
  int j = i & 7, lane = (i>>3)&63, mt = (i>>9)&3, p = i>>11;
  int blk = p/18, r = p - blk*18, tap = r>>1, ks = r&1;
  int co = mt*16 + (lane & 15);
  int ci = blk*64 + ks*32 + ((lane>>4)<<3) + j;
  o[idx] = (unsigned short)f2bf(wp[((size_t)co*Cin + ci)*9 + tap]);
}

// ---------- weight pack for 1x1 (Cin=64): blocks ordered ks*MT+mt ----------
__global__ void k_packpw(const float* __restrict__ w, unsigned short* __restrict__ o,
                         int Cout, int MT, int n){
  int i = blockIdx.x*256 + threadIdx.x;
  if (i >= n) return;
  int per = MT << 10;                 // 2*MT*512
  int set = i / per;
  int r = i - set*per;
  int j = r & 7, lane = (r>>3)&63, blk = r>>9;
  int ks = blk / MT, mt = blk - ks*MT;
  int co = mt*16 + (lane & 15);
  int ci = ks*32 + ((lane>>4)<<3) + j;
  float v = (co < Cout) ? w[(size_t)set*Cout*64 + co*64 + ci] : 0.f;
  o[i] = (unsigned short)f2bf(v);
}

// ---------- weight transform for fused fd1/fd2/fconv chain ----------
__global__ void k_wfdc(const float* __restrict__ fd1w, const float* __restrict__ fd2w,
                       const float* __restrict__ fcw,  const float* __restrict__ fd1g,
                       const float* __restrict__ fd2g, float* __restrict__ o){
  int i = blockIdx.x*256 + threadIdx.x;   // 2*13312
  if (i >= 26624) return;
  int br = i / 13312, r = i - br*13312;
  float v;
  if (r < 2048){
    int ci = r >> 5, j = r & 31;
    v = fd1w[br*2048 + j*64 + ci] * (fd1g[br*32 + j]*BN_SCALE);
  } else if (r < 5120){
    int rr = r - 2048; int ci = rr >> 5, j = rr & 31;
    v = fd2w[br*3072 + j*96 + ci] * (fd2g[br*32 + j]*BN_SCALE);
  } else {
    int rr = r - 5120; int ci = rr >> 6, j = rr & 63;
    v = fcw[br*8192 + j*128 + ci];
  }
  o[i] = v;
}

// ---------- fused fd1+fd2+fconv over FFT-domain pixels (f32 exact) ----------
__global__ __launch_bounds__(256) void k_fdc(
    const float* __restrict__ in, const float* __restrict__ wT,
    const float* __restrict__ bt1, const float* __restrict__ bt2,
    float* __restrict__ outp){
  __shared__ float tls[32*256];
  __shared__ float uls[32*256];
  int b = blockIdx.x, tile = blockIdx.y;
  int tid = threadIdx.x;
  int p = tile*256 + tid;
  bool act = p < HWFn;
  if (!act) p = HWFn - 1;
  const float* ip = in + (size_t)b*64*HWFn + p;
  float t[32];
  #pragma unroll
  for (int j=0;j<32;j++) t[j] = bt1[j];
  for (int ci=0; ci<64; ci++){
    float v = ip[(size_t)ci*HWFn];
    const float* w = wT + ci*32;
    #pragma unroll
    for (int j=0;j<32;j++) t[j] = fmaf(v, w[j], t[j]);
  }
  #pragma unroll
  for (int j=0;j<32;j++){
    float a = t[j]; tls[j*256+tid] = (a>=0.f)? a : 0.1f*a;
  }
  float u[32];
  #pragma unroll
  for (int j=0;j<32;j++) u[j] = bt2[j];
  for (int ci=0; ci<64; ci++){
    float v = ip[(size_t)ci*HWFn];
    const float* w = wT + 2048 + ci*32;
    #pragma unroll
    for (int j=0;j<32;j++) u[j] = fmaf(v, w[j], u[j]);
  }
  for (int ci=0; ci<32; ci++){
    float v = tls[ci*256+tid];
    const float* w = wT + 2048 + (64+ci)*32;
    #pragma unroll
    for (int j=0;j<32;j++) u[j] = fmaf(v, w[j], u[j]);
  }
  #pragma unroll
  for (int j=0;j<32;j++){
    float a = u[j]; uls[j*256+tid] = (a>=0.f)? a : 0.1f*a;
  }
  float acc[64];
  #pragma unroll
  for (int j=0;j<64;j++) acc[j] = 0.f;
  for (int ci=0; ci<64; ci++){
    float v = ip[(size_t)ci*HWFn];
    const float* w = wT + 5120 + ci*64;
    #pragma unroll
    for (int j=0;j<64;j++) acc[j] = fmaf(v, w[j], acc[j]);
  }
  for (int ci=0; ci<32; ci++){
    float v = tls[ci*256+tid];
    const float* w = wT + 5120 + (64+ci)*64;
    #pragma unroll
    for (int j=0;j<64;j++) acc[j] = fmaf(v, w[j], acc[j]);
  }
  for (int ci=0; ci<32; ci++){
    float v = uls[ci*256+tid];
    const float* w = wT + 5120 + (96+ci)*64;
    #pragma unroll
    for (int j=0;j<64;j++) acc[j] = fmaf(v, w[j], acc[j]);
  }
  if (act){
    float* op = outp + (size_t)b*64*HWFn + p;
    #pragma unroll
    for (int j=0;j<64;j++) op[(size_t)j*HWFn] = acc[j];
  }
}

// ---------- MFMA 3x3 conv: Cout=64, one output row per WG ----------
constexpr int XST = 72;
__global__ __launch_bounds__(256) void k_mconv(
    const float* __restrict__ in, const float* __restrict__ in2,
    const unsigned short* __restrict__ wpk, const float* __restrict__ bias,
    const float* __restrict__ res, float* __restrict__ out,
    int nblk, int dl, int leaky){
  __shared__ short lds[3*134*XST];
  int b = blockIdx.x >> 7, y = blockIdx.x & 127;
  int tid = threadIdx.x;
  int wv = tid >> 6, lane = tid & 63;
  int nq = lane >> 4, nr = lane & 15;
  float4v acc[4][2];
  #pragma unroll
  for (int mt=0; mt<4; mt++)
    #pragma unroll
    for (int nt=0; nt<2; nt++) acc[mt][nt] = (float4v){0.f,0.f,0.f,0.f};

  for (int blk=0; blk<nblk; blk++){
    const float* src = blk ? in2 : in;
    __syncthreads();
    for (int e = tid; e < 3*64*32; e += 256){
      int dy = e >> 11;
      int r  = e & 2047;
      int ci = r >> 5;
      int xx = (r & 31) << 2;              // 0..124
      int yy = y + (dy-1)*dl;
      float4 v = make_float4(0.f,0.f,0.f,0.f);
      if (yy >= 0 && yy < Hn)
        v = *(const float4*)&src[(((size_t)b*64 + ci)*Hn + yy)*Wn + xx];
      short* d = &lds[(dy*134 + xx + 3)*XST + ci];
      d[0]     = f2bf(v.x);
      d[XST]   = f2bf(v.y);
      d[2*XST] = f2bf(v.z);
      d[3*XST] = f2bf(v.w);
    }
    for (int e = tid; e < 3*64*6; e += 256){
      int dy = e / 384; int r = e - dy*384;
      int ci = r / 6;   int k = r - ci*6;
      int x = (k < 3) ? k : 128 + k;
      lds[(dy*134 + x)*XST + ci] = 0;
    }
    __syncthreads();
    const unsigned short* wb = wpk + (size_t)blk*36864;
    for (int tap=0; tap<9; tap++){
      int dy = tap/3, dx = tap - (tap/3)*3;
      #pragma unroll
      for (int ks=0; ks<2; ks++){
        short8 a[4];
        #pragma unroll
        for (int mt=0; mt<4; mt++)
          a[mt] = *(const short8*)(wb + (((size_t)(tap*2+ks)*4+mt)<<9) + ((size_t)lane<<3));
        #pragma unroll
        for (int nt=0; nt<2; nt++){
          int x = wv*32 + nt*16 + nr + (dx-1)*dl + 3;
          short8 bf = *(const short8*)&lds[(dy*134 + x)*XST + ks*32 + nq*8];
          #pragma unroll
          for (int mt=0; mt<4; mt++)
            acc[mt][nt] = __builtin_amdgcn_mfma_f32_16x16x32_bf16(a[mt], bf, acc[mt][nt], 0, 0, 0);
        }
      }
    }
  }
  #pragma unroll
  for (int mt=0; mt<4; mt++)
  #pragma unroll
  for (int nt=0; nt<2; nt++){
    int x = wv*32 + nt*16 + nr;
    #pragma unroll
    for (int r2=0; r2<4; r2++){
      int co = mt*16 + nq*4 + r2;
      float a = acc[mt][nt][r2] + (bias ? bias[co] : 0.f);
      if (leaky) a = (a >= 0.f) ? a : 0.01f*a;
      size_t idx = (((size_t)b*64 + co)*Hn + y)*Wn + x;
      if (res) a += res[idx];
      out[idx] = a;
    }
  }
}

// ---------- fused depthwise 3x3 + pointwise 1x1 (Cin=64) via MFMA ----------
template<int MT>
__global__ __launch_bounds__(256) void k_dwpw(
    const float* __restrict__ in, const float* __restrict__ dww, const float* __restrict__ dwb,
    const unsigned short* __restrict__ pwpk, const float* __restrict__ pwb,
    float* __restrict__ out, int Cout, size_t outb, int post){
  __shared__ short tb[128*72];       // dw output [x][ci] bf16
  __shared__ float wsm[640];         // dw weights 64*9 + bias 64
  int b = blockIdx.x >> 7, y = blockIdx.x & 127;
  int tid = threadIdx.x;
  for (int i = tid; i < 640; i += 256)
    wsm[i] = (i < 576) ? dww[i] : (dwb ? dwb[i-576] : 0.f);
  __syncthreads();
  for (int e = tid; e < 2048; e += 256){
    int ci = e >> 5;
    int xx = (e & 31) << 2;            // 0..124
    const float* ip = in + ((size_t)b*64 + ci)*HWn;
    const float* wp = wsm + ci*9;
    float4 a0 = make_float4(0.f,0.f,0.f,0.f), a1 = a0, a2 = a0;
    float L0=0.f,L1=0.f,L2=0.f,R0=0.f,R1=0.f,R2=0.f;
    if (y > 0){
      const float* r = ip + (y-1)*Wn;
      a0 = *(const float4*)(r + xx);
      if (xx) L0 = r[xx-1];
      if (xx < 124) R0 = r[xx+4];
    }
    {
      const float* r = ip + y*Wn;
      a1 = *(const float4*)(r + xx);
      if (xx) L1 = r[xx-1];
      if (xx < 124) R1 = r[xx+4];
    }
    if (y < Hn-1){
      const float* r = ip + (y+1)*Wn;
      a2 = *(const float4*)(r + xx);
      if (xx) L2 = r[xx-1];
      if (xx < 124) R2 = r[xx+4];
    }
    float bb = wsm[576+ci];
    float o0=bb,o1=bb,o2=bb,o3=bb;
    float w0=wp[0],w1=wp[1],w2=wp[2];
    o0 = fmaf(w0,L0,  fmaf(w1,a0.x, fmaf(w2,a0.y, o0)));
    o1 = fmaf(w0,a0.x,fmaf(w1,a0.y, fmaf(w2,a0.z, o1)));
    o2 = fmaf(w0,a0.y,fmaf(w1,a0.z, fmaf(w2,a0.w, o2)));
    o3 = fmaf(w0,a0.z,fmaf(w1,a0.w, fmaf(w2,R0,   o3)));
    w0=wp[3];w1=wp[4];w2=wp[5];
    o0 = fmaf(w0,L1,  fmaf(w1,a1.x, fmaf(w2,a1.y, o0)));
    o1 = fmaf(w0,a1.x,fmaf(w1,a1.y, fmaf(w2,a1.z, o1)));
    o2 = fmaf(w0,a1.y,fmaf(w1,a1.z, fmaf(w2,a1.w, o2)));
    o3 = fmaf(w0,a1.z,fmaf(w1,a1.w, fmaf(w2,R1,   o3)));
    w0=wp[6];w1=wp[7];w2=wp[8];
    o0 = fmaf(w0,L2,  fmaf(w1,a2.x, fmaf(w2,a2.y, o0)));
    o1 = fmaf(w0,a2.x,fmaf(w1,a2.y, fmaf(w2,a2.z, o1)));
    o2 = fmaf(w0,a2.y,fmaf(w1,a2.z, fmaf(w2,a2.w, o2)));
    o3 = fmaf(w0,a2.z,fmaf(w1,a2.w, fmaf(w2,R2,   o3)));
    short* d = &tb[xx*72 + ci];
    d[0]   = f2bf(o0);
    d[72]  = f2bf(o1);
    d[144] = f2bf(o2);
    d[216] = f2bf(o3);
  }
  __syncthreads();
  int wv = tid>>6, lane = tid&63, nq = lane>>4, nr = lane&15;
  float4v acc[MT][2];
  #pragma unroll
  for (int mt=0; mt<MT; mt++)
    #pragma unroll
    for (int nt=0; nt<2; nt++) acc[mt][nt] = (float4v){0.f,0.f,0.f,0.f};
  #pragma unroll
  for (int ks=0; ks<2; ks++){
    short8 a[MT];
    #pragma unroll
    for (int mt=0; mt<MT; mt++)
      a[mt] = *(const short8*)(pwpk + ((ks*MT+mt)<<9) + (lane<<3));
    #pragma unroll
    for (int nt=0; nt<2; nt++){
      int x = wv*32 + nt*16 + nr;
      short8 bf = *(const short8*)&tb[x*72 + ks*32 + nq*8];
      #pragma unroll
      for (int mt=0; mt<MT; mt++)
        acc[mt][nt] = __builtin_amdgcn_mfma_f32_16x16x32_bf16(a[mt], bf, acc[mt][nt], 0, 0, 0);
    }
  }
  #pragma unroll
  for (int mt=0; mt<MT; mt++)
  #pragma unroll
  for (int nt=0; nt<2; nt++){
    int x = wv*32 + nt*16 + nr;
    #pragma unroll
    for (int r2=0; r2<4; r2++){
      int co = mt*16 + nq*4 + r2;
      if (co < Cout){
        float a = acc[mt][nt][r2] + (pwb ? pwb[co] : 0.f);
        if (post == 1) a = fminf(fmaxf(a, -1.f), 1.f);
        else if (post == 2) a = a*fminf(fmaxf(a+3.f, 0.f), 6.f)*(1.f/6.f);
        out[(size_t)b*outb + (size_t)co*HWn + y*Wn + x] = a;
      }
    }
  }
}

// ---------- fused deformable dw 3x3 + pointwise 1x1 (64 -> Cout<=16) ----------
// Offsets are clipped to [-1,1] upstream => all bilinear taps live in rows
// [y-2, y+2]. Stage that 5-row x 64-ch slab in LDS (bf16) and gather from LDS.
__global__ __launch_bounds__(512) void k_defpw(
    const float* __restrict__ xg, const float* __restrict__ off, const float* __restrict__ dcnw,
    const unsigned short* __restrict__ pwpk, float* __restrict__ out,
    int Cout, size_t outb, int post){
  __shared__ unsigned short xs[5*64*130];   // [tr][ci][c] bf16 (83.2 KB)
  __shared__ short tb[128*72];
  __shared__ float wsm[576];
  int b = blockIdx.x >> 7, y = blockIdx.x & 127;
  int tid = threadIdx.x;
  int px = tid & 127, sub = tid >> 7;       // 4 threads per pixel
  for (int i = tid; i < 576; i += 512) wsm[i] = dcnw[i];
  // stage rows clamp(y-2+tr, 0, 127) of all 64 channels as bf16
  for (int e = tid; e < 10240; e += 512){   // 5*64*32 float4 units
    int tr = e >> 11;
    int r  = e & 2047;
    int ci = r >> 5;
    int xx = (r & 31) << 2;
    int gy = min(max(y - 2 + tr, 0), Hn-1);
    float4 v = *(const float4*)&xg[(((size_t)b*64 + ci)*Hn + gy)*Wn + xx];
    unsigned short* d = &xs[(tr*64 + ci)*130 + xx];
    d[0] = (unsigned short)f2bf(v.x);
    d[1] = (unsigned short)f2bf(v.y);
    d[2] = (unsigned short)f2bf(v.z);
    d[3] = (unsigned short)f2bf(v.w);
  }
  // per-thread tap precompute (validity folded into weights; indices -> tile)
  const float* op = off + (size_t)b*18*HWn + y*Wn + px;
  int t0[9], t1[9], c0[9], c1[9];
  float w00[9], w01[9], w10[9], w11[9];
  #pragma unroll
  for (int k=0; k<9; k++){
    int ky = k/3 - 1, kx = k - (k/3)*3 - 1;
    float oy = op[(size_t)(2*k)*HWn];
    float ox = op[(size_t)(2*k+1)*HWn];
    float py = (float)(y + ky) + oy;
    float pxx = (float)(px + kx) + ox;
    float fy = floorf(py), fx = floorf(pxx);
    float wy = py - fy, wx = pxx - fx;
    int y0 = (int)fy, x0 = (int)fx;
    float vy0 = (y0 >= 0 && y0 < Hn) ? 1.f : 0.f;
    float vy1 = (y0+1 >= 0 && y0+1 < Hn) ? 1.f : 0.f;
    float vx0 = (x0 >= 0 && x0 < Wn) ? 1.f : 0.f;
    float vx1 = (x0+1 >= 0 && x0+1 < Wn) ? 1.f : 0.f;
    w00[k] = (1.f-wy)*(1.f-wx)*vy0*vx0;
    w01[k] = (1.f-wy)*wx*vy0*vx1;
    w10[k] = wy*(1.f-wx)*vy1*vx0;
    w11[k] = wy*wx*vy1*vx1;
    // tile-row indices: clamp to [0,4]; any tap forced into clamp has weight 0
    t0[k] = min(max(min(max(y0,   0), Hn-1) - (y-2), 0), 4);
    t1[k] = min(max(min(max(y0+1, 0), Hn-1) - (y-2), 0), 4);
    c0[k] = min(max(x0,   0), Wn-1);
    c1[k] = min(max(x0+1, 0), Wn-1);
  }
  __syncthreads();
  // gather from LDS: each thread handles 16 channels for its pixel
  for (int ci = sub; ci < 64; ci += 4){
    float acc = 0.f;
    #pragma unroll
    for (int k=0; k<9; k++){
      const unsigned short* b0 = &xs[(t0[k]*64 + ci)*130];
      const unsigned short* b1 = &xs[(t1[k]*64 + ci)*130];
      float v = w00[k]*bf2f(b0[c0[k]]) + w01[k]*bf2f(b0[c1[k]])
              + w10[k]*bf2f(b1[c0[k]]) + w11[k]*bf2f(b1[c1[k]]);
      acc = fmaf(v, wsm[ci*9 + k], acc);
    }
    tb[px*72 + ci] = f2bf(acc);
  }
  __syncthreads();
  // pointwise 1x1 via MFMA: 8 waves x 16 px each
  int wv = tid>>6, lane = tid&63, nq = lane>>4, nr = lane&15;
  float4v acc = (float4v){0.f,0.f,0.f,0.f};
  int x = wv*16 + nr;
  #pragma unroll
  for (int ks=0; ks<2; ks++){
    short8 a = *(const short8*)(pwpk + (ks<<9) + (lane<<3));
    short8 bf = *(const short8*)&tb[x*72 + ks*32 + nq*8];
    acc = __builtin_amdgcn_mfma_f32_16x16x32_bf16(a, bf, acc, 0, 0, 0);
  }
  #pragma unroll
  for (int r2=0; r2<4; r2++){
    int co = nq*4 + r2;
    if (co < Cout){
      float a = acc[r2];
      if (post == 2) a = a*fminf(fmaxf(a+3.f, 0.f), 6.f)*(1.f/6.f);
      out[(size_t)b*outb + (size_t)co*HWn + y*Wn + x] = a;
    }
  }
}

// ---------- depthwise 3x3, pad 1 (phase-1, 3ch) ----------
__global__ void k_dw3x3(const float* __restrict__ in, const float* __restrict__ w,
                        const float* __restrict__ bias, float* __restrict__ out, int C){
  int bc = blockIdx.x; int y = blockIdx.y; int x = threadIdx.x;
  int c = bc % C;
  const float* ip = in + (size_t)bc*HWn;
  const float* wp = w + c*9;
  float acc = bias ? bias[c] : 0.f;
  #pragma unroll
  for (int ky=0; ky<3; ky++){
    int yy = y + ky - 1; if (yy < 0 || yy >= Hn) continue;
    #pragma unroll
    for (int kx=0; kx<3; kx++){
      int xx = x + kx - 1; if (xx < 0 || xx >= Wn) continue;
      acc = fmaf(ip[yy*Wn+xx], wp[ky*3+kx], acc);
    }
  }
  out[(size_t)bc*HWn + y*Wn + x] = acc;
}

// ---------- pointwise 1x1, register-tiled (phase-1 only) ----------
template<int CT>
__global__ void k_pwt(const float* __restrict__ in, const float* __restrict__ wg,
                      const float* __restrict__ bias, const float* __restrict__ bng,
                      const float* __restrict__ bnb, float* __restrict__ out,
                      int Cin, int Cout, int npix, int inb, int outb, int post, float slope){
  extern __shared__ float wsm[];
  int nt = (Cout + CT - 1)/CT;
  int b = blockIdx.x / nt, t = blockIdx.x - b*nt;
  int co0 = t*CT;
  for (int i = threadIdx.x; i < CT*Cin; i += 256){
    int co = i / Cin;
    wsm[i] = (co0 + co < Cout) ? wg[(size_t)(co0+co)*Cin + (i - co*Cin)] : 0.f;
  }
  __syncthreads();
  int p = blockIdx.y*256 + threadIdx.x;
  if (p >= npix) return;
  const float* ip = in + (size_t)b*inb + p;
  float acc[CT];
  #pragma unroll
  for (int j=0; j<CT; j++) acc[j] = 0.f;
  for (int ci=0; ci<Cin; ci++){
    float v = ip[(size_t)ci*npix];
    #pragma unroll
    for (int j=0; j<CT; j++) acc[j] = fmaf(v, wsm[j*Cin+ci], acc[j]);
  }
  #pragma unroll
  for (int j=0; j<CT; j++){
    int co = co0 + j;
    if (co < Cout){
      float a = acc[j] + (bias ? bias[co] : 0.f);
      if (bng) a = a*(bng[co]*BN_SCALE) + bnb[co];
      if (post == 1) a = fminf(fmaxf(a, -1.f), 1.f);
      else if (post == 2) a = a*fminf(fmaxf(a+3.f, 0.f), 6.f)*(1.f/6.f);
      else if (post == 3) a = (a >= 0.f) ? a : a*slope;
      out[(size_t)b*outb + (size_t)co*npix + p] = a;
    }
  }
}

// ---------- deformable depthwise 3x3 (phase-1, 3ch) ----------
__global__ void k_deform(const float* __restrict__ x, const float* __restrict__ off,
                         const float* __restrict__ w, float* __restrict__ out, int C){
  int bc = blockIdx.x; int b = bc / C; int c = bc - b*C;
  int y = blockIdx.y; int x0 = threadIdx.x;
  const float* xp = x + (size_t)bc*HWn;
  const float* op = off + (size_t)b*18*HWn + y*Wn + x0;
  const float* wp = w + c*9;
  float acc = 0.f;
  #pragma unroll
  for (int k=0; k<9; k++){
    int ky = k/3 - 1, kx = k - (k/3)*3 - 1;
    float oy = op[(size_t)(2*k)*HWn];
    float ox = op[(size_t)(2*k+1)*HWn];
    float py = (float)y + (float)ky + oy;
    float px = (float)x0 + (float)kx + ox;
    float fy = floorf(py), fx = floorf(px);
    float wy = py - fy, wx = px - fx;
    int y0 = (int)fy, xx0 = (int)fx;
    float val = 0.f;
    #pragma unroll
    for (int dy=0; dy<2; dy++){
      int iy = y0 + dy; if (iy < 0 || iy >= Hn) continue;
      float wyv = dy ? wy : (1.f - wy);
      #pragma unroll
      for (int dx=0; dx<2; dx++){
        int ix = xx0 + dx; if (ix < 0 || ix >= Wn) continue;
        float wxv = dx ? wx : (1.f - wx);
        val = fmaf(xp[iy*Wn+ix], wyv*wxv, val);
      }
    }
    acc = fmaf(val, wp[k], acc);
  }
  out[(size_t)bc*HWn + y*Wn + x0] = acc;
}

// ---------- small direct conv (final 6->3) ----------
__global__ void k_conv3x3s(const float* __restrict__ in, const float* __restrict__ wgt,
                           const float* __restrict__ bias, const float* __restrict__ res,
                           float* __restrict__ out, int Cin, int Cout){
  int g = blockIdx.x;
  int b = g / Cout; int o0 = g - b*Cout;
  int y = blockIdx.y, x = threadIdx.x;
  float acc = bias ? bias[o0] : 0.f;
  for (int ci=0; ci<Cin; ci++){
    const float* iip = in + ((size_t)b*Cin + ci)*HWn;
    const float* wp = wgt + ((size_t)o0*Cin + ci)*9;
    #pragma unroll
    for (int ky=0; ky<3; ky++){
      int yy = y + ky - 1; if (yy < 0 || yy >= Hn) continue;
      #pragma unroll
      for (int kx=0; kx<3; kx++){
        int xx = x + kx - 1; if (xx < 0 || xx >= Wn) continue;
        acc = fmaf(iip[yy*Wn+xx], wp[ky*3+kx], acc);
      }
    }
  }
  size_t idx = ((size_t)b*Cout + o0)*HWn + y*Wn + x;
  if (res) acc += res[idx];
  out[idx] = acc;
}

// ---------- fused cross-attention: one WG per (b,h) ----------
__global__ __launch_bounds__(256) void k_attn(
    const float* __restrict__ q, const float* __restrict__ k,
    const float* __restrict__ v, float* __restrict__ o){
  __shared__ float qs[64][129];
  __shared__ float ks[64][129];
  __shared__ float vs[64][129];
  __shared__ float ps[64][66];
  int bh = blockIdx.x; int b = bh >> 7, h = bh & 127;
  size_t base = ((size_t)b*64*128 + h)*128;
  int tid = threadIdx.x;
  for (int e = tid; e < 8192; e += 256){
    int c = e >> 7, w = e & 127;
    size_t g = base + (size_t)c*HWn + w;
    qs[c][w] = q[g]; ks[c][w] = k[g]; vs[c][w] = v[g];
  }
  __syncthreads();
  {
    int c0 = (tid >> 4) << 2, d0 = (tid & 15) << 2;
    float acc[4][4];
    #pragma unroll
    for (int a=0; a<4; a++)
      #pragma unroll
      for (int bb=0; bb<4; bb++) acc[a][bb] = 0.f;
    for (int i=0; i<128; i++){
      float qv[4], kv[4];
      #pragma unroll
      for (int a=0; a<4; a++){ qv[a] = qs[c0+a][i]; kv[a] = ks[d0+a][i]; }
      #pragma unroll
      for (int a=0; a<4; a++)
        #pragma unroll
        for (int bb=0; bb<4; bb++) acc[a][bb] = fmaf(qv[a], kv[bb], acc[a][bb]);
    }
    #pragma unroll
    for (int a=0; a<4; a++)
      #pragma unroll
      for (int bb=0; bb<4; bb++)
        ps[c0+a][d0+bb] = acc[a][bb] * 0.35355339059327373f;
  }
  __syncthreads();
  {
    int wv = tid >> 6, lane = tid & 63;
    for (int it=0; it<16; it++){
      int row = wv*16 + it;
      float vv = ps[row][lane];
      float m = vv;
      #pragma unroll
      for (int off=32; off; off>>=1) m = fmaxf(m, __shfl_xor(m, off));
      float e = expf(vv - m);
      float s = e;
      #pragma unroll
      for (int off=32; off; off>>=1) s += __shfl_xor(s, off);
      ps[row][lane] = e / s;
    }
  }
  __syncthreads();
  {
    int c0 = (tid >> 4) << 2, w0 = (tid & 15) << 3;
    float acc[4][8];
    #pragma unroll
    for (int a=0; a<4; a++)
      #pragma unroll
      for (int j=0; j<8; j++) acc[a][j] = 0.f;
    for (int d=0; d<64; d++){
      float pv[4], vv[8];
      #pragma unroll
      for (int a=0; a<4; a++) pv[a] = ps[c0+a][d];
      #pragma unroll
      for (int j=0; j<8; j++) vv[j] = vs[d][w0+j];
      #pragma unroll
      for (int a=0; a<4; a++)
        #pragma unroll
        for (int j=0; j<8; j++) acc[a][j] = fmaf(pv[a], vv[j], acc[a][j]);
    }
    #pragma unroll
    for (int a=0; a<4; a++)
      #pragma unroll
      for (int j=0; j<8; j++)
        o[base + (size_t)(c0+a)*HWn + w0 + j] = acc[a][j];
  }
}

// ============ wave-level 128-pt FFT (no barriers, register-resident) ============
__device__ __forceinline__ float2 cmul(float2 a, float2 b){
  return make_float2(a.x*b.x - a.y*b.y, a.x*b.y + a.y*b.x);
}

__device__ __forceinline__ void wfft(float2& z0, float2& z1, const float2* twl, int l){
  {
    float dx = z0.x - z1.x, dy = z0.y - z1.y;
    z0.x += z1.x; z0.y += z1.y;
    z1 = cmul(make_float2(dx, dy), twl[6]);
  }
  #pragma unroll
  for (int s = 5; s >= 0; --s){
    int h = 1 << s;
    bool up = (l & h) != 0;
    float2 w = twl[s];
    {
      float ox = __shfl_xor(z0.x, h), oy = __shfl_xor(z0.y, h);
      float sx = up ? ox - z0.x : z0.x + ox;
      float sy = up ? oy - z0.y : z0.y + oy;
      float2 t = cmul(make_float2(sx, sy), w);
      z0.x = up ? t.x : sx;  z0.y = up ? t.y : sy;
    }
    {
      float ox = __shfl_xor(z1.x, h), oy = __shfl_xor(z1.y, h);
      float sx = up ? ox - z1.x : z1.x + ox;
      float sy = up ? oy - z1.y : z1.y + oy;
      float2 t = cmul(make_float2(sx, sy), w);
      z1.x = up ? t.x : sx;  z1.y = up ? t.y : sy;
    }
  }
}

__device__ __forceinline__ void wreorder(float2 z0, float2 z1, float2& n0, float2& n1, int l){
  int a = (int)(__brev((unsigned)(l >> 1)) >> 26);
  float p0x = __shfl(z0.x, a),   p0y = __shfl(z0.y, a);
  float p1x = __shfl(z1.x, a),   p1y = __shfl(z1.y, a);
  float q0x = __shfl(z0.x, a+1), q0y = __shfl(z0.y, a+1);
  float q1x = __shfl(z1.x, a+1), q1y = __shfl(z1.y, a+1);
  bool odd = (l & 1) != 0;
  n0 = odd ? make_float2(p1x, p1y) : make_float2(p0x, p0y);
  n1 = odd ? make_float2(q1x, q1y) : make_float2(q0x, q0y);
}

// ---------- fused rfft2 + mag/pha: mag/pha are [B*64][HWFn] ----------
__global__ __launch_bounds__(256) void k_fft2(
    const float* __restrict__ x, float* __restrict__ mag, float* __restrict__ pha){
  __shared__ float2 sp[8320];
  int img = blockIdx.x;
  int tid = threadIdx.x;
  int wv = tid >> 6, l = tid & 63;
  float2 twl[7];
  #pragma unroll
  for (int s = 0; s < 7; ++s){
    int jh = (l & ((1 << s) - 1)) << (6 - s);
    float sv, cv; sincosf(-TWOPI * (float)jh * (1.f/128.f), &sv, &cv);
    twl[s] = make_float2(cv, sv);
  }
  const float* xp = x + (size_t)img*HWn;
  for (int f = wv; f < 64; f += 4){
    const float* r0 = xp + (2*f)*Wn;
    const float* r1 = xp + (2*f+1)*Wn;
    float2 z0 = make_float2(r0[l],      r1[l]);
    float2 z1 = make_float2(r0[64 + l], r1[64 + l]);
    wfft(z0, z1, twl, l);
    float2 n0, n1; wreorder(z0, z1, n0, n1, l);
    float zhx = __shfl(n1.x, (64 - l) & 63);
    float zhy = __shfl(n1.y, (64 - l) & 63);
    float2 Zn = (l == 0) ? n0 : make_float2(zhx, zhy);
    float2 A  = make_float2(0.5f*(n0.x + Zn.x), 0.5f*(n0.y - Zn.y));
    float2 Bv = make_float2(0.5f*(n0.y + Zn.y), 0.5f*(Zn.x - n0.x));
    sp[(2*f)*65 + l]   = A;
    sp[(2*f+1)*65 + l] = Bv;
    if (l == 0){
      sp[(2*f)*65 + 64]   = make_float2(n1.x, 0.f);
      sp[(2*f+1)*65 + 64] = make_float2(n1.y, 0.f);
    }
  }
  __syncthreads();
  for (int c = wv; c < 65; c += 4){
    float2 z0 = sp[l*65 + c];
    float2 z1 = sp[(64 + l)*65 + c];
    wfft(z0, z1, twl, l);
    float2 n0, n1; wreorder(z0, z1, n0, n1, l);
    sp[l*65 + c]        = make_float2(sqrtf(n0.x*n0.x + n0.y*n0.y), atan2f(n0.y, n0.x));
    sp[(64 + l)*65 + c] = make_float2(sqrtf(n1.x*n1.x + n1.y*n1.y), atan2f(n1.y, n1.x));
  }
  __syncthreads();
  float* mp = mag + (size_t)img*HWFn;
  float* pp = pha + (size_t)img*HWFn;
  for (int i = tid; i < 8320; i += 256){
    float2 v = sp[i];
    mp[i] = v.x; pp[i] = v.y;
  }
}

// ---------- fused irfft2 + residual add ----------
__global__ __launch_bounds__(256) void k_ifft2(
    const float* __restrict__ mo, const float* __restrict__ po,
    const float* __restrict__ hsrc, float* __restrict__ outp){
  __shared__ float2 sp[8320];
  int img = blockIdx.x;
  int tid = threadIdx.x;
  int wv = tid >> 6, l = tid & 63;
  float2 twl[7];
  #pragma unroll
  for (int s = 0; s < 7; ++s){
    int jh = (l & ((1 << s) - 1)) << (6 - s);
    float sv, cv; sincosf(TWOPI * (float)jh * (1.f/128.f), &sv, &cv);
    twl[s] = make_float2(cv, sv);
  }
  const float* mp = mo + (size_t)img*HWFn;
  const float* pp = po + (size_t)img*HWFn;
  for (int i = tid; i < 8320; i += 256){
    float m = mp[i], p = pp[i];
    float sv, cv; sincosf(p, &sv, &cv);
    sp[i] = make_float2(m*cv, m*sv);
  }
  __syncthreads();
  for (int c = wv; c < 65; c += 4){
    float2 z0 = sp[l*65 + c];
    float2 z1 = sp[(64 + l)*65 + c];
    wfft(z0, z1, twl, l);
    float2 n0, n1; wreorder(z0, z1, n0, n1, l);
    sp[l*65 + c]        = n0;
    sp[(64 + l)*65 + c] = n1;
  }
  __syncthreads();
  const float scl = 1.f/16384.f;
  for (int f = wv; f < 64; f += 4){
    float2 A  = sp[(2*f)*65 + l];
    float2 Bv = sp[(2*f+1)*65 + l];
    if (l == 0){ A.y = 0.f; Bv.y = 0.f; }
    float2 z0 = make_float2(A.x - Bv.y, A.y + Bv.x);
    int lm = 64 - l;
    float2 Am = sp[(2*f)*65 + lm];
    float2 Bm = sp[(2*f+1)*65 + lm];
    float2 z1 = (l == 0) ? make_float2(Am.x, Bm.x)
                         : make_float2(Am.x + Bm.y, Bm.x - Am.y);
    wfft(z0, z1, twl, l);
    float2 n0, n1; wreorder(z0, z1, n0, n1, l);
    size_t g0 = (size_t)img*HWn + (size_t)(2*f)*Wn + l;
    size_t g1 = g0 + Wn;
    outp[g0]      = n0.x*scl + hsrc[g0];
    outp[g0 + 64] = n1.x*scl + hsrc[g0 + 64];
    outp[g1]      = n0.y*scl + hsrc[g1];
    outp[g1 + 64] = n1.y*scl + hsrc[g1 + 64];
  }
}

} // namespace

extern "C" void kernel_launch(void* const* d_in, const int* in_sizes, int n_in,
                              void* d_out, int out_size, void* d_ws, size_t ws_size,
                              hipStream_t stream){
  const float *xf   =(const float*)d_in[0],  *chodw=(const float*)d_in[1],
              *chopw=(const float*)d_in[2],  *chdcn=(const float*)d_in[3],
              *chpw =(const float*)d_in[4],  *ctodw=(const float*)d_in[5],
              *ctopw=(const float*)d_in[6],  *ctdcn=(const float*)d_in[7],
              *ctpw =(const float*)d_in[8],  *dbw  =(const float*)d_in[9],
              *dbb  =(const float*)d_in[10], *cadw =(const float*)d_in[11],
              *cadb =(const float*)d_in[12], *capw =(const float*)d_in[13],
              *capb =(const float*)d_in[14], *hhw  =(const float*)d_in[15],
              *hhb  =(const float*)d_in[16], *fd1w =(const float*)d_in[17],
              *fd2w =(const float*)d_in[18], *fd1g =(const float*)d_in[19],
              *fd1bt=(const float*)d_in[20], *fd2g =(const float*)d_in[21],
              *fd2bt=(const float*)d_in[22], *fcw  =(const float*)d_in[23],
              *cw   =(const float*)d_in[24], *cb   =(const float*)d_in[25];

  constexpr size_t M = 1048576;            // one batch x 64ch x HW (floats)
  float* ws = (float*)d_ws;
  float* h     = ws;                       // 12*M
  float* fftHL = ws + 12*M;                // 4*M
  float* cat6  = ws + 16*M;                // 1,179,648
  unsigned short* wpkDB = (unsigned short*)(cat6 + 1179648);
  unsigned short* wpkHH = wpkDB + 552960;
  float* wfdc = (float*)(wpkHH + 73728);   // 26624 floats (2 branches x 13312)
  float* P = cat6 + 1179648 + 313344 + 26624;   // pool

  const int NB = (ws_size >= 266018816ull) ? 4 : 1;
  const size_t S = (size_t)NB*M;
  float* kb  = P;        float* vb  = P + S;   float* qb  = P + 2*S;
  float* qsl = P + 3*S;  // packed pw weights live here (written after phase 2)
  float* aA  = P + 4*S;  float* aB  = P + 5*S;
  float* aC  = P + 6*S;  float* hh1 = P + 7*S; float* sA  = P + 8*S;
  float* sB  = P + 9*S;  float* dbuf= P + 10*S;
  float* X   = P + 11*S;
  unsigned short* pwpkCA = (unsigned short*)qsl;      // 6*4096
  unsigned short* pwpkTO = pwpkCA + 24576;            // 2048
  unsigned short* pwpkTP = pwpkTO + 2048;             // 1024
  // phase-1 aliases
  float* dwb3 = P; float* offb12 = P + 589824; float* yb3 = P + 4128768;

  float* out = (float*)d_out;
  float* out0 = out;
  float* out1 = out + 589824;
  float* out2 = out + 589824 + 6389760;

  auto PW = [&](const float* in, const float* wg, const float* bi, const float* g, const float* bt,
                float* o, int B, int Ci, int Co, int npix, int inb, int outb, int post, float slope){
    int py = (npix + 255)/256;
    if (Co > 32){
      k_pwt<32><<<dim3(B*2, py), 256, 32*Ci*4, stream>>>(in, wg, bi, g, bt, o, Ci, Co, npix, inb, outb, post, slope);
    } else if (Co > 18){
      k_pwt<32><<<dim3(B, py), 256, 32*Ci*4, stream>>>(in, wg, bi, g, bt, o, Ci, Co, npix, inb, outb, post, slope);
    } else if (Co > 3){
      k_pwt<18><<<dim3(B, py), 256, 18*Ci*4, stream>>>(in, wg, bi, g, bt, o, Ci, Co, npix, inb, outb, post, slope);
    } else {
      k_pwt<3><<<dim3(B, py), 256, 3*Ci*4, stream>>>(in, wg, bi, g, bt, o, Ci, Co, npix, inb, outb, post, slope);
    }
  };
  auto MCONV = [&](const float* in, const float* in2, const unsigned short* wp, const float* bi,
                   const float* res, float* o, int B, int nblk, int dl, int lk){
    k_mconv<<<B*128, 256, 0, stream>>>(in, in2, wp, bi, res, o, nblk, dl, lk);
  };
  auto DILm = [&](const float* in, int set, const float* bset, int B){
    const unsigned short* w5 = wpkDB + (size_t)set*5*36864;
    MCONV(in, nullptr, w5,          bset,      nullptr, sA,   B, 1, 1, 1);
    MCONV(sA, nullptr, w5+36864,    bset+64,   nullptr, sB,   B, 1, 2, 1);
    MCONV(sB, nullptr, w5+2*36864,  bset+128,  nullptr, sA,   B, 1, 3, 1);
    MCONV(sA, nullptr, w5+3*36864,  bset+192,  nullptr, sB,   B, 1, 2, 1);
    MCONV(sB, nullptr, w5+4*36864,  bset+256,  in,      dbuf, B, 1, 1, 0);
  };
  auto DCONVm = [&](const float* in, int idx, float* o, int B){
    k_dwpw<4><<<B*128, 256, 0, stream>>>(in, cadw + idx*576, cadb + idx*64,
        pwpkCA + (size_t)idx*4096, capb + idx*64, o, 64, (size_t)64*HWn, 0);
  };
  auto ATTNm = [&](const float* qsrc, int qidx, float* o, int B){
    DCONVm(qsrc, qidx, qb, B);
    k_attn<<<B*128, 256, 0, stream>>>(qb, kb, vb, o);
  };
  auto PEMBEDm = [&](const float* in, float* outSlice, int B){
    k_dwpw<2><<<B*128, 256, 0, stream>>>(in, ctodw, nullptr, pwpkTO, nullptr,
        X, 18, (size_t)18*HWn, 1);
    k_defpw<<<B*128, 512, 0, stream>>>(in, X, ctdcn, pwpkTP, outSlice, 3, (size_t)6*HWn, 2);
  };

  // ===== Pack 3x3 conv weights + fdc weight transform =====
  k_pack<<<(552960 + 255)/256, 256, 0, stream>>>(dbw, wpkDB, 64, 36864, 552960);
  k_pack<<<288, 256, 0, stream>>>(hhw, wpkHH, 128, 73728, 73728);
  k_wfdc<<<104, 256, 0, stream>>>(fd1w, fd2w, fcw, fd1g, fd2g, wfdc);

  // ===== Phase 1: patch_embed(ch) -> h (3-channel, unfused path) =====
  k_dw3x3<<<dim3(36, Hn), 128, 0, stream>>>(xf, chodw, nullptr, dwb3, 3);
  PW(dwb3, chopw, nullptr, nullptr, nullptr, offb12, 12, 3, 18, HWn, 3*HWn, 18*HWn, 1, 0.f);
  k_deform<<<dim3(36, Hn), 128, 0, stream>>>(xf, offb12, chdcn, yb3, 3);
  PW(yb3, chpw, nullptr, nullptr, nullptr, h, 12, 3, 64, HWn, 3*HWn, 64*HWn, 2, 0.f);

  // ===== Phase 2: fft_block (wave-register 2-D FFT + fused branch chain) =====
  if (NB == 4){
    float* mB = P;                 // [12][64][8320]
    float* pB = P + 6389760;
    k_fft2<<<768, 256, 0, stream>>>(h, mB, pB);
    k_fdc<<<dim3(12, 33), 256, 0, stream>>>(mB, wfdc,         fd1bt,      fd2bt,      out1);
    k_fdc<<<dim3(12, 33), 256, 0, stream>>>(pB, wfdc + 13312, fd1bt + 32, fd2bt + 32, out2);
    k_ifft2<<<256, 256, 0, stream>>>(out1, out2, h, fftHL);
  } else {
    // 3 chunks of 4 batches
    float* mB = P;                 // [4][64][8320]
    float* pB = P + 2129920;
    for (int c=0; c<3; c++){
      const float* hsrc = h + (size_t)c*4*M;
      float* o1 = out1 + (size_t)c*2129920;
      float* o2 = out2 + (size_t)c*2129920;
      k_fft2<<<256, 256, 0, stream>>>(hsrc, mB, pB);
      k_fdc<<<dim3(4, 33), 256, 0, stream>>>(mB, wfdc,         fd1bt,      fd2bt,      o1);
      k_fdc<<<dim3(4, 33), 256, 0, stream>>>(pB, wfdc + 13312, fd1bt + 32, fd2bt + 32, o2);
      if (c == 0)
        k_ifft2<<<256, 256, 0, stream>>>(out1, out2, h, fftHL);
    }
  }

  // ===== Pack 1x1 pw weights (into pool slot; free after phase 2) =====
  k_packpw<<<96, 256, 0, stream>>>(capw,  pwpkCA, 64, 4, 24576);
  k_packpw<<<8,  256, 0, stream>>>(ctopw, pwpkTO, 18, 2, 2048);
  k_packpw<<<4,  256, 0, stream>>>(ctpw,  pwpkTP, 3,  1, 1024);

  // ===== Phases 3-5 in groups of NB batches =====
  for (int g0=0; g0<4; g0+=NB){
    const float* hHL = h + (size_t)g0*M;
    const float* hLH = h + (size_t)(4+g0)*M;
    const float* hHH = h + (size_t)(8+g0)*M;
    const float* fHL = fftHL + (size_t)g0*M;
    DCONVm(hHH, 1, kb, NB);
    DCONVm(hHH, 2, vb, NB);
    ATTNm(hLH, 0, aA, NB);                       // x_HH_LH (== f_HH_LH)
    DCONVm(hHH, 4, kb, NB);
    DCONVm(hHH, 5, vb, NB);
    ATTNm(hHL, 3, aB, NB);                       // x_HH_HL
    ATTNm(fHL, 3, aC, NB);                       // f_HH_HL
    // x_HH2 path
    MCONV(aA, aB, wpkHH, hhb, nullptr, hh1, NB, 2, 1, 0);
    DILm(hh1, 2, dbb + 2*320, NB);
    PEMBEDm(dbuf, cat6 + (size_t)((8+g0)*6)*HWn, NB);
    // f_HH2 path
    MCONV(aA, aC, wpkHH, hhb, nullptr, hh1, NB, 2, 1, 0);
    DILm(hh1, 2, dbb + 2*320, NB);
    PEMBEDm(dbuf, cat6 + (size_t)((8+g0)*6+3)*HWn, NB);
    // x_HL2 / x_LH2
    DILm(hHL, 1, dbb + 320, NB);
    PEMBEDm(dbuf, cat6 + (size_t)(g0*6)*HWn, NB);
    DILm(hLH, 0, dbb, NB);
    PEMBEDm(dbuf, cat6 + (size_t)((4+g0)*6)*HWn, NB);
    // fft_HL / fft_LH passthroughs
    PEMBEDm(fHL, cat6 + (size_t)(g0*6+3)*HWn, NB);
    PEMBEDm(hLH, cat6 + (size_t)((4+g0)*6+3)*HWn, NB);
  }

  // ===== Final conv + residual -> out0 =====
  k_conv3x3s<<<dim3(36, Hn), 128, 0, stream>>>(cat6, cw, cb, xf, out0, 6, 3);
}